// Round 1
// baseline (5169.501 us; speedup 1.0000x reference)
//
#include <hip/hip_runtime.h>
#include <hip/hip_bf16.h>
#include <math.h>

#define D_MODEL 384
#define HEADS 8
#define DIM_HEAD 48
#define NTOK 1024
#define BATCH 8
#define D_FF 1536
#define LN_EPS 1e-5f

// ---------------- elementwise add (float4) ----------------
__global__ void add_kernel(const float4* __restrict__ a, const float4* __restrict__ b,
                           float4* __restrict__ o, int n4) {
    int i = blockIdx.x * blockDim.x + threadIdx.x;
    if (i < n4) {
        float4 x = a[i], y = b[i];
        o[i] = make_float4(x.x + y.x, x.y + y.y, x.z + y.z, x.w + y.w);
    }
}

// ---------------- relative bias (transposed per head) ----------------
// BT[h][n][m] = table[((ym-yn+31)*63 + (xm-xn+31))*HEADS + h]
__global__ void biasT_kernel(const float* __restrict__ table, float* __restrict__ BT) {
    long i = (long)blockIdx.x * blockDim.x + threadIdx.x;
    const long total = (long)HEADS * NTOK * NTOK;
    if (i >= total) return;
    int m = (int)(i & 1023);
    int n = (int)((i >> 10) & 1023);
    int h = (int)(i >> 20);
    int dy = (m >> 5) - (n >> 5) + 31;
    int dx = (m & 31) - (n & 31) + 31;
    BT[i] = table[(dy * 63 + dx) * HEADS + h];
}

// ---------------- generic tiled GEMM ----------------
// C = A(MxK) @ B(KxN)  [+bias[col]] [+Res] [gelu]
// batched over z: z -> (bb, hh); per-batch offsets via strides. sA_b is always 0 here.
template<bool HAS_BIAS, bool HAS_RES, bool GELU_>
__global__ __launch_bounds__(256) void gemm_kernel(
        const float* __restrict__ Ab, const float* __restrict__ Bb,
        float* __restrict__ Cb, const float* __restrict__ bias,
        const float* __restrict__ Rb,
        int M, int Kd, int Nd, int lda, int ldb, int ldc, int ldr,
        long sAh, long sBb, long sBh, long sCb, long sCh,
        long sRb, long sRh, int Hb) {
    int z = blockIdx.z;
    int bb = z / Hb, hh = z - bb * Hb;
    const float* A = Ab + (long)hh * sAh;
    const float* B = Bb + (long)bb * sBb + (long)hh * sBh;
    float* C = Cb + (long)bb * sCb + (long)hh * sCh;
    const float* R = HAS_RES ? (Rb + (long)bb * sRb + (long)hh * sRh) : nullptr;

    __shared__ float As[32][33];
    __shared__ float Bs[32][33];
    int tx = threadIdx.x, ty = threadIdx.y;  // 16x16
    int t = ty * 16 + tx;
    int row0 = blockIdx.y * 32;
    int col0 = blockIdx.x * 32;
    float acc00 = 0, acc01 = 0, acc10 = 0, acc11 = 0;

    for (int k0 = 0; k0 < Kd; k0 += 32) {
#pragma unroll
        for (int l = 0; l < 4; ++l) {
            int e = t + l * 256;
            int i = e >> 5, j = e & 31;
            int ar = row0 + i, ac = k0 + j;
            As[i][j] = (ar < M && ac < Kd) ? A[(long)ar * lda + ac] : 0.f;
            int br = k0 + i, bc = col0 + j;
            Bs[i][j] = (br < Kd && bc < Nd) ? B[(long)br * ldb + bc] : 0.f;
        }
        __syncthreads();
#pragma unroll
        for (int kk = 0; kk < 32; ++kk) {
            float a0 = As[ty * 2][kk], a1 = As[ty * 2 + 1][kk];
            float b0 = Bs[kk][tx * 2], b1 = Bs[kk][tx * 2 + 1];
            acc00 += a0 * b0; acc01 += a0 * b1;
            acc10 += a1 * b0; acc11 += a1 * b1;
        }
        __syncthreads();
    }

    float vals[2][2] = {{acc00, acc01}, {acc10, acc11}};
    int r0 = row0 + ty * 2, c0 = col0 + tx * 2;
#pragma unroll
    for (int dr = 0; dr < 2; ++dr)
#pragma unroll
        for (int dc = 0; dc < 2; ++dc) {
            int r = r0 + dr, c = c0 + dc;
            if (r < M && c < Nd) {
                float v = vals[dr][dc];
                if (HAS_BIAS) v += bias[c];
                if (HAS_RES)  v += R[(long)r * ldr + c];
                if (GELU_)    v = 0.5f * v * (1.f + erff(v * 0.70710678118654752f));
                C[(long)r * ldc + c] = v;
            }
        }
}

// ---------------- attention (one block per (b,h,query-row)) ----------------
__global__ __launch_bounds__(256) void attn_kernel(
        const float* __restrict__ q2, const float* __restrict__ k2,
        const float* __restrict__ v2, float* __restrict__ att) {
    const int n = blockIdx.x, h = blockIdx.y, b = blockIdx.z;
    const int tid = threadIdx.x;
    const long base = ((long)b * NTOK) * D_MODEL + h * DIM_HEAD;
    __shared__ float qs[DIM_HEAD];
    __shared__ float sc[NTOK];
    __shared__ float red[256];
    __shared__ float accs[5][DIM_HEAD];

    if (tid < DIM_HEAD) qs[tid] = q2[base + (long)n * D_MODEL + tid];
    __syncthreads();

    const float scale = 0.14433756729740643f;  // 48^-0.5
    float lmax = -1e30f;
    for (int m = tid; m < NTOK; m += 256) {
        const float* kr = k2 + base + (long)m * D_MODEL;
        float a = 0.f;
#pragma unroll
        for (int d = 0; d < DIM_HEAD; ++d) a += qs[d] * kr[d];
        a *= scale;
        sc[m] = a;
        lmax = fmaxf(lmax, a);
    }
    red[tid] = lmax; __syncthreads();
    for (int st = 128; st > 0; st >>= 1) {
        if (tid < st) red[tid] = fmaxf(red[tid], red[tid + st]);
        __syncthreads();
    }
    float mx = red[0];
    __syncthreads();

    float lsum = 0.f;
    for (int m = tid; m < NTOK; m += 256) {
        float p = expf(sc[m] - mx);
        sc[m] = p;
        lsum += p;
    }
    red[tid] = lsum; __syncthreads();
    for (int st = 128; st > 0; st >>= 1) {
        if (tid < st) red[tid] += red[tid + st];
        __syncthreads();
    }
    float inv = 1.f / red[0];
    __syncthreads();

    int d = tid % DIM_HEAD, part = tid / DIM_HEAD;
    if (part < 5) {
        float a = 0.f;
        for (int m = part; m < NTOK; m += 5)
            a += sc[m] * v2[base + (long)m * D_MODEL + d];
        accs[part][d] = a;
    }
    __syncthreads();
    if (tid < DIM_HEAD) {
        float a = accs[0][tid] + accs[1][tid] + accs[2][tid] + accs[3][tid] + accs[4][tid];
        att[((long)b * NTOK + n) * D_MODEL + h * DIM_HEAD + tid] = a * inv;
    }
}

// ---------------- layernorm (optional residual add) ----------------
__global__ __launch_bounds__(128) void ln_kernel(
        const float* __restrict__ X, const float* __restrict__ Rb,
        const float* __restrict__ g, const float* __restrict__ be,
        float* __restrict__ O, int hasRes) {
    int row = blockIdx.x;
    int tid = threadIdx.x;  // 128
    const float* x = X + (long)row * D_MODEL;
    float v[3];
#pragma unroll
    for (int l = 0; l < 3; ++l) {
        int c = tid + l * 128;
        v[l] = x[c];
        if (hasRes) v[l] += Rb[(long)row * D_MODEL + c];
    }
    __shared__ float red[128];
    float s = v[0] + v[1] + v[2];
    red[tid] = s; __syncthreads();
    for (int st = 64; st > 0; st >>= 1) {
        if (tid < st) red[tid] += red[tid + st];
        __syncthreads();
    }
    float mean = red[0] * (1.f / 384.f);
    __syncthreads();
    float sq = 0.f;
#pragma unroll
    for (int l = 0; l < 3; ++l) { float d = v[l] - mean; sq += d * d; }
    red[tid] = sq; __syncthreads();
    for (int st = 64; st > 0; st >>= 1) {
        if (tid < st) red[tid] += red[tid + st];
        __syncthreads();
    }
    float rstd = rsqrtf(red[0] * (1.f / 384.f) + LN_EPS);
#pragma unroll
    for (int l = 0; l < 3; ++l) {
        int c = tid + l * 128;
        O[(long)row * D_MODEL + c] = (v[l] - mean) * rstd * g[c] + be[c];
    }
}

extern "C" void kernel_launch(void* const* d_in, const int* in_sizes, int n_in,
                              void* d_out, int out_size, void* d_ws, size_t ws_size,
                              hipStream_t stream) {
    const float* src   = (const float*)d_in[0];
    const float* pos   = (const float*)d_in[1];
    const float* table = (const float*)d_in[2];
    const float* Wq  = (const float*)d_in[3];
    const float* Wk  = (const float*)d_in[4];
    const float* Wv  = (const float*)d_in[5];
    const float* Wo  = (const float*)d_in[6];
    const float* bo  = (const float*)d_in[7];
    const float* W1  = (const float*)d_in[8];
    const float* b1  = (const float*)d_in[9];
    const float* W2  = (const float*)d_in[10];
    const float* b2  = (const float*)d_in[11];
    const float* g1  = (const float*)d_in[12];
    const float* be1 = (const float*)d_in[13];
    const float* g2  = (const float*)d_in[14];
    const float* be2 = (const float*)d_in[15];
    float* out = (float*)d_out;
    float* ws  = (float*)d_ws;

    const long SZ = (long)BATCH * NTOK * D_MODEL;  // 3,145,728
    float* A  = ws;            // qk_in, later x (post-LN1)
    float* Qb = ws + SZ;       // q, later att-out
    float* Kb = ws + 2 * SZ;   // k, later o (pre-LN1)
    float* Vb = ws + 3 * SZ;   // v, later ff-out
    float* Q2 = ws + 4 * SZ;
    float* K2 = ws + 5 * SZ;
    float* V2 = ws + 6 * SZ;
    float* SH = ws + 7 * SZ;   // biasT (8.4M floats) then ff hidden (12.6M floats)

    dim3 blk(16, 16);

    // 1. A = src + pos
    {
        int n4 = (int)(SZ / 4);
        add_kernel<<<(n4 + 255) / 256, 256, 0, stream>>>(
            (const float4*)src, (const float4*)pos, (float4*)A, n4);
    }
    // 2-4. projections
    gemm_kernel<false, false, false><<<dim3(12, 256, 1), blk, 0, stream>>>(
        A, Wq, Qb, nullptr, nullptr, 8192, 384, 384, 384, 384, 384, 0,
        0, 0, 0, 0, 0, 0, 0, 1);
    gemm_kernel<false, false, false><<<dim3(12, 256, 1), blk, 0, stream>>>(
        A, Wk, Kb, nullptr, nullptr, 8192, 384, 384, 384, 384, 384, 0,
        0, 0, 0, 0, 0, 0, 0, 1);
    gemm_kernel<false, false, false><<<dim3(12, 256, 1), blk, 0, stream>>>(
        src, Wv, Vb, nullptr, nullptr, 8192, 384, 384, 384, 384, 384, 0,
        0, 0, 0, 0, 0, 0, 0, 1);
    // 5. biasT
    biasT_kernel<<<(int)(((long)HEADS * NTOK * NTOK + 255) / 256), 256, 0, stream>>>(table, SH);
    // 6-8. per-(b,h): X2 = X + biasT[h] @ X   (M=1024, K=1024, N=48)
    const long sB_b = (long)NTOK * D_MODEL, sB_h = DIM_HEAD;
    gemm_kernel<false, true, false><<<dim3(2, 32, 64), blk, 0, stream>>>(
        SH, Qb, Q2, nullptr, Qb, 1024, 1024, 48, 1024, 384, 384, 384,
        (long)NTOK * NTOK, sB_b, sB_h, sB_b, sB_h, sB_b, sB_h, HEADS);
    gemm_kernel<false, true, false><<<dim3(2, 32, 64), blk, 0, stream>>>(
        SH, Kb, K2, nullptr, Kb, 1024, 1024, 48, 1024, 384, 384, 384,
        (long)NTOK * NTOK, sB_b, sB_h, sB_b, sB_h, sB_b, sB_h, HEADS);
    gemm_kernel<false, true, false><<<dim3(2, 32, 64), blk, 0, stream>>>(
        SH, Vb, V2, nullptr, Vb, 1024, 1024, 48, 1024, 384, 384, 384,
        (long)NTOK * NTOK, sB_b, sB_h, sB_b, sB_h, sB_b, sB_h, HEADS);
    // 9. attention -> Qb (reused)
    attn_kernel<<<dim3(1024, HEADS, BATCH), 256, 0, stream>>>(Q2, K2, V2, Qb);
    // 10. o = att @ Wo + bo + src -> Kb
    gemm_kernel<true, true, false><<<dim3(12, 256, 1), blk, 0, stream>>>(
        Qb, Wo, Kb, bo, src, 8192, 384, 384, 384, 384, 384, 384,
        0, 0, 0, 0, 0, 0, 0, 1);
    // 11. x = LN(o)*g1+be1 -> A
    ln_kernel<<<8192, 128, 0, stream>>>(Kb, nullptr, g1, be1, A, 0);
    // 12. h1 = gelu(x @ W1 + b1) -> SH
    gemm_kernel<true, false, true><<<dim3(48, 256, 1), blk, 0, stream>>>(
        A, W1, SH, b1, nullptr, 8192, 384, 1536, 384, 1536, 1536, 0,
        0, 0, 0, 0, 0, 0, 0, 1);
    // 13. f = h1 @ W2 + b2 -> Vb
    gemm_kernel<true, false, false><<<dim3(12, 256, 1), blk, 0, stream>>>(
        SH, W2, Vb, b2, nullptr, 8192, 1536, 384, 1536, 384, 384, 0,
        0, 0, 0, 0, 0, 0, 0, 1);
    // 14. out = LN(x + f)*g2+be2
    ln_kernel<<<8192, 128, 0, stream>>>(A, Vb, g2, be2, out, 1);
}

// Round 3
// 3570.016 us; speedup vs baseline: 1.4480x; 1.4480x over previous
//
#include <hip/hip_runtime.h>
#include <math.h>

#define D_MODEL 384
#define HEADS 8
#define DIM_HEAD 48
#define NTOK 1024
#define BATCH 8
#define D_FF 1536
#define LN_EPS 1e-5f

typedef unsigned short u16;
typedef unsigned long long u64;
typedef short short8 __attribute__((ext_vector_type(8)));
typedef float f32x4 __attribute__((ext_vector_type(4)));

union F8 { short8 v; u64 q[2]; u16 u[8]; };

__device__ __forceinline__ u16 f2bf(float f) {
    union { float f; unsigned u; } c; c.f = f;
    unsigned r = c.u + 0x7FFFu + ((c.u >> 16) & 1u);
    return (u16)(r >> 16);
}

// ---------------- add + cast (QKin = bf16(src+pos), SRCB = bf16(src)) ----------------
__global__ __launch_bounds__(256) void add_cast_kernel(
        const float4* __restrict__ a, const float4* __restrict__ b,
        ushort4* __restrict__ o1, ushort4* __restrict__ o2, int n4) {
    int i = blockIdx.x * blockDim.x + threadIdx.x;
    if (i >= n4) return;
    float4 x = a[i], y = b[i];
    ushort4 u1, u2;
    u1.x = f2bf(x.x + y.x); u1.y = f2bf(x.y + y.y); u1.z = f2bf(x.z + y.z); u1.w = f2bf(x.w + y.w);
    u2.x = f2bf(x.x); u2.y = f2bf(x.y); u2.z = f2bf(x.z); u2.w = f2bf(x.w);
    o1[i] = u1; o2[i] = u2;
}

// ---------------- transpose + cast: out[c][r] = bf16(in[r][c]) ----------------
__global__ __launch_bounds__(256) void castT_kernel(
        const float* __restrict__ in, u16* __restrict__ out, int R, int C) {
    __shared__ float t[32][33];
    int c0 = blockIdx.x * 32, r0 = blockIdx.y * 32;
    int tx = threadIdx.x, ty = threadIdx.y;  // 32 x 8
    for (int i = ty; i < 32; i += 8)
        t[i][tx] = in[(long)(r0 + i) * C + c0 + tx];
    __syncthreads();
    for (int i = ty; i < 32; i += 8)
        out[(long)(c0 + i) * R + r0 + tx] = f2bf(t[tx][i]);
}

// ---------------- relative bias, transposed, bf16: BT[h][n][m] ----------------
__global__ __launch_bounds__(256) void biasT_bf16_kernel(const float* __restrict__ table,
                                                         u16* __restrict__ BT) {
    long i = (long)blockIdx.x * blockDim.x + threadIdx.x;
    const long total = (long)HEADS * NTOK * NTOK;
    if (i >= total) return;
    int m = (int)(i & 1023);
    int n = (int)((i >> 10) & 1023);
    int h = (int)(i >> 20);
    int dy = (m >> 5) - (n >> 5) + 31;
    int dx = (m & 31) - (n & 31) + 31;
    BT[i] = f2bf(table[(dy * 63 + dx) * HEADS + h]);
}

// ---------------- MFMA GEMM ----------------
// C[M x N] = A[M x K](bf16, row-major) @ B (given as Bt[N x K] bf16, row-major)
// OUTMODE bits: 1 = f32 store, 2 = bf16 store, 4 = transposed bf16 store (Ct[col][row], ldt)
template<int OUTMODE, bool HAS_BIAS, bool HAS_RES, bool GELU_>
__global__ __launch_bounds__(256) void mgemm_kernel(
        const u16* __restrict__ Ab, const u16* __restrict__ Btb,
        float* __restrict__ Cf, u16* __restrict__ Cb, u16* __restrict__ Ct,
        const float* __restrict__ bias, const float* __restrict__ Rb,
        int M, int Kd, int Nd, int lda, int ldbt, int ldc, int ldr, int ldt,
        long sAh, long sBb, long sBh, long sCb, long sCh, long sRb, long sRh, int Hb) {
    int z = blockIdx.z, bb = z / Hb, hh = z - bb * Hb;
    const u16* A  = Ab  + (long)hh * sAh;
    const u16* Bt = Btb + (long)bb * sBb + (long)hh * sBh;
    long coff = (long)bb * sCb + (long)hh * sCh;
    long roff = (long)bb * sRb + (long)hh * sRh;

    __shared__ u16 As[64][40];
    __shared__ u16 Bs[64][40];
    int tid = threadIdx.x;
    int wave = tid >> 6, lane = tid & 63, g = lane >> 4, l15 = lane & 15;
    int wm = wave >> 1, wn = wave & 1;
    int row0 = blockIdx.y * 64, col0 = blockIdx.x * 64;

    f32x4 acc[2][2] = {};

    int sr = tid >> 2, sch = tid & 3;
    const u16* aSrc = A + (long)(row0 + sr) * lda + sch * 8;
    bool bValid = (col0 + sr) < Nd;
    const u16* bSrc = Bt + (long)(col0 + sr) * ldbt + sch * 8;

    for (int k0 = 0; k0 < Kd; k0 += 32) {
        {
            uint4 va = *(const uint4*)(aSrc + k0);
            *(u64*)&As[sr][sch * 8]     = ((const u64*)&va)[0];
            *(u64*)&As[sr][sch * 8 + 4] = ((const u64*)&va)[1];
            u64 w0 = 0, w1 = 0;
            if (bValid) {
                uint4 vb = *(const uint4*)(bSrc + k0);
                w0 = ((const u64*)&vb)[0]; w1 = ((const u64*)&vb)[1];
            }
            *(u64*)&Bs[sr][sch * 8]     = w0;
            *(u64*)&Bs[sr][sch * 8 + 4] = w1;
        }
        __syncthreads();
        F8 af[2], bfr[2];
#pragma unroll
        for (int fm = 0; fm < 2; ++fm) {
            int r = wm * 32 + fm * 16 + l15;
            af[fm].q[0] = *(const u64*)&As[r][g * 8];
            af[fm].q[1] = *(const u64*)&As[r][g * 8 + 4];
        }
#pragma unroll
        for (int fn = 0; fn < 2; ++fn) {
            int c = wn * 32 + fn * 16 + l15;
            bfr[fn].q[0] = *(const u64*)&Bs[c][g * 8];
            bfr[fn].q[1] = *(const u64*)&Bs[c][g * 8 + 4];
        }
#pragma unroll
        for (int fm = 0; fm < 2; ++fm)
#pragma unroll
            for (int fn = 0; fn < 2; ++fn)
                acc[fm][fn] = __builtin_amdgcn_mfma_f32_16x16x32_bf16(
                    af[fm].v, bfr[fn].v, acc[fm][fn], 0, 0, 0);
        __syncthreads();
    }

#pragma unroll
    for (int fm = 0; fm < 2; ++fm) {
        int rbase = row0 + wm * 32 + fm * 16 + g * 4;
#pragma unroll
        for (int fn = 0; fn < 2; ++fn) {
            int c = col0 + wn * 32 + fn * 16 + l15;
            if (c < Nd) {
                float bv = HAS_BIAS ? bias[c] : 0.f;
                float vs[4];
#pragma unroll
                for (int r = 0; r < 4; ++r) {
                    float v = acc[fm][fn][r] + bv;
                    if (HAS_RES) v += Rb[roff + (long)(rbase + r) * ldr + c];
                    if (GELU_)   v = 0.5f * v * (1.f + erff(v * 0.70710678118654752f));
                    vs[r] = v;
                    if (OUTMODE & 1) Cf[coff + (long)(rbase + r) * ldc + c] = v;
                    if (OUTMODE & 2) Cb[coff + (long)(rbase + r) * ldc + c] = f2bf(v);
                }
                if (OUTMODE & 4) {
                    ushort4 o;
                    o.x = f2bf(vs[0]); o.y = f2bf(vs[1]); o.z = f2bf(vs[2]); o.w = f2bf(vs[3]);
                    *(ushort4*)&Ct[(long)c * ldt + rbase] = o;
                }
            }
        }
    }
}

// ---------------- attention, f32, two-pass, scores in LDS (known-good) ----------------
// grid (128, HEADS, BATCH), 256 threads; block handles 8 query rows.
__global__ __launch_bounds__(256) void attn_f32_kernel(
        const float* __restrict__ Q2f, const float* __restrict__ K2f,
        const float* __restrict__ V2f, u16* __restrict__ ATT) {
    int qt = blockIdx.x, h = blockIdx.y, b = blockIdx.z;
    const long base = ((long)b * NTOK) * D_MODEL + h * DIM_HEAD;
    __shared__ float qs[8][DIM_HEAD];
    __shared__ float sc[8][NTOK];
    int tid = threadIdx.x;
    int qr = tid >> 5, lane32 = tid & 31;

    for (int i = tid; i < 8 * DIM_HEAD; i += 256)
        qs[i / DIM_HEAD][i % DIM_HEAD] =
            Q2f[base + (long)(qt * 8 + i / DIM_HEAD) * D_MODEL + (i % DIM_HEAD)];
    __syncthreads();

    const float scale = 0.14433756729740643f;
    float mx = -1e30f;
    for (int m = lane32; m < NTOK; m += 32) {
        const float* kr = K2f + base + (long)m * D_MODEL;
        float a = 0.f;
#pragma unroll
        for (int d = 0; d < DIM_HEAD; ++d) a += qs[qr][d] * kr[d];
        a *= scale;
        sc[qr][m] = a;
        mx = fmaxf(mx, a);
    }
#pragma unroll
    for (int off = 16; off; off >>= 1) mx = fmaxf(mx, __shfl_xor(mx, off, 32));
    float sum = 0.f;
    for (int m = lane32; m < NTOK; m += 32) {
        float p = __expf(sc[qr][m] - mx);
        sc[qr][m] = p;
        sum += p;
    }
#pragma unroll
    for (int off = 16; off; off >>= 1) sum += __shfl_xor(sum, off, 32);
    float inv = 1.f / sum;
    __syncthreads();  // all sc[][] exp values visible to all threads

    float o0 = 0.f, o1 = 0.f;
    for (int m = 0; m < NTOK; ++m) {
        float p = sc[qr][m];
        const float* vr = V2f + base + (long)m * D_MODEL;
        o0 += p * vr[lane32];
        if (lane32 < 16) o1 += p * vr[32 + lane32];
    }
    long orow = base + (long)(qt * 8 + qr) * D_MODEL;
    ATT[orow + lane32] = f2bf(o0 * inv);
    if (lane32 < 16) ATT[orow + 32 + lane32] = f2bf(o1 * inv);
}

// ---------------- layernorm (+optional residual, optional bf16 copy) ----------------
__global__ __launch_bounds__(128) void ln_kernel(
        const float* __restrict__ X, const float* __restrict__ Rb,
        const float* __restrict__ g, const float* __restrict__ be,
        float* __restrict__ O, u16* __restrict__ Obf, int hasRes) {
    int row = blockIdx.x;
    int tid = threadIdx.x;
    const float* x = X + (long)row * D_MODEL;
    float v[3];
#pragma unroll
    for (int l = 0; l < 3; ++l) {
        int c = tid + l * 128;
        v[l] = x[c];
        if (hasRes) v[l] += Rb[(long)row * D_MODEL + c];
    }
    __shared__ float red[128];
    float s = v[0] + v[1] + v[2];
    red[tid] = s; __syncthreads();
    for (int st = 64; st > 0; st >>= 1) {
        if (tid < st) red[tid] += red[tid + st];
        __syncthreads();
    }
    float mean = red[0] * (1.f / 384.f);
    __syncthreads();
    float sq = 0.f;
#pragma unroll
    for (int l = 0; l < 3; ++l) { float d = v[l] - mean; sq += d * d; }
    red[tid] = sq; __syncthreads();
    for (int st = 64; st > 0; st >>= 1) {
        if (tid < st) red[tid] += red[tid + st];
        __syncthreads();
    }
    float rstd = rsqrtf(red[0] * (1.f / 384.f) + LN_EPS);
#pragma unroll
    for (int l = 0; l < 3; ++l) {
        int c = tid + l * 128;
        float o = (v[l] - mean) * rstd * g[c] + be[c];
        O[(long)row * D_MODEL + c] = o;
        if (Obf) Obf[(long)row * D_MODEL + c] = f2bf(o);
    }
}

extern "C" void kernel_launch(void* const* d_in, const int* in_sizes, int n_in,
                              void* d_out, int out_size, void* d_ws, size_t ws_size,
                              hipStream_t stream) {
    const float* src   = (const float*)d_in[0];
    const float* pos   = (const float*)d_in[1];
    const float* table = (const float*)d_in[2];
    const float* Wq  = (const float*)d_in[3];
    const float* Wk  = (const float*)d_in[4];
    const float* Wv  = (const float*)d_in[5];
    const float* Wo  = (const float*)d_in[6];
    const float* bo  = (const float*)d_in[7];
    const float* W1  = (const float*)d_in[8];
    const float* b1  = (const float*)d_in[9];
    const float* W2  = (const float*)d_in[10];
    const float* b2  = (const float*)d_in[11];
    const float* g1  = (const float*)d_in[12];
    const float* be1 = (const float*)d_in[13];
    const float* g2  = (const float*)d_in[14];
    const float* be2 = (const float*)d_in[15];
    float* out = (float*)d_out;

    const long SZ = (long)BATCH * NTOK * D_MODEL;  // 3,145,728 elements

    u16* WqT = (u16*)d_ws;                 // 384*384
    u16* WkT = WqT + 147456;
    u16* WvT = WkT + 147456;
    u16* WoT = WvT + 147456;
    u16* W1T = WoT + 147456;               // 1536*384
    u16* W2T = W1T + 589824;               // 384*1536
    u16* QKin = W2T + 589824;              // [8192][384] bf16
    u16* SRCB = QKin + SZ;
    float* Qf = (float*)(SRCB + SZ);       // f32 [8192][384]
    float* Kf = Qf + SZ;
    float* Vf = Kf + SZ;
    u16* Qt = (u16*)(Vf + SZ);             // bf16 [384][8192]
    u16* Kt = Qt + SZ;
    u16* Vt = Kt + SZ;
    u16* BT = Vt + SZ;                     // bf16 [8][1024][1024]
    float* Q2f = (float*)(BT + (long)HEADS * NTOK * NTOK);  // f32 [8192][384]
    float* K2f = Q2f + SZ;
    float* V2f = K2f + SZ;
    u16* ATT = (u16*)(V2f + SZ);           // bf16 [8192][384]
    // aliases (lifetimes disjoint):
    float* Of = Qf;        // pre-LN1
    float* xf = Kf;        // post-LN1 f32
    float* ff = Vf;        // pre-LN2
    u16* xbf = Qt;         // post-LN1 bf16
    u16* hbf = BT;         // FF hidden [8192][1536] bf16 (overlaps BT + Q2f head)

    // 1. adds + casts
    add_cast_kernel<<<(int)(SZ / 4 + 255) / 256, 256, 0, stream>>>(
        (const float4*)src, (const float4*)pos, (ushort4*)QKin, (ushort4*)SRCB, (int)(SZ / 4));
    // 2. weight transposes
    dim3 tb(32, 8);
    castT_kernel<<<dim3(12, 12), tb, 0, stream>>>(Wq, WqT, 384, 384);
    castT_kernel<<<dim3(12, 12), tb, 0, stream>>>(Wk, WkT, 384, 384);
    castT_kernel<<<dim3(12, 12), tb, 0, stream>>>(Wv, WvT, 384, 384);
    castT_kernel<<<dim3(12, 12), tb, 0, stream>>>(Wo, WoT, 384, 384);
    castT_kernel<<<dim3(48, 12), tb, 0, stream>>>(W1, W1T, 384, 1536);
    castT_kernel<<<dim3(12, 48), tb, 0, stream>>>(W2, W2T, 1536, 384);
    // 3. relative bias (transposed, bf16)
    biasT_bf16_kernel<<<32768, 256, 0, stream>>>(table, BT);
    // 4. projections: f32 + transposed-bf16 outputs
    mgemm_kernel<5, false, false, false><<<dim3(6, 128, 1), 256, 0, stream>>>(
        QKin, WqT, Qf, nullptr, Qt, nullptr, nullptr,
        8192, 384, 384, 384, 384, 384, 0, 8192, 0, 0, 0, 0, 0, 0, 0, 1);
    mgemm_kernel<5, false, false, false><<<dim3(6, 128, 1), 256, 0, stream>>>(
        QKin, WkT, Kf, nullptr, Kt, nullptr, nullptr,
        8192, 384, 384, 384, 384, 384, 0, 8192, 0, 0, 0, 0, 0, 0, 0, 1);
    mgemm_kernel<5, false, false, false><<<dim3(6, 128, 1), 256, 0, stream>>>(
        SRCB, WvT, Vf, nullptr, Vt, nullptr, nullptr,
        8192, 384, 384, 384, 384, 384, 0, 8192, 0, 0, 0, 0, 0, 0, 0, 1);
    // 5. x2 = x + biasT[h] @ x  per (b,h): M=1024, K=1024, N=48  -> f32 outputs
    const long NN = (long)NTOK * NTOK;
    mgemm_kernel<1, false, true, false><<<dim3(1, 16, 64), 256, 0, stream>>>(
        BT, Qt, Q2f, nullptr, nullptr, nullptr, Qf,
        1024, 1024, 48, 1024, 8192, 384, 384, 0,
        NN, 1024, (long)48 * 8192, (long)NTOK * D_MODEL, 48, (long)NTOK * D_MODEL, 48, HEADS);
    mgemm_kernel<1, false, true, false><<<dim3(1, 16, 64), 256, 0, stream>>>(
        BT, Kt, K2f, nullptr, nullptr, nullptr, Kf,
        1024, 1024, 48, 1024, 8192, 384, 384, 0,
        NN, 1024, (long)48 * 8192, (long)NTOK * D_MODEL, 48, (long)NTOK * D_MODEL, 48, HEADS);
    mgemm_kernel<1, false, true, false><<<dim3(1, 16, 64), 256, 0, stream>>>(
        BT, Vt, V2f, nullptr, nullptr, nullptr, Vf,
        1024, 1024, 48, 1024, 8192, 384, 384, 0,
        NN, 1024, (long)48 * 8192, (long)NTOK * D_MODEL, 48, (long)NTOK * D_MODEL, 48, HEADS);
    // 6. attention (f32, known-good)
    attn_f32_kernel<<<dim3(128, HEADS, BATCH), 256, 0, stream>>>(Q2f, K2f, V2f, ATT);
    // 7. o = att @ Wo + bo + src
    mgemm_kernel<1, true, true, false><<<dim3(6, 128, 1), 256, 0, stream>>>(
        ATT, WoT, Of, nullptr, nullptr, bo, src,
        8192, 384, 384, 384, 384, 384, 384, 0, 0, 0, 0, 0, 0, 0, 0, 1);
    // 8. x = LN1(o)
    ln_kernel<<<8192, 128, 0, stream>>>(Of, nullptr, g1, be1, xf, xbf, 0);
    // 9. h = gelu(x @ W1 + b1)
    mgemm_kernel<2, true, false, true><<<dim3(24, 128, 1), 256, 0, stream>>>(
        xbf, W1T, nullptr, hbf, nullptr, b1, nullptr,
        8192, 384, 1536, 384, 384, 1536, 0, 0, 0, 0, 0, 0, 0, 0, 0, 1);
    // 10. ff = h @ W2 + b2 + x
    mgemm_kernel<1, true, true, false><<<dim3(6, 128, 1), 256, 0, stream>>>(
        hbf, W2T, ff, nullptr, nullptr, b2, xf,
        8192, 1536, 384, 1536, 1536, 384, 384, 0, 0, 0, 0, 0, 0, 0, 0, 1);
    // 11. out = LN2(ff)
    ln_kernel<<<8192, 128, 0, stream>>>(ff, nullptr, g2, be2, out, nullptr, 0);
}

// Round 4
// 357.042 us; speedup vs baseline: 14.4787x; 9.9989x over previous
//
#include <hip/hip_runtime.h>
#include <math.h>

#define D_MODEL 384
#define HEADS 8
#define DIM_HEAD 48
#define NTOK 1024
#define BATCH 8
#define D_FF 1536
#define LN_EPS 1e-5f

typedef unsigned short u16;
typedef unsigned long long u64;
typedef short short8 __attribute__((ext_vector_type(8)));
typedef float f32x4 __attribute__((ext_vector_type(4)));

union F8 { short8 v; u64 q[2]; u16 u[8]; };

__device__ __forceinline__ u16 f2bf(float f) {
    union { float f; unsigned u; } c; c.f = f;
    unsigned r = c.u + 0x7FFFu + ((c.u >> 16) & 1u);
    return (u16)(r >> 16);
}

// ---------------- add + cast (QKin = bf16(src+pos), SRCB = bf16(src)) ----------------
__global__ __launch_bounds__(256) void add_cast_kernel(
        const float4* __restrict__ a, const float4* __restrict__ b,
        ushort4* __restrict__ o1, ushort4* __restrict__ o2, int n4) {
    int i = blockIdx.x * blockDim.x + threadIdx.x;
    if (i >= n4) return;
    float4 x = a[i], y = b[i];
    ushort4 u1, u2;
    u1.x = f2bf(x.x + y.x); u1.y = f2bf(x.y + y.y); u1.z = f2bf(x.z + y.z); u1.w = f2bf(x.w + y.w);
    u2.x = f2bf(x.x); u2.y = f2bf(x.y); u2.z = f2bf(x.z); u2.w = f2bf(x.w);
    o1[i] = u1; o2[i] = u2;
}

// ---------------- transpose + cast: out[c][r] = bf16(in[r][c]) ----------------
__global__ __launch_bounds__(256) void castT_kernel(
        const float* __restrict__ in, u16* __restrict__ out, int R, int C) {
    __shared__ float t[32][33];
    int c0 = blockIdx.x * 32, r0 = blockIdx.y * 32;
    int tx = threadIdx.x, ty = threadIdx.y;  // 32 x 8
    for (int i = ty; i < 32; i += 8)
        t[i][tx] = in[(long)(r0 + i) * C + c0 + tx];
    __syncthreads();
    for (int i = ty; i < 32; i += 8)
        out[(long)(c0 + i) * R + r0 + tx] = f2bf(t[tx][i]);
}

// ---------------- relative bias, transposed, bf16: BT[h][n][m] ----------------
__global__ __launch_bounds__(256) void biasT_bf16_kernel(const float* __restrict__ table,
                                                         u16* __restrict__ BT) {
    long i = (long)blockIdx.x * blockDim.x + threadIdx.x;
    const long total = (long)HEADS * NTOK * NTOK;
    if (i >= total) return;
    int m = (int)(i & 1023);
    int n = (int)((i >> 10) & 1023);
    int h = (int)(i >> 20);
    int dy = (m >> 5) - (n >> 5) + 31;
    int dx = (m & 31) - (n & 31) + 31;
    BT[i] = f2bf(table[(dy * 63 + dx) * HEADS + h]);
}

// ---------------- MFMA GEMM ----------------
// C[M x N] = A[M x K](bf16, row-major) @ B (given as Bt[N x K] bf16, row-major)
// OUTMODE bits: 1 = f32 store, 2 = bf16 store, 4 = transposed bf16 store (Ct[col][row], ldt)
template<int OUTMODE, bool HAS_BIAS, bool HAS_RES, bool GELU_>
__global__ __launch_bounds__(256) void mgemm_kernel(
        const u16* __restrict__ Ab, const u16* __restrict__ Btb,
        float* __restrict__ Cf, u16* __restrict__ Cb, u16* __restrict__ Ct,
        const float* __restrict__ bias, const float* __restrict__ Rb,
        int M, int Kd, int Nd, int lda, int ldbt, int ldc, int ldr, int ldt,
        long sAh, long sBb, long sBh, long sCb, long sCh, long sRb, long sRh, int Hb) {
    int z = blockIdx.z, bb = z / Hb, hh = z - bb * Hb;
    const u16* A  = Ab  + (long)hh * sAh;
    const u16* Bt = Btb + (long)bb * sBb + (long)hh * sBh;
    long coff = (long)bb * sCb + (long)hh * sCh;
    long roff = (long)bb * sRb + (long)hh * sRh;

    __shared__ u16 As[64][40];
    __shared__ u16 Bs[64][40];
    int tid = threadIdx.x;
    int wave = tid >> 6, lane = tid & 63, g = lane >> 4, l15 = lane & 15;
    int wm = wave >> 1, wn = wave & 1;
    int row0 = blockIdx.y * 64, col0 = blockIdx.x * 64;

    f32x4 acc[2][2] = {};

    int sr = tid >> 2, sch = tid & 3;
    const u16* aSrc = A + (long)(row0 + sr) * lda + sch * 8;
    bool bValid = (col0 + sr) < Nd;
    const u16* bSrc = Bt + (long)(col0 + sr) * ldbt + sch * 8;

    for (int k0 = 0; k0 < Kd; k0 += 32) {
        {
            uint4 va = *(const uint4*)(aSrc + k0);
            *(u64*)&As[sr][sch * 8]     = ((const u64*)&va)[0];
            *(u64*)&As[sr][sch * 8 + 4] = ((const u64*)&va)[1];
            u64 w0 = 0, w1 = 0;
            if (bValid) {
                uint4 vb = *(const uint4*)(bSrc + k0);
                w0 = ((const u64*)&vb)[0]; w1 = ((const u64*)&vb)[1];
            }
            *(u64*)&Bs[sr][sch * 8]     = w0;
            *(u64*)&Bs[sr][sch * 8 + 4] = w1;
        }
        __syncthreads();
        F8 af[2], bfr[2];
#pragma unroll
        for (int fm = 0; fm < 2; ++fm) {
            int r = wm * 32 + fm * 16 + l15;
            af[fm].q[0] = *(const u64*)&As[r][g * 8];
            af[fm].q[1] = *(const u64*)&As[r][g * 8 + 4];
        }
#pragma unroll
        for (int fn = 0; fn < 2; ++fn) {
            int c = wn * 32 + fn * 16 + l15;
            bfr[fn].q[0] = *(const u64*)&Bs[c][g * 8];
            bfr[fn].q[1] = *(const u64*)&Bs[c][g * 8 + 4];
        }
#pragma unroll
        for (int fm = 0; fm < 2; ++fm)
#pragma unroll
            for (int fn = 0; fn < 2; ++fn)
                acc[fm][fn] = __builtin_amdgcn_mfma_f32_16x16x32_bf16(
                    af[fm].v, bfr[fn].v, acc[fm][fn], 0, 0, 0);
        __syncthreads();
    }

#pragma unroll
    for (int fm = 0; fm < 2; ++fm) {
        int rbase = row0 + wm * 32 + fm * 16 + g * 4;
#pragma unroll
        for (int fn = 0; fn < 2; ++fn) {
            int c = col0 + wn * 32 + fn * 16 + l15;
            if (c < Nd) {
                float bv = HAS_BIAS ? bias[c] : 0.f;
                float vs[4];
#pragma unroll
                for (int r = 0; r < 4; ++r) {
                    float v = acc[fm][fn][r] + bv;
                    if (HAS_RES) v += Rb[roff + (long)(rbase + r) * ldr + c];
                    if (GELU_)   v = 0.5f * v * (1.f + erff(v * 0.70710678118654752f));
                    vs[r] = v;
                    if (OUTMODE & 1) Cf[coff + (long)(rbase + r) * ldc + c] = v;
                    if (OUTMODE & 2) Cb[coff + (long)(rbase + r) * ldc + c] = f2bf(v);
                }
                if (OUTMODE & 4) {
                    ushort4 o;
                    o.x = f2bf(vs[0]); o.y = f2bf(vs[1]); o.z = f2bf(vs[2]); o.w = f2bf(vs[3]);
                    *(ushort4*)&Ct[(long)c * ldt + rbase] = o;
                }
            }
        }
    }
}

// ---------------- flash attention, MFMA, bf16 ----------------
// grid (16 qblocks, HEADS, BATCH), 256 threads = 4 waves x 16 q-rows.
// S^T = mfma(A=K, B=Q)  -> lane-local softmax (query = lane&15, keys across g),
// P via per-wave LDS, O^T = mfma(A=V^T, B=P^T).
__global__ __launch_bounds__(256) void attn_mfma_kernel(
        const u16* __restrict__ Q2, const u16* __restrict__ K2,
        const u16* __restrict__ V2, u16* __restrict__ O) {
    int qb = blockIdx.x, h = blockIdx.y, b = blockIdx.z;
    int tid = threadIdx.x, wave = tid >> 6, lane = tid & 63, g = lane >> 4, l15 = lane & 15;
    const long rowbase = (long)b * NTOK;
    const int colbase = h * DIM_HEAD;

    __shared__ u16 Vt[48][36];       // V^T tile: [d][m]
    __shared__ u16 Pl[4][16][40];    // per-wave P: [n][m]

    const u16* qptr = Q2 + (rowbase + qb * 64 + wave * 16 + l15) * D_MODEL + colbase;
    F8 qf[2];
    qf[0].q[0] = *(const u64*)(qptr + g * 8);
    qf[0].q[1] = *(const u64*)(qptr + g * 8 + 4);
    if (g < 2) {
        qf[1].q[0] = *(const u64*)(qptr + 32 + g * 8);
        qf[1].q[1] = *(const u64*)(qptr + 32 + g * 8 + 4);
    } else { qf[1].q[0] = 0; qf[1].q[1] = 0; }

    f32x4 oacc[3] = {};
    float runm = -1e30f, runl = 0.f;
    const float sc = 0.14433756729740643f;  // 48^-0.5

    for (int m0 = 0; m0 < NTOK; m0 += 32) {
        __syncthreads();  // previous Vt fully consumed
        for (int idx = tid; idx < 12 * 32; idx += 256) {
            int mi = idx & 31, d0 = (idx >> 5) * 4;
            const u16* vp = V2 + (rowbase + m0 + mi) * D_MODEL + colbase + d0;
            ushort4 vv = *(const ushort4*)vp;
            Vt[d0][mi] = vv.x; Vt[d0 + 1][mi] = vv.y; Vt[d0 + 2][mi] = vv.z; Vt[d0 + 3][mi] = vv.w;
        }
        __syncthreads();

        f32x4 s[2] = {};
#pragma unroll
        for (int mt = 0; mt < 2; ++mt) {
            const u16* kp = K2 + (rowbase + m0 + mt * 16 + l15) * D_MODEL + colbase;
            F8 kf0, kf1;
            kf0.q[0] = *(const u64*)(kp + g * 8);
            kf0.q[1] = *(const u64*)(kp + g * 8 + 4);
            if (g < 2) {
                kf1.q[0] = *(const u64*)(kp + 32 + g * 8);
                kf1.q[1] = *(const u64*)(kp + 32 + g * 8 + 4);
            } else { kf1.q[0] = 0; kf1.q[1] = 0; }
            s[mt] = __builtin_amdgcn_mfma_f32_16x16x32_bf16(kf0.v, qf[0].v, s[mt], 0, 0, 0);
            s[mt] = __builtin_amdgcn_mfma_f32_16x16x32_bf16(kf1.v, qf[1].v, s[mt], 0, 0, 0);
        }

        float p[8];
        float tmax = -1e30f;
#pragma unroll
        for (int i = 0; i < 8; ++i) {
            float v = s[i >> 2][i & 3] * sc;
            p[i] = v; tmax = fmaxf(tmax, v);
        }
        tmax = fmaxf(tmax, __shfl_xor(tmax, 16));
        tmax = fmaxf(tmax, __shfl_xor(tmax, 32));
        float nm = fmaxf(runm, tmax);
        float corr = __expf(runm - nm);
        runm = nm;
        float ps = 0.f;
#pragma unroll
        for (int i = 0; i < 8; ++i) { p[i] = __expf(p[i] - nm); ps += p[i]; }
        ps += __shfl_xor(ps, 16);
        ps += __shfl_xor(ps, 32);
        runl = runl * corr + ps;
#pragma unroll
        for (int dt = 0; dt < 3; ++dt) {
            oacc[dt][0] *= corr; oacc[dt][1] *= corr;
            oacc[dt][2] *= corr; oacc[dt][3] *= corr;
        }
#pragma unroll
        for (int mt = 0; mt < 2; ++mt) {
            ushort4 pk;
            pk.x = f2bf(p[mt * 4]); pk.y = f2bf(p[mt * 4 + 1]);
            pk.z = f2bf(p[mt * 4 + 2]); pk.w = f2bf(p[mt * 4 + 3]);
            *(ushort4*)&Pl[wave][l15][mt * 16 + g * 4] = pk;
        }
        // ensure the per-wave P LDS writes are complete & ordered before fragment reads
        asm volatile("s_waitcnt lgkmcnt(0)" ::: "memory");
        __builtin_amdgcn_sched_barrier(0);
        F8 pb;
        pb.q[0] = *(const u64*)&Pl[wave][l15][g * 8];
        pb.q[1] = *(const u64*)&Pl[wave][l15][g * 8 + 4];
#pragma unroll
        for (int dt = 0; dt < 3; ++dt) {
            F8 vf;
            vf.q[0] = *(const u64*)&Vt[dt * 16 + l15][g * 8];
            vf.q[1] = *(const u64*)&Vt[dt * 16 + l15][g * 8 + 4];
            oacc[dt] = __builtin_amdgcn_mfma_f32_16x16x32_bf16(vf.v, pb.v, oacc[dt], 0, 0, 0);
        }
    }

    float inv = 1.f / runl;
    u16* op = O + (rowbase + qb * 64 + wave * 16 + l15) * D_MODEL + colbase;
#pragma unroll
    for (int dt = 0; dt < 3; ++dt) {
        ushort4 o;
        o.x = f2bf(oacc[dt][0] * inv); o.y = f2bf(oacc[dt][1] * inv);
        o.z = f2bf(oacc[dt][2] * inv); o.w = f2bf(oacc[dt][3] * inv);
        *(ushort4*)(op + dt * 16 + g * 4) = o;
    }
}

// ---------------- layernorm (+optional residual, optional bf16 copy) ----------------
__global__ __launch_bounds__(128) void ln_kernel(
        const float* __restrict__ X, const float* __restrict__ Rb,
        const float* __restrict__ g, const float* __restrict__ be,
        float* __restrict__ O, u16* __restrict__ Obf, int hasRes) {
    int row = blockIdx.x;
    int tid = threadIdx.x;
    const float* x = X + (long)row * D_MODEL;
    float v[3];
#pragma unroll
    for (int l = 0; l < 3; ++l) {
        int c = tid + l * 128;
        v[l] = x[c];
        if (hasRes) v[l] += Rb[(long)row * D_MODEL + c];
    }
    __shared__ float red[128];
    float s = v[0] + v[1] + v[2];
    red[tid] = s; __syncthreads();
    for (int st = 64; st > 0; st >>= 1) {
        if (tid < st) red[tid] += red[tid + st];
        __syncthreads();
    }
    float mean = red[0] * (1.f / 384.f);
    __syncthreads();
    float sq = 0.f;
#pragma unroll
    for (int l = 0; l < 3; ++l) { float d = v[l] - mean; sq += d * d; }
    red[tid] = sq; __syncthreads();
    for (int st = 64; st > 0; st >>= 1) {
        if (tid < st) red[tid] += red[tid + st];
        __syncthreads();
    }
    float rstd = rsqrtf(red[0] * (1.f / 384.f) + LN_EPS);
#pragma unroll
    for (int l = 0; l < 3; ++l) {
        int c = tid + l * 128;
        float o = (v[l] - mean) * rstd * g[c] + be[c];
        O[(long)row * D_MODEL + c] = o;
        if (Obf) Obf[(long)row * D_MODEL + c] = f2bf(o);
    }
}

extern "C" void kernel_launch(void* const* d_in, const int* in_sizes, int n_in,
                              void* d_out, int out_size, void* d_ws, size_t ws_size,
                              hipStream_t stream) {
    const float* src   = (const float*)d_in[0];
    const float* pos   = (const float*)d_in[1];
    const float* table = (const float*)d_in[2];
    const float* Wq  = (const float*)d_in[3];
    const float* Wk  = (const float*)d_in[4];
    const float* Wv  = (const float*)d_in[5];
    const float* Wo  = (const float*)d_in[6];
    const float* bo  = (const float*)d_in[7];
    const float* W1  = (const float*)d_in[8];
    const float* b1  = (const float*)d_in[9];
    const float* W2  = (const float*)d_in[10];
    const float* b2  = (const float*)d_in[11];
    const float* g1  = (const float*)d_in[12];
    const float* be1 = (const float*)d_in[13];
    const float* g2  = (const float*)d_in[14];
    const float* be2 = (const float*)d_in[15];
    float* out = (float*)d_out;

    const long SZ = (long)BATCH * NTOK * D_MODEL;  // 3,145,728 elements

    u16* WqT = (u16*)d_ws;                 // 384*384
    u16* WkT = WqT + 147456;
    u16* WvT = WkT + 147456;
    u16* WoT = WvT + 147456;
    u16* W1T = WoT + 147456;               // 1536*384
    u16* W2T = W1T + 589824;               // 384*1536
    u16* QKin = W2T + 589824;              // [8192][384] bf16
    u16* SRCB = QKin + SZ;
    float* Qf = (float*)(SRCB + SZ);       // f32 [8192][384]
    float* Kf = Qf + SZ;
    float* Vf = Kf + SZ;
    u16* Qt = (u16*)(Vf + SZ);             // bf16 [384][8192]
    u16* Kt = Qt + SZ;
    u16* Vt = Kt + SZ;
    u16* BT = Vt + SZ;                     // bf16 [8][1024][1024]
    u16* Q2 = BT + (long)HEADS * NTOK * NTOK;
    u16* K2 = Q2 + SZ;
    u16* V2 = K2 + SZ;
    u16* ATT = V2 + SZ;
    // aliases (lifetimes disjoint):
    float* Of = Qf;        // pre-LN1
    float* xf = Kf;        // post-LN1 f32
    float* ff = Vf;        // pre-LN2
    u16* xbf = Qt;         // post-LN1 bf16
    u16* hbf = BT;         // FF hidden [8192][1536] bf16 (overlaps BT+Q2+K2; dead by then)

    // 1. adds + casts
    add_cast_kernel<<<(int)(SZ / 4 + 255) / 256, 256, 0, stream>>>(
        (const float4*)src, (const float4*)pos, (ushort4*)QKin, (ushort4*)SRCB, (int)(SZ / 4));
    // 2. weight transposes
    dim3 tb(32, 8);
    castT_kernel<<<dim3(12, 12), tb, 0, stream>>>(Wq, WqT, 384, 384);
    castT_kernel<<<dim3(12, 12), tb, 0, stream>>>(Wk, WkT, 384, 384);
    castT_kernel<<<dim3(12, 12), tb, 0, stream>>>(Wv, WvT, 384, 384);
    castT_kernel<<<dim3(12, 12), tb, 0, stream>>>(Wo, WoT, 384, 384);
    castT_kernel<<<dim3(48, 12), tb, 0, stream>>>(W1, W1T, 384, 1536);
    castT_kernel<<<dim3(12, 48), tb, 0, stream>>>(W2, W2T, 1536, 384);
    // 3. relative bias (transposed, bf16)
    biasT_bf16_kernel<<<32768, 256, 0, stream>>>(table, BT);
    // 4. projections: f32 + transposed-bf16 outputs
    mgemm_kernel<5, false, false, false><<<dim3(6, 128, 1), 256, 0, stream>>>(
        QKin, WqT, Qf, nullptr, Qt, nullptr, nullptr,
        8192, 384, 384, 384, 384, 384, 0, 8192, 0, 0, 0, 0, 0, 0, 0, 1);
    mgemm_kernel<5, false, false, false><<<dim3(6, 128, 1), 256, 0, stream>>>(
        QKin, WkT, Kf, nullptr, Kt, nullptr, nullptr,
        8192, 384, 384, 384, 384, 384, 0, 8192, 0, 0, 0, 0, 0, 0, 0, 1);
    mgemm_kernel<5, false, false, false><<<dim3(6, 128, 1), 256, 0, stream>>>(
        SRCB, WvT, Vf, nullptr, Vt, nullptr, nullptr,
        8192, 384, 384, 384, 384, 384, 0, 8192, 0, 0, 0, 0, 0, 0, 0, 1);
    // 5. x2 = x + biasT[h] @ x  per (b,h): M=1024, K=1024, N=48 -> bf16 outputs
    const long NN = (long)NTOK * NTOK;
    mgemm_kernel<2, false, true, false><<<dim3(1, 16, 64), 256, 0, stream>>>(
        BT, Qt, nullptr, Q2, nullptr, nullptr, Qf,
        1024, 1024, 48, 1024, 8192, 384, 384, 0,
        NN, 1024, (long)48 * 8192, (long)NTOK * D_MODEL, 48, (long)NTOK * D_MODEL, 48, HEADS);
    mgemm_kernel<2, false, true, false><<<dim3(1, 16, 64), 256, 0, stream>>>(
        BT, Kt, nullptr, K2, nullptr, nullptr, Kf,
        1024, 1024, 48, 1024, 8192, 384, 384, 0,
        NN, 1024, (long)48 * 8192, (long)NTOK * D_MODEL, 48, (long)NTOK * D_MODEL, 48, HEADS);
    mgemm_kernel<2, false, true, false><<<dim3(1, 16, 64), 256, 0, stream>>>(
        BT, Vt, nullptr, V2, nullptr, nullptr, Vf,
        1024, 1024, 48, 1024, 8192, 384, 384, 0,
        NN, 1024, (long)48 * 8192, (long)NTOK * D_MODEL, 48, (long)NTOK * D_MODEL, 48, HEADS);
    // 6. attention (MFMA flash)
    attn_mfma_kernel<<<dim3(16, HEADS, BATCH), 256, 0, stream>>>(Q2, K2, V2, ATT);
    // 7. o = att @ Wo + bo + src
    mgemm_kernel<1, true, true, false><<<dim3(6, 128, 1), 256, 0, stream>>>(
        ATT, WoT, Of, nullptr, nullptr, bo, src,
        8192, 384, 384, 384, 384, 384, 384, 0, 0, 0, 0, 0, 0, 0, 0, 1);
    // 8. x = LN1(o)
    ln_kernel<<<8192, 128, 0, stream>>>(Of, nullptr, g1, be1, xf, xbf, 0);
    // 9. h = gelu(x @ W1 + b1)
    mgemm_kernel<2, true, false, true><<<dim3(24, 128, 1), 256, 0, stream>>>(
        xbf, W1T, nullptr, hbf, nullptr, b1, nullptr,
        8192, 384, 1536, 384, 384, 1536, 0, 0, 0, 0, 0, 0, 0, 0, 0, 1);
    // 10. ff = h @ W2 + b2 + x   (ldbt = 1536 — W2T is [384][1536]; R2's bug was 384 here)
    mgemm_kernel<1, true, true, false><<<dim3(6, 128, 1), 256, 0, stream>>>(
        hbf, W2T, ff, nullptr, nullptr, b2, xf,
        8192, 1536, 384, 1536, 1536, 384, 384, 0, 0, 0, 0, 0, 0, 0, 0, 1);
    // 11. out = LN2(ff)
    ln_kernel<<<8192, 128, 0, stream>>>(ff, nullptr, g2, be2, out, nullptr, 0);
}

// Round 5
// 305.310 us; speedup vs baseline: 16.9320x; 1.1694x over previous
//
#include <hip/hip_runtime.h>
#include <math.h>

#define D_MODEL 384
#define HEADS 8
#define DIM_HEAD 48
#define NTOK 1024
#define BATCH 8
#define D_FF 1536
#define LN_EPS 1e-5f

typedef unsigned short u16;
typedef unsigned int u32;
typedef unsigned long long u64;
typedef short short8 __attribute__((ext_vector_type(8)));
typedef float f32x4 __attribute__((ext_vector_type(4)));

union F8 { short8 v; u64 q[2]; u16 u[8]; };

__device__ __forceinline__ u16 f2bf(float f) {
    union { float f; unsigned u; } c; c.f = f;
    unsigned r = c.u + 0x7FFFu + ((c.u >> 16) & 1u);
    return (u16)(r >> 16);
}
__device__ __forceinline__ float bf2f(u16 u) {
    union { unsigned u; float f; } c; c.u = ((unsigned)u) << 16; return c.f;
}

// ---------------- add + cast (QKin = bf16(src+pos), SRCB = bf16(src)) ----------------
__global__ __launch_bounds__(256) void add_cast_kernel(
        const float4* __restrict__ a, const float4* __restrict__ b,
        ushort4* __restrict__ o1, ushort4* __restrict__ o2, int n4) {
    int i = blockIdx.x * blockDim.x + threadIdx.x;
    if (i >= n4) return;
    float4 x = a[i], y = b[i];
    ushort4 u1, u2;
    u1.x = f2bf(x.x + y.x); u1.y = f2bf(x.y + y.y); u1.z = f2bf(x.z + y.z); u1.w = f2bf(x.w + y.w);
    u2.x = f2bf(x.x); u2.y = f2bf(x.y); u2.z = f2bf(x.z); u2.w = f2bf(x.w);
    o1[i] = u1; o2[i] = u2;
}

// ---------------- transpose + cast: out[c][r] = bf16(in[r][c]) ----------------
__global__ __launch_bounds__(256) void castT_kernel(
        const float* __restrict__ in, u16* __restrict__ out, int R, int C) {
    __shared__ float t[32][33];
    int c0 = blockIdx.x * 32, r0 = blockIdx.y * 32;
    int tx = threadIdx.x, ty = threadIdx.y;  // 32 x 8
    for (int i = ty; i < 32; i += 8)
        t[i][tx] = in[(long)(r0 + i) * C + c0 + tx];
    __syncthreads();
    for (int i = ty; i < 32; i += 8)
        out[(long)(c0 + i) * R + r0 + tx] = f2bf(t[tx][i]);
}

// ---------------- relative bias, transposed, bf16: BT[h][n][m] = bias[h][m][n] ----------------
__global__ __launch_bounds__(256) void biasT_bf16_kernel(const float* __restrict__ table,
                                                         u16* __restrict__ BT) {
    long i = (long)blockIdx.x * blockDim.x + threadIdx.x;
    const long total = (long)HEADS * NTOK * NTOK;
    if (i >= total) return;
    int m = (int)(i & 1023);
    int n = (int)((i >> 10) & 1023);
    int h = (int)(i >> 20);
    int dy = (m >> 5) - (n >> 5) + 31;
    int dx = (m & 31) - (n & 31) + 31;
    BT[i] = f2bf(table[(dy * 63 + dx) * HEADS + h]);
}

// ---------------- MFMA GEMM ----------------
// C[M x N] = A[M x K](bf16, row-major) @ B (given as Bt[N x K] bf16, row-major)
// OUTMODE bits: 1 = f32 store, 2 = bf16 store, 8 = head-transposed bf16 store
//   (Ct[h][b*48+d][m] where h=c/48, d=c%48, b=row>>10, m=row&1023)
template<int OUTMODE, bool HAS_BIAS, bool HAS_RES, bool GELU_>
__global__ __launch_bounds__(256) void mgemm_kernel(
        const u16* __restrict__ Ab, const u16* __restrict__ Btb,
        float* __restrict__ Cf, u16* __restrict__ Cb, u16* __restrict__ Ct,
        const float* __restrict__ bias, const float* __restrict__ Rb,
        int M, int Kd, int Nd, int lda, int ldbt, int ldc, int ldr) {
    const u16* A  = Ab;
    const u16* Bt = Btb;

    __shared__ u16 As[64][40];
    __shared__ u16 Bs[64][40];
    int tid = threadIdx.x;
    int wave = tid >> 6, lane = tid & 63, g = lane >> 4, l15 = lane & 15;
    int wm = wave >> 1, wn = wave & 1;
    int row0 = blockIdx.y * 64, col0 = blockIdx.x * 64;

    f32x4 acc[2][2] = {};

    int sr = tid >> 2, sch = tid & 3;
    const u16* aSrc = A + (long)(row0 + sr) * lda + sch * 8;
    const u16* bSrc = Bt + (long)(col0 + sr) * ldbt + sch * 8;

    for (int k0 = 0; k0 < Kd; k0 += 32) {
        {
            uint4 va = *(const uint4*)(aSrc + k0);
            uint4 vb = *(const uint4*)(bSrc + k0);
            *(u64*)&As[sr][sch * 8]     = ((const u64*)&va)[0];
            *(u64*)&As[sr][sch * 8 + 4] = ((const u64*)&va)[1];
            *(u64*)&Bs[sr][sch * 8]     = ((const u64*)&vb)[0];
            *(u64*)&Bs[sr][sch * 8 + 4] = ((const u64*)&vb)[1];
        }
        __syncthreads();
        F8 af[2], bfr[2];
#pragma unroll
        for (int fm = 0; fm < 2; ++fm) {
            int r = wm * 32 + fm * 16 + l15;
            af[fm].q[0] = *(const u64*)&As[r][g * 8];
            af[fm].q[1] = *(const u64*)&As[r][g * 8 + 4];
        }
#pragma unroll
        for (int fn = 0; fn < 2; ++fn) {
            int c = wn * 32 + fn * 16 + l15;
            bfr[fn].q[0] = *(const u64*)&Bs[c][g * 8];
            bfr[fn].q[1] = *(const u64*)&Bs[c][g * 8 + 4];
        }
#pragma unroll
        for (int fm = 0; fm < 2; ++fm)
#pragma unroll
            for (int fn = 0; fn < 2; ++fn)
                acc[fm][fn] = __builtin_amdgcn_mfma_f32_16x16x32_bf16(
                    af[fm].v, bfr[fn].v, acc[fm][fn], 0, 0, 0);
        __syncthreads();
    }

#pragma unroll
    for (int fm = 0; fm < 2; ++fm) {
        int rbase = row0 + wm * 32 + fm * 16 + g * 4;
#pragma unroll
        for (int fn = 0; fn < 2; ++fn) {
            int c = col0 + wn * 32 + fn * 16 + l15;
            if (c < Nd) {
                float bv = HAS_BIAS ? bias[c] : 0.f;
                float vs[4];
#pragma unroll
                for (int r = 0; r < 4; ++r) {
                    float v = acc[fm][fn][r] + bv;
                    if (HAS_RES) v += Rb[(long)(rbase + r) * ldr + c];
                    if (GELU_)   v = 0.5f * v * (1.f + erff(v * 0.70710678118654752f));
                    vs[r] = v;
                    if (OUTMODE & 1) Cf[(long)(rbase + r) * ldc + c] = v;
                    if (OUTMODE & 2) Cb[(long)(rbase + r) * ldc + c] = f2bf(v);
                }
                if (OUTMODE & 8) {
                    int hh2 = (c * 683) >> 15; int dd = c - hh2 * 48;
                    int bb2 = rbase >> 10;     int mm = rbase & 1023;
                    ushort4 o;
                    o.x = f2bf(vs[0]); o.y = f2bf(vs[1]); o.z = f2bf(vs[2]); o.w = f2bf(vs[3]);
                    *(ushort4*)&Ct[(long)hh2 * 393216 + (long)(bb2 * 48 + dd) * 1024 + mm] = o;
                }
            }
        }
    }
}

// ---------------- fused bias matmuls: {Q2,K2,V2T} = X + BT[h] @ X for X in {Q,K,V} ----------------
// grid (6 colblocks, 16 rowblocks, 8 heads), 256 threads.
// A = BT[h] [1024][1024]; B-operands = XtH[h] [384=b*48+d][1024=m]; residual = same XtH.
// Outputs: Q2,K2 std [b][n][h*48+d] bf16 (Q pre-scaled by 48^-0.5); V2T head-major [h][b*48+d][n].
__global__ __launch_bounds__(256) void bias3_kernel(
        const u16* __restrict__ BT, const u16* __restrict__ QtH,
        const u16* __restrict__ KtH, const u16* __restrict__ VtH,
        u16* __restrict__ Q2, u16* __restrict__ K2, u16* __restrict__ V2T) {
    int h = blockIdx.z;
    const long hb = (long)h * 393216;
    const u16* A = BT + (long)h * 1048576;
    __shared__ u16 As[64][40];
    __shared__ u16 Bq[64][40], Bk[64][40], Bv[64][40];
    int tid = threadIdx.x, wave = tid >> 6, lane = tid & 63, g = lane >> 4, l15 = lane & 15;
    int wm = wave >> 1, wn = wave & 1;
    int row0 = blockIdx.y * 64, col0 = blockIdx.x * 64;
    f32x4 acc[3][2][2] = {};
    int sr = tid >> 2, sch = tid & 3;
    const u16* aSrc = A   + (long)(row0 + sr) * 1024 + sch * 8;
    const u16* qSrc = QtH + hb + (long)(col0 + sr) * 1024 + sch * 8;
    const u16* kSrc = KtH + hb + (long)(col0 + sr) * 1024 + sch * 8;
    const u16* vSrc = VtH + hb + (long)(col0 + sr) * 1024 + sch * 8;

    for (int k0 = 0; k0 < 1024; k0 += 32) {
        uint4 va = *(const uint4*)(aSrc + k0);
        uint4 vq = *(const uint4*)(qSrc + k0);
        uint4 vk = *(const uint4*)(kSrc + k0);
        uint4 vv = *(const uint4*)(vSrc + k0);
        *(u64*)&As[sr][sch * 8] = ((const u64*)&va)[0]; *(u64*)&As[sr][sch * 8 + 4] = ((const u64*)&va)[1];
        *(u64*)&Bq[sr][sch * 8] = ((const u64*)&vq)[0]; *(u64*)&Bq[sr][sch * 8 + 4] = ((const u64*)&vq)[1];
        *(u64*)&Bk[sr][sch * 8] = ((const u64*)&vk)[0]; *(u64*)&Bk[sr][sch * 8 + 4] = ((const u64*)&vk)[1];
        *(u64*)&Bv[sr][sch * 8] = ((const u64*)&vv)[0]; *(u64*)&Bv[sr][sch * 8 + 4] = ((const u64*)&vv)[1];
        __syncthreads();
        F8 af0, af1, b0, b1;
        af0.q[0] = *(const u64*)&As[wm * 32 + l15][g * 8];
        af0.q[1] = *(const u64*)&As[wm * 32 + l15][g * 8 + 4];
        af1.q[0] = *(const u64*)&As[wm * 32 + 16 + l15][g * 8];
        af1.q[1] = *(const u64*)&As[wm * 32 + 16 + l15][g * 8 + 4];
        // Q
        b0.q[0] = *(const u64*)&Bq[wn * 32 + l15][g * 8];
        b0.q[1] = *(const u64*)&Bq[wn * 32 + l15][g * 8 + 4];
        b1.q[0] = *(const u64*)&Bq[wn * 32 + 16 + l15][g * 8];
        b1.q[1] = *(const u64*)&Bq[wn * 32 + 16 + l15][g * 8 + 4];
        acc[0][0][0] = __builtin_amdgcn_mfma_f32_16x16x32_bf16(af0.v, b0.v, acc[0][0][0], 0, 0, 0);
        acc[0][0][1] = __builtin_amdgcn_mfma_f32_16x16x32_bf16(af0.v, b1.v, acc[0][0][1], 0, 0, 0);
        acc[0][1][0] = __builtin_amdgcn_mfma_f32_16x16x32_bf16(af1.v, b0.v, acc[0][1][0], 0, 0, 0);
        acc[0][1][1] = __builtin_amdgcn_mfma_f32_16x16x32_bf16(af1.v, b1.v, acc[0][1][1], 0, 0, 0);
        // K
        b0.q[0] = *(const u64*)&Bk[wn * 32 + l15][g * 8];
        b0.q[1] = *(const u64*)&Bk[wn * 32 + l15][g * 8 + 4];
        b1.q[0] = *(const u64*)&Bk[wn * 32 + 16 + l15][g * 8];
        b1.q[1] = *(const u64*)&Bk[wn * 32 + 16 + l15][g * 8 + 4];
        acc[1][0][0] = __builtin_amdgcn_mfma_f32_16x16x32_bf16(af0.v, b0.v, acc[1][0][0], 0, 0, 0);
        acc[1][0][1] = __builtin_amdgcn_mfma_f32_16x16x32_bf16(af0.v, b1.v, acc[1][0][1], 0, 0, 0);
        acc[1][1][0] = __builtin_amdgcn_mfma_f32_16x16x32_bf16(af1.v, b0.v, acc[1][1][0], 0, 0, 0);
        acc[1][1][1] = __builtin_amdgcn_mfma_f32_16x16x32_bf16(af1.v, b1.v, acc[1][1][1], 0, 0, 0);
        // V
        b0.q[0] = *(const u64*)&Bv[wn * 32 + l15][g * 8];
        b0.q[1] = *(const u64*)&Bv[wn * 32 + l15][g * 8 + 4];
        b1.q[0] = *(const u64*)&Bv[wn * 32 + 16 + l15][g * 8];
        b1.q[1] = *(const u64*)&Bv[wn * 32 + 16 + l15][g * 8 + 4];
        acc[2][0][0] = __builtin_amdgcn_mfma_f32_16x16x32_bf16(af0.v, b0.v, acc[2][0][0], 0, 0, 0);
        acc[2][0][1] = __builtin_amdgcn_mfma_f32_16x16x32_bf16(af0.v, b1.v, acc[2][0][1], 0, 0, 0);
        acc[2][1][0] = __builtin_amdgcn_mfma_f32_16x16x32_bf16(af1.v, b0.v, acc[2][1][0], 0, 0, 0);
        acc[2][1][1] = __builtin_amdgcn_mfma_f32_16x16x32_bf16(af1.v, b1.v, acc[2][1][1], 0, 0, 0);
        __syncthreads();
    }

    const float qsc = 0.14433756729740643f;  // 48^-0.5 folded into Q
#pragma unroll
    for (int fm = 0; fm < 2; ++fm) {
        int rbase = row0 + wm * 32 + fm * 16 + g * 4;  // n
#pragma unroll
        for (int fn = 0; fn < 2; ++fn) {
            int c = col0 + wn * 32 + fn * 16 + l15;    // 0..383 = b*48+d
            int b2 = (c * 683) >> 15, d = c - b2 * 48;
            ushort4 rq = *(const ushort4*)&QtH[hb + (long)c * 1024 + rbase];
            ushort4 rk = *(const ushort4*)&KtH[hb + (long)c * 1024 + rbase];
            ushort4 rv = *(const ushort4*)&VtH[hb + (long)c * 1024 + rbase];
            u16* qp = Q2 + (long)b2 * 393216 + (long)rbase * 384 + h * 48 + d;
            u16* kp = K2 + (long)b2 * 393216 + (long)rbase * 384 + h * 48 + d;
            ushort4 vo;
            const u16* rqa = (const u16*)&rq;
            const u16* rka = (const u16*)&rk;
            const u16* rva = (const u16*)&rv;
            u16* voa = (u16*)&vo;
#pragma unroll
            for (int r = 0; r < 4; ++r) {
                float qv = acc[0][fm][fn][r] + bf2f(rqa[r]);
                qp[r * 384] = f2bf(qv * qsc);
                float kv = acc[1][fm][fn][r] + bf2f(rka[r]);
                kp[r * 384] = f2bf(kv);
                float vv2 = acc[2][fm][fn][r] + bf2f(rva[r]);
                voa[r] = f2bf(vv2);
            }
            *(ushort4*)&V2T[hb + (long)c * 1024 + rbase] = vo;
        }
    }
}

// ---------------- flash attention, MFMA, bf16, no block barriers ----------------
// grid (16 qblocks, HEADS, BATCH), 256 threads = 4 independent waves x 16 q-rows.
// S^T = mfma(A=K, B=Q) -> lane-local softmax; P via per-wave LDS; O^T = mfma(A=V^T(global), B=P^T).
__global__ __launch_bounds__(256) void attn_mfma_kernel(
        const u16* __restrict__ Q2, const u16* __restrict__ K2,
        const u16* __restrict__ V2T, u16* __restrict__ O) {
    int qb = blockIdx.x, h = blockIdx.y, b = blockIdx.z;
    int tid = threadIdx.x, wave = tid >> 6, lane = tid & 63, g = lane >> 4, l15 = lane & 15;
    const long rowbase = (long)b * NTOK;
    const int colbase = h * DIM_HEAD;

    __shared__ u16 Pl[4][16][40];    // per-wave P: [query][key]

    const u16* qptr = Q2 + (rowbase + qb * 64 + wave * 16 + l15) * D_MODEL + colbase;
    F8 qf[2];
    qf[0].q[0] = *(const u64*)(qptr + g * 8);
    qf[0].q[1] = *(const u64*)(qptr + g * 8 + 4);
    if (g < 2) {
        qf[1].q[0] = *(const u64*)(qptr + 32 + g * 8);
        qf[1].q[1] = *(const u64*)(qptr + 32 + g * 8 + 4);
    } else { qf[1].q[0] = 0; qf[1].q[1] = 0; }

    const u16* vbase = V2T + (long)h * 393216 + (long)b * 49152;  // [48 d][1024 m]

    f32x4 oacc[3] = {};
    float runm = -1e30f, runl = 0.f;

    for (int m0 = 0; m0 < NTOK; m0 += 32) {
        f32x4 s[2] = {};
#pragma unroll
        for (int mt = 0; mt < 2; ++mt) {
            const u16* kp = K2 + (rowbase + m0 + mt * 16 + l15) * D_MODEL + colbase;
            F8 kf0, kf1;
            kf0.q[0] = *(const u64*)(kp + g * 8);
            kf0.q[1] = *(const u64*)(kp + g * 8 + 4);
            if (g < 2) {
                kf1.q[0] = *(const u64*)(kp + 32 + g * 8);
                kf1.q[1] = *(const u64*)(kp + 32 + g * 8 + 4);
            } else { kf1.q[0] = 0; kf1.q[1] = 0; }
            s[mt] = __builtin_amdgcn_mfma_f32_16x16x32_bf16(kf0.v, qf[0].v, s[mt], 0, 0, 0);
            s[mt] = __builtin_amdgcn_mfma_f32_16x16x32_bf16(kf1.v, qf[1].v, s[mt], 0, 0, 0);
        }

        float p[8];
        float tmax = -1e30f;
#pragma unroll
        for (int i = 0; i < 8; ++i) {
            float v = s[i >> 2][i & 3];   // scale pre-folded into Q
            p[i] = v; tmax = fmaxf(tmax, v);
        }
        tmax = fmaxf(tmax, __shfl_xor(tmax, 16));
        tmax = fmaxf(tmax, __shfl_xor(tmax, 32));
        // defer-max: only rescale when the running max grows by > 8
        if (!__all(tmax <= runm + 8.0f)) {
            float nm = fmaxf(runm, tmax);
            float corr = __expf(runm - nm);
            runm = nm; runl *= corr;
#pragma unroll
            for (int dt = 0; dt < 3; ++dt) {
                oacc[dt][0] *= corr; oacc[dt][1] *= corr;
                oacc[dt][2] *= corr; oacc[dt][3] *= corr;
            }
        }
        float ps = 0.f;
#pragma unroll
        for (int i = 0; i < 8; ++i) { p[i] = __expf(p[i] - runm); ps += p[i]; }
        ps += __shfl_xor(ps, 16);
        ps += __shfl_xor(ps, 32);
        runl += ps;

        u32 w0, w1, w2, w3;
        asm("v_cvt_pk_bf16_f32 %0, %1, %2" : "=v"(w0) : "v"(p[0]), "v"(p[1]));
        asm("v_cvt_pk_bf16_f32 %0, %1, %2" : "=v"(w1) : "v"(p[2]), "v"(p[3]));
        asm("v_cvt_pk_bf16_f32 %0, %1, %2" : "=v"(w2) : "v"(p[4]), "v"(p[5]));
        asm("v_cvt_pk_bf16_f32 %0, %1, %2" : "=v"(w3) : "v"(p[6]), "v"(p[7]));
        *(u64*)&Pl[wave][l15][g * 4]      = ((u64)w1 << 32) | w0;
        *(u64*)&Pl[wave][l15][16 + g * 4] = ((u64)w3 << 32) | w2;
        // per-wave LDS: wait for writes, and fence MFMA hoisting (rule #18)
        asm volatile("s_waitcnt lgkmcnt(0)" ::: "memory");
        __builtin_amdgcn_sched_barrier(0);
        F8 pb;
        pb.q[0] = *(const u64*)&Pl[wave][l15][g * 8];
        pb.q[1] = *(const u64*)&Pl[wave][l15][g * 8 + 4];
#pragma unroll
        for (int dt = 0; dt < 3; ++dt) {
            F8 vf;
            const u16* vp = vbase + (long)(dt * 16 + l15) * 1024 + m0 + g * 8;
            vf.q[0] = *(const u64*)vp;
            vf.q[1] = *(const u64*)(vp + 4);
            oacc[dt] = __builtin_amdgcn_mfma_f32_16x16x32_bf16(vf.v, pb.v, oacc[dt], 0, 0, 0);
        }
    }

    float inv = 1.f / runl;
    u16* op = O + (rowbase + qb * 64 + wave * 16 + l15) * D_MODEL + colbase;
#pragma unroll
    for (int dt = 0; dt < 3; ++dt) {
        ushort4 o;
        o.x = f2bf(oacc[dt][0] * inv); o.y = f2bf(oacc[dt][1] * inv);
        o.z = f2bf(oacc[dt][2] * inv); o.w = f2bf(oacc[dt][3] * inv);
        *(ushort4*)(op + dt * 16 + g * 4) = o;
    }
}

// ---------------- layernorm (+optional residual, optional bf16 copy) ----------------
__global__ __launch_bounds__(128) void ln_kernel(
        const float* __restrict__ X, const float* __restrict__ Rb,
        const float* __restrict__ g, const float* __restrict__ be,
        float* __restrict__ O, u16* __restrict__ Obf, int hasRes) {
    int row = blockIdx.x;
    int tid = threadIdx.x;
    const float* x = X + (long)row * D_MODEL;
    float v[3];
#pragma unroll
    for (int l = 0; l < 3; ++l) {
        int c = tid + l * 128;
        v[l] = x[c];
        if (hasRes) v[l] += Rb[(long)row * D_MODEL + c];
    }
    __shared__ float red[128];
    float s = v[0] + v[1] + v[2];
    red[tid] = s; __syncthreads();
    for (int st = 64; st > 0; st >>= 1) {
        if (tid < st) red[tid] += red[tid + st];
        __syncthreads();
    }
    float mean = red[0] * (1.f / 384.f);
    __syncthreads();
    float sq = 0.f;
#pragma unroll
    for (int l = 0; l < 3; ++l) { float d = v[l] - mean; sq += d * d; }
    red[tid] = sq; __syncthreads();
    for (int st = 64; st > 0; st >>= 1) {
        if (tid < st) red[tid] += red[tid + st];
        __syncthreads();
    }
    float rstd = rsqrtf(red[0] * (1.f / 384.f) + LN_EPS);
#pragma unroll
    for (int l = 0; l < 3; ++l) {
        int c = tid + l * 128;
        float o = (v[l] - mean) * rstd * g[c] + be[c];
        O[(long)row * D_MODEL + c] = o;
        if (Obf) Obf[(long)row * D_MODEL + c] = f2bf(o);
    }
}

extern "C" void kernel_launch(void* const* d_in, const int* in_sizes, int n_in,
                              void* d_out, int out_size, void* d_ws, size_t ws_size,
                              hipStream_t stream) {
    const float* src   = (const float*)d_in[0];
    const float* pos   = (const float*)d_in[1];
    const float* table = (const float*)d_in[2];
    const float* Wq  = (const float*)d_in[3];
    const float* Wk  = (const float*)d_in[4];
    const float* Wv  = (const float*)d_in[5];
    const float* Wo  = (const float*)d_in[6];
    const float* bo  = (const float*)d_in[7];
    const float* W1  = (const float*)d_in[8];
    const float* b1  = (const float*)d_in[9];
    const float* W2  = (const float*)d_in[10];
    const float* b2  = (const float*)d_in[11];
    const float* g1  = (const float*)d_in[12];
    const float* be1 = (const float*)d_in[13];
    const float* g2  = (const float*)d_in[14];
    const float* be2 = (const float*)d_in[15];
    float* out = (float*)d_out;
    u16* ws = (u16*)d_ws;

    const long SZ = (long)BATCH * NTOK * D_MODEL;  // 3,145,728

    // workspace layout (u16 units); total 38,469,632 u16 = 77 MB
    u16* WqT  = ws + 0;
    u16* WkT  = ws + 147456;
    u16* WvT  = ws + 294912;
    u16* WoT  = ws + 442368;
    u16* W1T  = ws + 589824;
    u16* W2T  = ws + 1179648;
    u16* QKin = ws + 1769472;
    u16* SRCB = ws + 4915200;
    u16* QtH  = ws + 8060928;    // [8][384][1024]
    u16* KtH  = ws + 11206656;
    u16* VtH  = ws + 14352384;
    u16* BT   = ws + 17498112;   // [8][1024][1024]
    u16* Q2   = ws + 25886720;   // std bf16 (scaled)
    u16* K2   = ws + 29032448;
    u16* V2T  = ws + 32178176;   // [8][384][1024]
    u16* ATT  = ws + 35323904;
    // aliases (lifetimes disjoint):
    float* Of  = (float*)(ws + 8060928);   // pre-LN1 f32 (over QtH+KtH, dead after bias3)
    float* xf  = (float*)(ws + 14352384);  // post-LN1 f32 (over VtH+BT head)
    u16*   xbf = QKin;                     // post-LN1 bf16 (QKin dead after projections)
    u16*   hbf = Q2;                       // FF hidden [8192][1536] (over Q2..ATT, dead by FF1)
    float* ff  = (float*)(ws + 8060928);   // pre-LN2 f32 (over Of, dead after LN1)

    // 1. adds + casts
    add_cast_kernel<<<(int)(SZ / 4 + 255) / 256, 256, 0, stream>>>(
        (const float4*)src, (const float4*)pos, (ushort4*)QKin, (ushort4*)SRCB, (int)(SZ / 4));
    // 2. weight transposes
    dim3 tb(32, 8);
    castT_kernel<<<dim3(12, 12), tb, 0, stream>>>(Wq, WqT, 384, 384);
    castT_kernel<<<dim3(12, 12), tb, 0, stream>>>(Wk, WkT, 384, 384);
    castT_kernel<<<dim3(12, 12), tb, 0, stream>>>(Wv, WvT, 384, 384);
    castT_kernel<<<dim3(12, 12), tb, 0, stream>>>(Wo, WoT, 384, 384);
    castT_kernel<<<dim3(48, 12), tb, 0, stream>>>(W1, W1T, 384, 1536);
    castT_kernel<<<dim3(12, 48), tb, 0, stream>>>(W2, W2T, 1536, 384);
    // 3. relative bias (transposed, bf16)
    biasT_bf16_kernel<<<32768, 256, 0, stream>>>(table, BT);
    // 4. projections -> head-major transposed bf16 only
    mgemm_kernel<8, false, false, false><<<dim3(6, 128, 1), 256, 0, stream>>>(
        QKin, WqT, nullptr, nullptr, QtH, nullptr, nullptr,
        8192, 384, 384, 384, 384, 0, 0);
    mgemm_kernel<8, false, false, false><<<dim3(6, 128, 1), 256, 0, stream>>>(
        QKin, WkT, nullptr, nullptr, KtH, nullptr, nullptr,
        8192, 384, 384, 384, 384, 0, 0);
    mgemm_kernel<8, false, false, false><<<dim3(6, 128, 1), 256, 0, stream>>>(
        SRCB, WvT, nullptr, nullptr, VtH, nullptr, nullptr,
        8192, 384, 384, 384, 384, 0, 0);
    // 5. fused bias matmuls -> Q2 (scaled), K2, V2T
    bias3_kernel<<<dim3(6, 16, 8), 256, 0, stream>>>(BT, QtH, KtH, VtH, Q2, K2, V2T);
    // 6. attention (MFMA flash, barrier-free)
    attn_mfma_kernel<<<dim3(16, HEADS, BATCH), 256, 0, stream>>>(Q2, K2, V2T, ATT);
    // 7. o = att @ Wo + bo + src
    mgemm_kernel<1, true, true, false><<<dim3(6, 128, 1), 256, 0, stream>>>(
        ATT, WoT, Of, nullptr, nullptr, bo, src,
        8192, 384, 384, 384, 384, 384, 384);
    // 8. x = LN1(o)
    ln_kernel<<<8192, 128, 0, stream>>>(Of, nullptr, g1, be1, xf, xbf, 0);
    // 9. h = gelu(x @ W1 + b1)
    mgemm_kernel<2, true, false, true><<<dim3(24, 128, 1), 256, 0, stream>>>(
        xbf, W1T, nullptr, hbf, nullptr, b1, nullptr,
        8192, 384, 1536, 384, 384, 1536, 0);
    // 10. ff = h @ W2 + b2 + x
    mgemm_kernel<1, true, true, false><<<dim3(6, 128, 1), 256, 0, stream>>>(
        hbf, W2T, ff, nullptr, nullptr, b2, xf,
        8192, 1536, 384, 1536, 1536, 384, 384);
    // 11. out = LN2(ff)
    ln_kernel<<<8192, 128, 0, stream>>>(ff, nullptr, g2, be2, out, nullptr, 0);
}

// Round 6
// 297.364 us; speedup vs baseline: 17.3844x; 1.0267x over previous
//
#include <hip/hip_runtime.h>
#include <math.h>

#define D_MODEL 384
#define HEADS 8
#define DIM_HEAD 48
#define NTOK 1024
#define BATCH 8
#define D_FF 1536
#define LN_EPS 1e-5f

typedef unsigned short u16;
typedef unsigned int u32;
typedef unsigned long long u64;
typedef short short8 __attribute__((ext_vector_type(8)));
typedef float f32x4 __attribute__((ext_vector_type(4)));

union F8 { short8 v; u64 q[2]; u16 u[8]; };

__device__ __forceinline__ u16 f2bf(float f) {
    union { float f; unsigned u; } c; c.f = f;
    unsigned r = c.u + 0x7FFFu + ((c.u >> 16) & 1u);
    return (u16)(r >> 16);
}
__device__ __forceinline__ float bf2f(u16 u) {
    union { unsigned u; float f; } c; c.u = ((unsigned)u) << 16; return c.f;
}

// ---------------- add + cast (QKin = bf16(src+pos), SRCB = bf16(src)) ----------------
__global__ __launch_bounds__(256) void add_cast_kernel(
        const float4* __restrict__ a, const float4* __restrict__ b,
        ushort4* __restrict__ o1, ushort4* __restrict__ o2, int n4) {
    int i = blockIdx.x * blockDim.x + threadIdx.x;
    if (i >= n4) return;
    float4 x = a[i], y = b[i];
    ushort4 u1, u2;
    u1.x = f2bf(x.x + y.x); u1.y = f2bf(x.y + y.y); u1.z = f2bf(x.z + y.z); u1.w = f2bf(x.w + y.w);
    u2.x = f2bf(x.x); u2.y = f2bf(x.y); u2.z = f2bf(x.z); u2.w = f2bf(x.w);
    o1[i] = u1; o2[i] = u2;
}

// ---------------- 4x square transpose + cast (384x384), z-batched ----------------
__global__ __launch_bounds__(256) void castT4_kernel(
        const float* __restrict__ i0, const float* __restrict__ i1,
        const float* __restrict__ i2, const float* __restrict__ i3,
        u16* __restrict__ o0, u16* __restrict__ o1,
        u16* __restrict__ o2, u16* __restrict__ o3) {
    const float* in  = (blockIdx.z == 0) ? i0 : (blockIdx.z == 1) ? i1 : (blockIdx.z == 2) ? i2 : i3;
    u16*         out = (blockIdx.z == 0) ? o0 : (blockIdx.z == 1) ? o1 : (blockIdx.z == 2) ? o2 : o3;
    __shared__ float t[32][33];
    int c0 = blockIdx.x * 32, r0 = blockIdx.y * 32;
    int tx = threadIdx.x, ty = threadIdx.y;  // 32 x 8
    for (int i = ty; i < 32; i += 8)
        t[i][tx] = in[(long)(r0 + i) * 384 + c0 + tx];
    __syncthreads();
    for (int i = ty; i < 32; i += 8)
        out[(long)(c0 + i) * 384 + r0 + tx] = f2bf(t[tx][i]);
}

// ---------------- transpose + cast: out[c][r] = bf16(in[r][c]) ----------------
__global__ __launch_bounds__(256) void castT_kernel(
        const float* __restrict__ in, u16* __restrict__ out, int R, int C) {
    __shared__ float t[32][33];
    int c0 = blockIdx.x * 32, r0 = blockIdx.y * 32;
    int tx = threadIdx.x, ty = threadIdx.y;  // 32 x 8
    for (int i = ty; i < 32; i += 8)
        t[i][tx] = in[(long)(r0 + i) * C + c0 + tx];
    __syncthreads();
    for (int i = ty; i < 32; i += 8)
        out[(long)(c0 + i) * R + r0 + tx] = f2bf(t[tx][i]);
}

// ---------------- relative bias, transposed, bf16: BT[h][n][m] = bias[h][m][n] ----------------
__global__ __launch_bounds__(256) void biasT_bf16_kernel(const float* __restrict__ table,
                                                         u16* __restrict__ BT) {
    long i = (long)blockIdx.x * blockDim.x + threadIdx.x;
    const long total = (long)HEADS * NTOK * NTOK;
    if (i >= total) return;
    int m = (int)(i & 1023);
    int n = (int)((i >> 10) & 1023);
    int h = (int)(i >> 20);
    int dy = (m >> 5) - (n >> 5) + 31;
    int dx = (m & 31) - (n & 31) + 31;
    BT[i] = f2bf(table[(dy * 63 + dx) * HEADS + h]);
}

// ---------------- MFMA GEMM ----------------
// C[M x N] = A[M x K](bf16, row-major) @ B (given as Bt[N x K] bf16, row-major)
// OUTMODE bits: 1 = f32 store, 2 = bf16 store, 8 = head-transposed bf16 store
template<int OUTMODE, bool HAS_BIAS, bool HAS_RES, bool GELU_>
__global__ __launch_bounds__(256) void mgemm_kernel(
        const u16* __restrict__ Ab, const u16* __restrict__ Btb,
        float* __restrict__ Cf, u16* __restrict__ Cb, u16* __restrict__ Ct,
        const float* __restrict__ bias, const float* __restrict__ Rb,
        int M, int Kd, int Nd, int lda, int ldbt, int ldc, int ldr) {
    const u16* A  = Ab;
    const u16* Bt = Btb;

    __shared__ u16 As[64][40];
    __shared__ u16 Bs[64][40];
    int tid = threadIdx.x;
    int wave = tid >> 6, lane = tid & 63, g = lane >> 4, l15 = lane & 15;
    int wm = wave >> 1, wn = wave & 1;
    int row0 = blockIdx.y * 64, col0 = blockIdx.x * 64;

    f32x4 acc[2][2] = {};

    int sr = tid >> 2, sch = tid & 3;
    const u16* aSrc = A + (long)(row0 + sr) * lda + sch * 8;
    const u16* bSrc = Bt + (long)(col0 + sr) * ldbt + sch * 8;

    for (int k0 = 0; k0 < Kd; k0 += 32) {
        {
            uint4 va = *(const uint4*)(aSrc + k0);
            uint4 vb = *(const uint4*)(bSrc + k0);
            *(u64*)&As[sr][sch * 8]     = ((const u64*)&va)[0];
            *(u64*)&As[sr][sch * 8 + 4] = ((const u64*)&va)[1];
            *(u64*)&Bs[sr][sch * 8]     = ((const u64*)&vb)[0];
            *(u64*)&Bs[sr][sch * 8 + 4] = ((const u64*)&vb)[1];
        }
        __syncthreads();
        F8 af[2], bfr[2];
#pragma unroll
        for (int fm = 0; fm < 2; ++fm) {
            int r = wm * 32 + fm * 16 + l15;
            af[fm].q[0] = *(const u64*)&As[r][g * 8];
            af[fm].q[1] = *(const u64*)&As[r][g * 8 + 4];
        }
#pragma unroll
        for (int fn = 0; fn < 2; ++fn) {
            int c = wn * 32 + fn * 16 + l15;
            bfr[fn].q[0] = *(const u64*)&Bs[c][g * 8];
            bfr[fn].q[1] = *(const u64*)&Bs[c][g * 8 + 4];
        }
#pragma unroll
        for (int fm = 0; fm < 2; ++fm)
#pragma unroll
            for (int fn = 0; fn < 2; ++fn)
                acc[fm][fn] = __builtin_amdgcn_mfma_f32_16x16x32_bf16(
                    af[fm].v, bfr[fn].v, acc[fm][fn], 0, 0, 0);
        __syncthreads();
    }

#pragma unroll
    for (int fm = 0; fm < 2; ++fm) {
        int rbase = row0 + wm * 32 + fm * 16 + g * 4;
#pragma unroll
        for (int fn = 0; fn < 2; ++fn) {
            int c = col0 + wn * 32 + fn * 16 + l15;
            if (c < Nd) {
                float bv = HAS_BIAS ? bias[c] : 0.f;
                float vs[4];
#pragma unroll
                for (int r = 0; r < 4; ++r) {
                    float v = acc[fm][fn][r] + bv;
                    if (HAS_RES) v += Rb[(long)(rbase + r) * ldr + c];
                    if (GELU_)   v = 0.5f * v * (1.f + erff(v * 0.70710678118654752f));
                    vs[r] = v;
                    if (OUTMODE & 1) Cf[(long)(rbase + r) * ldc + c] = v;
                    if (OUTMODE & 2) Cb[(long)(rbase + r) * ldc + c] = f2bf(v);
                }
                if (OUTMODE & 8) {
                    int hh2 = (c * 683) >> 15; int dd = c - hh2 * 48;
                    int bb2 = rbase >> 10;     int mm = rbase & 1023;
                    ushort4 o;
                    o.x = f2bf(vs[0]); o.y = f2bf(vs[1]); o.z = f2bf(vs[2]); o.w = f2bf(vs[3]);
                    *(ushort4*)&Ct[(long)hh2 * 393216 + (long)(bb2 * 48 + dd) * 1024 + mm] = o;
                }
            }
        }
    }
}

// ---------------- fused bias matmuls: {Q2,K2,V2T} = X + BT[h] @ X ----------------
__global__ __launch_bounds__(256) void bias3_kernel(
        const u16* __restrict__ BT, const u16* __restrict__ QtH,
        const u16* __restrict__ KtH, const u16* __restrict__ VtH,
        u16* __restrict__ Q2, u16* __restrict__ K2, u16* __restrict__ V2T) {
    int h = blockIdx.z;
    const long hb = (long)h * 393216;
    const u16* A = BT + (long)h * 1048576;
    __shared__ u16 As[64][40];
    __shared__ u16 Bq[64][40], Bk[64][40], Bv[64][40];
    int tid = threadIdx.x, wave = tid >> 6, lane = tid & 63, g = lane >> 4, l15 = lane & 15;
    int wm = wave >> 1, wn = wave & 1;
    int row0 = blockIdx.y * 64, col0 = blockIdx.x * 64;
    f32x4 acc[3][2][2] = {};
    int sr = tid >> 2, sch = tid & 3;
    const u16* aSrc = A   + (long)(row0 + sr) * 1024 + sch * 8;
    const u16* qSrc = QtH + hb + (long)(col0 + sr) * 1024 + sch * 8;
    const u16* kSrc = KtH + hb + (long)(col0 + sr) * 1024 + sch * 8;
    const u16* vSrc = VtH + hb + (long)(col0 + sr) * 1024 + sch * 8;

    for (int k0 = 0; k0 < 1024; k0 += 32) {
        uint4 va = *(const uint4*)(aSrc + k0);
        uint4 vq = *(const uint4*)(qSrc + k0);
        uint4 vk = *(const uint4*)(kSrc + k0);
        uint4 vv = *(const uint4*)(vSrc + k0);
        *(u64*)&As[sr][sch * 8] = ((const u64*)&va)[0]; *(u64*)&As[sr][sch * 8 + 4] = ((const u64*)&va)[1];
        *(u64*)&Bq[sr][sch * 8] = ((const u64*)&vq)[0]; *(u64*)&Bq[sr][sch * 8 + 4] = ((const u64*)&vq)[1];
        *(u64*)&Bk[sr][sch * 8] = ((const u64*)&vk)[0]; *(u64*)&Bk[sr][sch * 8 + 4] = ((const u64*)&vk)[1];
        *(u64*)&Bv[sr][sch * 8] = ((const u64*)&vv)[0]; *(u64*)&Bv[sr][sch * 8 + 4] = ((const u64*)&vv)[1];
        __syncthreads();
        F8 af0, af1, b0, b1;
        af0.q[0] = *(const u64*)&As[wm * 32 + l15][g * 8];
        af0.q[1] = *(const u64*)&As[wm * 32 + l15][g * 8 + 4];
        af1.q[0] = *(const u64*)&As[wm * 32 + 16 + l15][g * 8];
        af1.q[1] = *(const u64*)&As[wm * 32 + 16 + l15][g * 8 + 4];
        b0.q[0] = *(const u64*)&Bq[wn * 32 + l15][g * 8];
        b0.q[1] = *(const u64*)&Bq[wn * 32 + l15][g * 8 + 4];
        b1.q[0] = *(const u64*)&Bq[wn * 32 + 16 + l15][g * 8];
        b1.q[1] = *(const u64*)&Bq[wn * 32 + 16 + l15][g * 8 + 4];
        acc[0][0][0] = __builtin_amdgcn_mfma_f32_16x16x32_bf16(af0.v, b0.v, acc[0][0][0], 0, 0, 0);
        acc[0][0][1] = __builtin_amdgcn_mfma_f32_16x16x32_bf16(af0.v, b1.v, acc[0][0][1], 0, 0, 0);
        acc[0][1][0] = __builtin_amdgcn_mfma_f32_16x16x32_bf16(af1.v, b0.v, acc[0][1][0], 0, 0, 0);
        acc[0][1][1] = __builtin_amdgcn_mfma_f32_16x16x32_bf16(af1.v, b1.v, acc[0][1][1], 0, 0, 0);
        b0.q[0] = *(const u64*)&Bk[wn * 32 + l15][g * 8];
        b0.q[1] = *(const u64*)&Bk[wn * 32 + l15][g * 8 + 4];
        b1.q[0] = *(const u64*)&Bk[wn * 32 + 16 + l15][g * 8];
        b1.q[1] = *(const u64*)&Bk[wn * 32 + 16 + l15][g * 8 + 4];
        acc[1][0][0] = __builtin_amdgcn_mfma_f32_16x16x32_bf16(af0.v, b0.v, acc[1][0][0], 0, 0, 0);
        acc[1][0][1] = __builtin_amdgcn_mfma_f32_16x16x32_bf16(af0.v, b1.v, acc[1][0][1], 0, 0, 0);
        acc[1][1][0] = __builtin_amdgcn_mfma_f32_16x16x32_bf16(af1.v, b0.v, acc[1][1][0], 0, 0, 0);
        acc[1][1][1] = __builtin_amdgcn_mfma_f32_16x16x32_bf16(af1.v, b1.v, acc[1][1][1], 0, 0, 0);
        b0.q[0] = *(const u64*)&Bv[wn * 32 + l15][g * 8];
        b0.q[1] = *(const u64*)&Bv[wn * 32 + l15][g * 8 + 4];
        b1.q[0] = *(const u64*)&Bv[wn * 32 + 16 + l15][g * 8];
        b1.q[1] = *(const u64*)&Bv[wn * 32 + 16 + l15][g * 8 + 4];
        acc[2][0][0] = __builtin_amdgcn_mfma_f32_16x16x32_bf16(af0.v, b0.v, acc[2][0][0], 0, 0, 0);
        acc[2][0][1] = __builtin_amdgcn_mfma_f32_16x16x32_bf16(af0.v, b1.v, acc[2][0][1], 0, 0, 0);
        acc[2][1][0] = __builtin_amdgcn_mfma_f32_16x16x32_bf16(af1.v, b0.v, acc[2][1][0], 0, 0, 0);
        acc[2][1][1] = __builtin_amdgcn_mfma_f32_16x16x32_bf16(af1.v, b1.v, acc[2][1][1], 0, 0, 0);
        __syncthreads();
    }

    // Q pre-scale: 48^-0.5 * log2(e)  (attention softmax runs in exp2 domain)
    const float qsc = 0.14433756729740643f * 1.4426950408889634f;
#pragma unroll
    for (int fm = 0; fm < 2; ++fm) {
        int rbase = row0 + wm * 32 + fm * 16 + g * 4;  // n
#pragma unroll
        for (int fn = 0; fn < 2; ++fn) {
            int c = col0 + wn * 32 + fn * 16 + l15;    // 0..383 = b*48+d
            int b2 = (c * 683) >> 15, d = c - b2 * 48;
            ushort4 rq = *(const ushort4*)&QtH[hb + (long)c * 1024 + rbase];
            ushort4 rk = *(const ushort4*)&KtH[hb + (long)c * 1024 + rbase];
            ushort4 rv = *(const ushort4*)&VtH[hb + (long)c * 1024 + rbase];
            u16* qp = Q2 + (long)b2 * 393216 + (long)rbase * 384 + h * 48 + d;
            u16* kp = K2 + (long)b2 * 393216 + (long)rbase * 384 + h * 48 + d;
            ushort4 vo;
            const u16* rqa = (const u16*)&rq;
            const u16* rka = (const u16*)&rk;
            const u16* rva = (const u16*)&rv;
            u16* voa = (u16*)&vo;
#pragma unroll
            for (int r = 0; r < 4; ++r) {
                float qv = acc[0][fm][fn][r] + bf2f(rqa[r]);
                qp[r * 384] = f2bf(qv * qsc);
                float kv = acc[1][fm][fn][r] + bf2f(rka[r]);
                kp[r * 384] = f2bf(kv);
                float vv2 = acc[2][fm][fn][r] + bf2f(rva[r]);
                voa[r] = f2bf(vv2);
            }
            *(ushort4*)&V2T[hb + (long)c * 1024 + rbase] = vo;
        }
    }
}

// ---------------- flash attention, MFMA, bf16, KVBLK=64, fence-free ----------------
// grid (16 qblocks, HEADS, BATCH), 256 threads = 4 independent waves x 16 q-rows.
// S^T = mfma(A=K, B=Q) -> lane-local softmax (exp2 domain); P via per-wave LDS
// (plain C++ DS ops: same-wave in-order, may-alias => compiler keeps order & waits);
// O^T = mfma(A=V^T(global), B=P^T).
__global__ __launch_bounds__(256) void attn_mfma_kernel(
        const u16* __restrict__ Q2, const u16* __restrict__ K2,
        const u16* __restrict__ V2T, u16* __restrict__ O) {
    int qb = blockIdx.x, h = blockIdx.y, b = blockIdx.z;
    int tid = threadIdx.x, wave = tid >> 6, lane = tid & 63, g = lane >> 4, l15 = lane & 15;
    const long rowbase = (long)b * NTOK;
    const int colbase = h * DIM_HEAD;

    __shared__ u16 Pl[4][16][72];    // per-wave P: [query l15][64 keys], pad+XOR-swizzled
    const int sw = ((l15 >> 3) & 1) << 5;   // kills the l15 vs l15+8 bank alias

    const u16* qptr = Q2 + (rowbase + qb * 64 + wave * 16 + l15) * D_MODEL + colbase;
    F8 qf0, qf1;
    qf0.q[0] = *(const u64*)(qptr + g * 8);
    qf0.q[1] = *(const u64*)(qptr + g * 8 + 4);
    if (g < 2) {
        qf1.q[0] = *(const u64*)(qptr + 32 + g * 8);
        qf1.q[1] = *(const u64*)(qptr + 32 + g * 8 + 4);
    } else { qf1.q[0] = 0; qf1.q[1] = 0; }

    const u16* vbase = V2T + (long)h * 393216 + (long)b * 49152;  // [48 d][1024 m]

    f32x4 oacc[3] = {};
    float runm = -1e30f, runl = 0.f;

    for (int m0 = 0; m0 < NTOK; m0 += 64) {
        // ---- QK^T for 64 keys ----
        f32x4 s[4] = {};
#pragma unroll
        for (int mt = 0; mt < 4; ++mt) {
            const u16* kp = K2 + (rowbase + m0 + mt * 16 + l15) * D_MODEL + colbase;
            F8 kf0, kf1;
            kf0.q[0] = *(const u64*)(kp + g * 8);
            kf0.q[1] = *(const u64*)(kp + g * 8 + 4);
            if (g < 2) {
                kf1.q[0] = *(const u64*)(kp + 32 + g * 8);
                kf1.q[1] = *(const u64*)(kp + 32 + g * 8 + 4);
            } else { kf1.q[0] = 0; kf1.q[1] = 0; }
            s[mt] = __builtin_amdgcn_mfma_f32_16x16x32_bf16(kf0.v, qf0.v, s[mt], 0, 0, 0);
            s[mt] = __builtin_amdgcn_mfma_f32_16x16x32_bf16(kf1.v, qf1.v, s[mt], 0, 0, 0);
        }

        // ---- V fragments (independent of softmax: latency hides under it) ----
        F8 vf[3][2];
#pragma unroll
        for (int dt = 0; dt < 3; ++dt)
#pragma unroll
            for (int ks = 0; ks < 2; ++ks) {
                const u16* vp = vbase + (long)(dt * 16 + l15) * 1024 + m0 + ks * 32 + g * 8;
                vf[dt][ks].q[0] = *(const u64*)vp;
                vf[dt][ks].q[1] = *(const u64*)(vp + 4);
            }

        // ---- online softmax (exp2 domain; scale*log2e pre-folded into Q) ----
        float p[16];
        float tmax = -1e30f;
#pragma unroll
        for (int i = 0; i < 16; ++i) {
            float v = s[i >> 2][i & 3];
            p[i] = v; tmax = fmaxf(tmax, v);
        }
        tmax = fmaxf(tmax, __shfl_xor(tmax, 16));
        tmax = fmaxf(tmax, __shfl_xor(tmax, 32));
        if (!__all(tmax <= runm + 8.0f)) {     // defer-max (T13)
            float nm = fmaxf(runm, tmax);
            float corr = __builtin_amdgcn_exp2f(runm - nm);
            runm = nm; runl *= corr;
#pragma unroll
            for (int dt = 0; dt < 3; ++dt) {
                oacc[dt][0] *= corr; oacc[dt][1] *= corr;
                oacc[dt][2] *= corr; oacc[dt][3] *= corr;
            }
        }
        float ps = 0.f;
#pragma unroll
        for (int i = 0; i < 16; ++i) { p[i] = __builtin_amdgcn_exp2f(p[i] - runm); ps += p[i]; }
        ps += __shfl_xor(ps, 16);
        ps += __shfl_xor(ps, 32);
        runl += ps;

        // ---- P -> bf16 -> per-wave LDS redistribution ----
#pragma unroll
        for (int mt = 0; mt < 4; ++mt) {
            u32 wa, wb;
            asm("v_cvt_pk_bf16_f32 %0, %1, %2" : "=v"(wa) : "v"(p[mt * 4]), "v"(p[mt * 4 + 1]));
            asm("v_cvt_pk_bf16_f32 %0, %1, %2" : "=v"(wb) : "v"(p[mt * 4 + 2]), "v"(p[mt * 4 + 3]));
            *(u64*)&Pl[wave][l15][(mt * 16 + g * 4) ^ sw] = ((u64)wb << 32) | wa;
        }
        F8 pb[2];
#pragma unroll
        for (int ks = 0; ks < 2; ++ks) {
            pb[ks].q[0] = *(const u64*)&Pl[wave][l15][(ks * 32 + g * 8) ^ sw];
            pb[ks].q[1] = *(const u64*)&Pl[wave][l15][((ks * 32 + g * 8) + 4) ^ sw];
        }

        // ---- PV ----
#pragma unroll
        for (int dt = 0; dt < 3; ++dt) {
            oacc[dt] = __builtin_amdgcn_mfma_f32_16x16x32_bf16(vf[dt][0].v, pb[0].v, oacc[dt], 0, 0, 0);
            oacc[dt] = __builtin_amdgcn_mfma_f32_16x16x32_bf16(vf[dt][1].v, pb[1].v, oacc[dt], 0, 0, 0);
        }
    }

    float inv = 1.f / runl;
    u16* op = O + (rowbase + qb * 64 + wave * 16 + l15) * D_MODEL + colbase;
#pragma unroll
    for (int dt = 0; dt < 3; ++dt) {
        ushort4 o;
        o.x = f2bf(oacc[dt][0] * inv); o.y = f2bf(oacc[dt][1] * inv);
        o.z = f2bf(oacc[dt][2] * inv); o.w = f2bf(oacc[dt][3] * inv);
        *(ushort4*)(op + dt * 16 + g * 4) = o;
    }
}

// ---------------- layernorm (+optional residual, optional bf16 copy) ----------------
__global__ __launch_bounds__(128) void ln_kernel(
        const float* __restrict__ X, const float* __restrict__ Rb,
        const float* __restrict__ g, const float* __restrict__ be,
        float* __restrict__ O, u16* __restrict__ Obf, int hasRes) {
    int row = blockIdx.x;
    int tid = threadIdx.x;
    const float* x = X + (long)row * D_MODEL;
    float v[3];
#pragma unroll
    for (int l = 0; l < 3; ++l) {
        int c = tid + l * 128;
        v[l] = x[c];
        if (hasRes) v[l] += Rb[(long)row * D_MODEL + c];
    }
    __shared__ float red[128];
    float s = v[0] + v[1] + v[2];
    red[tid] = s; __syncthreads();
    for (int st = 64; st > 0; st >>= 1) {
        if (tid < st) red[tid] += red[tid + st];
        __syncthreads();
    }
    float mean = red[0] * (1.f / 384.f);
    __syncthreads();
    float sq = 0.f;
#pragma unroll
    for (int l = 0; l < 3; ++l) { float d = v[l] - mean; sq += d * d; }
    red[tid] = sq; __syncthreads();
    for (int st = 64; st > 0; st >>= 1) {
        if (tid < st) red[tid] += red[tid + st];
        __syncthreads();
    }
    float rstd = rsqrtf(red[0] * (1.f / 384.f) + LN_EPS);
#pragma unroll
    for (int l = 0; l < 3; ++l) {
        int c = tid + l * 128;
        float o = (v[l] - mean) * rstd * g[c] + be[c];
        O[(long)row * D_MODEL + c] = o;
        if (Obf) Obf[(long)row * D_MODEL + c] = f2bf(o);
    }
}

extern "C" void kernel_launch(void* const* d_in, const int* in_sizes, int n_in,
                              void* d_out, int out_size, void* d_ws, size_t ws_size,
                              hipStream_t stream) {
    const float* src   = (const float*)d_in[0];
    const float* pos   = (const float*)d_in[1];
    const float* table = (const float*)d_in[2];
    const float* Wq  = (const float*)d_in[3];
    const float* Wk  = (const float*)d_in[4];
    const float* Wv  = (const float*)d_in[5];
    const float* Wo  = (const float*)d_in[6];
    const float* bo  = (const float*)d_in[7];
    const float* W1  = (const float*)d_in[8];
    const float* b1  = (const float*)d_in[9];
    const float* W2  = (const float*)d_in[10];
    const float* b2  = (const float*)d_in[11];
    const float* g1  = (const float*)d_in[12];
    const float* be1 = (const float*)d_in[13];
    const float* g2  = (const float*)d_in[14];
    const float* be2 = (const float*)d_in[15];
    float* out = (float*)d_out;
    u16* ws = (u16*)d_ws;

    const long SZ = (long)BATCH * NTOK * D_MODEL;  // 3,145,728

    u16* WqT  = ws + 0;
    u16* WkT  = ws + 147456;
    u16* WvT  = ws + 294912;
    u16* WoT  = ws + 442368;
    u16* W1T  = ws + 589824;
    u16* W2T  = ws + 1179648;
    u16* QKin = ws + 1769472;
    u16* SRCB = ws + 4915200;
    u16* QtH  = ws + 8060928;    // [8][384][1024]
    u16* KtH  = ws + 11206656;
    u16* VtH  = ws + 14352384;
    u16* BT   = ws + 17498112;   // [8][1024][1024]
    u16* Q2   = ws + 25886720;   // std bf16 (scaled by 48^-0.5*log2e)
    u16* K2   = ws + 29032448;
    u16* V2T  = ws + 32178176;   // [8][384][1024]
    u16* ATT  = ws + 35323904;
    // aliases (lifetimes disjoint):
    float* Of  = (float*)(ws + 8060928);   // pre-LN1 f32 (over QtH+KtH, dead after bias3)
    float* xf  = (float*)(ws + 14352384);  // post-LN1 f32 (over VtH+BT head)
    u16*   xbf = QKin;                     // post-LN1 bf16 (QKin dead after projections)
    u16*   hbf = Q2;                       // FF hidden [8192][1536] (over Q2..ATT, dead by FF1)
    float* ff  = (float*)(ws + 8060928);   // pre-LN2 f32 (over Of, dead after LN1)

    // 1. adds + casts
    add_cast_kernel<<<(int)(SZ / 4 + 255) / 256, 256, 0, stream>>>(
        (const float4*)src, (const float4*)pos, (ushort4*)QKin, (ushort4*)SRCB, (int)(SZ / 4));
    // 2. weight transposes
    dim3 tb(32, 8);
    castT4_kernel<<<dim3(12, 12, 4), tb, 0, stream>>>(Wq, Wk, Wv, Wo, WqT, WkT, WvT, WoT);
    castT_kernel<<<dim3(48, 12), tb, 0, stream>>>(W1, W1T, 384, 1536);
    castT_kernel<<<dim3(12, 48), tb, 0, stream>>>(W2, W2T, 1536, 384);
    // 3. relative bias (transposed, bf16)
    biasT_bf16_kernel<<<32768, 256, 0, stream>>>(table, BT);
    // 4. projections -> head-major transposed bf16
    mgemm_kernel<8, false, false, false><<<dim3(6, 128, 1), 256, 0, stream>>>(
        QKin, WqT, nullptr, nullptr, QtH, nullptr, nullptr,
        8192, 384, 384, 384, 384, 0, 0);
    mgemm_kernel<8, false, false, false><<<dim3(6, 128, 1), 256, 0, stream>>>(
        QKin, WkT, nullptr, nullptr, KtH, nullptr, nullptr,
        8192, 384, 384, 384, 384, 0, 0);
    mgemm_kernel<8, false, false, false><<<dim3(6, 128, 1), 256, 0, stream>>>(
        SRCB, WvT, nullptr, nullptr, VtH, nullptr, nullptr,
        8192, 384, 384, 384, 384, 0, 0);
    // 5. fused bias matmuls -> Q2 (scaled), K2, V2T
    bias3_kernel<<<dim3(6, 16, 8), 256, 0, stream>>>(BT, QtH, KtH, VtH, Q2, K2, V2T);
    // 6. attention
    attn_mfma_kernel<<<dim3(16, HEADS, BATCH), 256, 0, stream>>>(Q2, K2, V2T, ATT);
    // 7. o = att @ Wo + bo + src
    mgemm_kernel<1, true, true, false><<<dim3(6, 128, 1), 256, 0, stream>>>(
        ATT, WoT, Of, nullptr, nullptr, bo, src,
        8192, 384, 384, 384, 384, 384, 384);
    // 8. x = LN1(o)
    ln_kernel<<<8192, 128, 0, stream>>>(Of, nullptr, g1, be1, xf, xbf, 0);
    // 9. h = gelu(x @ W1 + b1)
    mgemm_kernel<2, true, false, true><<<dim3(24, 128, 1), 256, 0, stream>>>(
        xbf, W1T, nullptr, hbf, nullptr, b1, nullptr,
        8192, 384, 1536, 384, 384, 1536, 0);
    // 10. ff = h @ W2 + b2 + x
    mgemm_kernel<1, true, true, false><<<dim3(6, 128, 1), 256, 0, stream>>>(
        hbf, W2T, ff, nullptr, nullptr, b2, xf,
        8192, 1536, 384, 1536, 1536, 384, 384);
    // 11. out = LN2(ff)
    ln_kernel<<<8192, 128, 0, stream>>>(ff, nullptr, g2, be2, out, nullptr, 0);
}

// Round 7
// 269.834 us; speedup vs baseline: 19.1581x; 1.1020x over previous
//
#include <hip/hip_runtime.h>
#include <math.h>

#define D_MODEL 384
#define HEADS 8
#define DIM_HEAD 48
#define NTOK 1024
#define BATCH 8
#define D_FF 1536
#define LN_EPS 1e-5f

typedef unsigned short u16;
typedef unsigned int u32;
typedef unsigned long long u64;
typedef short short8 __attribute__((ext_vector_type(8)));
typedef float f32x4 __attribute__((ext_vector_type(4)));

union F8 { short8 v; u64 q[2]; u16 u[8]; };

__device__ __forceinline__ u16 f2bf(float f) {
    union { float f; unsigned u; } c; c.f = f;
    unsigned r = c.u + 0x7FFFu + ((c.u >> 16) & 1u);
    return (u16)(r >> 16);
}
__device__ __forceinline__ float bf2f(u16 u) {
    union { unsigned u; float f; } c; c.u = ((unsigned)u) << 16; return c.f;
}

// ---------------- add + cast (QKin = bf16(src+pos), SRCB = bf16(src)) ----------------
__global__ __launch_bounds__(256) void add_cast_kernel(
        const float4* __restrict__ a, const float4* __restrict__ b,
        ushort4* __restrict__ o1, ushort4* __restrict__ o2, int n4) {
    int i = blockIdx.x * blockDim.x + threadIdx.x;
    if (i >= n4) return;
    float4 x = a[i], y = b[i];
    ushort4 u1, u2;
    u1.x = f2bf(x.x + y.x); u1.y = f2bf(x.y + y.y); u1.z = f2bf(x.z + y.z); u1.w = f2bf(x.w + y.w);
    u2.x = f2bf(x.x); u2.y = f2bf(x.y); u2.z = f2bf(x.z); u2.w = f2bf(x.w);
    o1[i] = u1; o2[i] = u2;
}

// ---------------- 4x square transpose + cast (384x384), z-batched ----------------
__global__ __launch_bounds__(256) void castT4_kernel(
        const float* __restrict__ i0, const float* __restrict__ i1,
        const float* __restrict__ i2, const float* __restrict__ i3,
        u16* __restrict__ o0, u16* __restrict__ o1,
        u16* __restrict__ o2, u16* __restrict__ o3) {
    const float* in  = (blockIdx.z == 0) ? i0 : (blockIdx.z == 1) ? i1 : (blockIdx.z == 2) ? i2 : i3;
    u16*         out = (blockIdx.z == 0) ? o0 : (blockIdx.z == 1) ? o1 : (blockIdx.z == 2) ? o2 : o3;
    __shared__ float t[32][33];
    int c0 = blockIdx.x * 32, r0 = blockIdx.y * 32;
    int tx = threadIdx.x, ty = threadIdx.y;  // 32 x 8
    for (int i = ty; i < 32; i += 8)
        t[i][tx] = in[(long)(r0 + i) * 384 + c0 + tx];
    __syncthreads();
    for (int i = ty; i < 32; i += 8)
        out[(long)(c0 + i) * 384 + r0 + tx] = f2bf(t[tx][i]);
}

// ---------------- transpose + cast: out[c][r] = bf16(in[r][c]) ----------------
__global__ __launch_bounds__(256) void castT_kernel(
        const float* __restrict__ in, u16* __restrict__ out, int R, int C) {
    __shared__ float t[32][33];
    int c0 = blockIdx.x * 32, r0 = blockIdx.y * 32;
    int tx = threadIdx.x, ty = threadIdx.y;  // 32 x 8
    for (int i = ty; i < 32; i += 8)
        t[i][tx] = in[(long)(r0 + i) * C + c0 + tx];
    __syncthreads();
    for (int i = ty; i < 32; i += 8)
        out[(long)(c0 + i) * R + r0 + tx] = f2bf(t[tx][i]);
}

// ---------------- relative bias, transposed, bf16: BT[h][n][m] = bias[h][m][n] ----------------
__global__ __launch_bounds__(256) void biasT_bf16_kernel(const float* __restrict__ table,
                                                         u16* __restrict__ BT) {
    long i = (long)blockIdx.x * blockDim.x + threadIdx.x;
    const long total = (long)HEADS * NTOK * NTOK;
    if (i >= total) return;
    int m = (int)(i & 1023);
    int n = (int)((i >> 10) & 1023);
    int h = (int)(i >> 20);
    int dy = (m >> 5) - (n >> 5) + 31;
    int dx = (m & 31) - (n & 31) + 31;
    BT[i] = f2bf(table[(dy * 63 + dx) * HEADS + h]);
}

// ---------------- MFMA GEMM ----------------
// C[M x N] = A[M x K](bf16, row-major) @ B (given as Bt[N x K] bf16, row-major)
// OUTMODE bits: 1 = f32 store, 2 = bf16 store, 8 = head-transposed bf16 store
template<int OUTMODE, bool HAS_BIAS, bool HAS_RES, bool GELU_>
__global__ __launch_bounds__(256) void mgemm_kernel(
        const u16* __restrict__ Ab, const u16* __restrict__ Btb,
        float* __restrict__ Cf, u16* __restrict__ Cb, u16* __restrict__ Ct,
        const float* __restrict__ bias, const float* __restrict__ Rb,
        int M, int Kd, int Nd, int lda, int ldbt, int ldc, int ldr) {
    const u16* A  = Ab;
    const u16* Bt = Btb;

    __shared__ u16 As[64][40];
    __shared__ u16 Bs[64][40];
    int tid = threadIdx.x;
    int wave = tid >> 6, lane = tid & 63, g = lane >> 4, l15 = lane & 15;
    int wm = wave >> 1, wn = wave & 1;
    int row0 = blockIdx.y * 64, col0 = blockIdx.x * 64;

    f32x4 acc[2][2] = {};

    int sr = tid >> 2, sch = tid & 3;
    const u16* aSrc = A + (long)(row0 + sr) * lda + sch * 8;
    const u16* bSrc = Bt + (long)(col0 + sr) * ldbt + sch * 8;

    for (int k0 = 0; k0 < Kd; k0 += 32) {
        {
            uint4 va = *(const uint4*)(aSrc + k0);
            uint4 vb = *(const uint4*)(bSrc + k0);
            *(u64*)&As[sr][sch * 8]     = ((const u64*)&va)[0];
            *(u64*)&As[sr][sch * 8 + 4] = ((const u64*)&va)[1];
            *(u64*)&Bs[sr][sch * 8]     = ((const u64*)&vb)[0];
            *(u64*)&Bs[sr][sch * 8 + 4] = ((const u64*)&vb)[1];
        }
        __syncthreads();
        F8 af[2], bfr[2];
#pragma unroll
        for (int fm = 0; fm < 2; ++fm) {
            int r = wm * 32 + fm * 16 + l15;
            af[fm].q[0] = *(const u64*)&As[r][g * 8];
            af[fm].q[1] = *(const u64*)&As[r][g * 8 + 4];
        }
#pragma unroll
        for (int fn = 0; fn < 2; ++fn) {
            int c = wn * 32 + fn * 16 + l15;
            bfr[fn].q[0] = *(const u64*)&Bs[c][g * 8];
            bfr[fn].q[1] = *(const u64*)&Bs[c][g * 8 + 4];
        }
#pragma unroll
        for (int fm = 0; fm < 2; ++fm)
#pragma unroll
            for (int fn = 0; fn < 2; ++fn)
                acc[fm][fn] = __builtin_amdgcn_mfma_f32_16x16x32_bf16(
                    af[fm].v, bfr[fn].v, acc[fm][fn], 0, 0, 0);
        __syncthreads();
    }

#pragma unroll
    for (int fm = 0; fm < 2; ++fm) {
        int rbase = row0 + wm * 32 + fm * 16 + g * 4;
#pragma unroll
        for (int fn = 0; fn < 2; ++fn) {
            int c = col0 + wn * 32 + fn * 16 + l15;
            if (c < Nd) {
                float bv = HAS_BIAS ? bias[c] : 0.f;
                float vs[4];
#pragma unroll
                for (int r = 0; r < 4; ++r) {
                    float v = acc[fm][fn][r] + bv;
                    if (HAS_RES) v += Rb[(long)(rbase + r) * ldr + c];
                    if (GELU_)   v = 0.5f * v * (1.f + erff(v * 0.70710678118654752f));
                    vs[r] = v;
                    if (OUTMODE & 1) Cf[(long)(rbase + r) * ldc + c] = v;
                    if (OUTMODE & 2) Cb[(long)(rbase + r) * ldc + c] = f2bf(v);
                }
                if (OUTMODE & 8) {
                    int hh2 = (c * 683) >> 15; int dd = c - hh2 * 48;
                    int bb2 = rbase >> 10;     int mm = rbase & 1023;
                    ushort4 o;
                    o.x = f2bf(vs[0]); o.y = f2bf(vs[1]); o.z = f2bf(vs[2]); o.w = f2bf(vs[3]);
                    *(ushort4*)&Ct[(long)hh2 * 393216 + (long)(bb2 * 48 + dd) * 1024 + mm] = o;
                }
            }
        }
    }
}

// ---------------- fused bias matmuls: {Q2H,K2H,V2T} = X + BT[h] @ X ----------------
// Outputs now ALL head-major:
//   Q2H,K2H: [(h*8+b)][n][48]  (rows 96B packed; Q pre-scaled by 48^-0.5*log2e)
//   V2T:     [h][b*48+d][1024]
__global__ __launch_bounds__(256) void bias3_kernel(
        const u16* __restrict__ BT, const u16* __restrict__ QtH,
        const u16* __restrict__ KtH, const u16* __restrict__ VtH,
        u16* __restrict__ Q2H, u16* __restrict__ K2H, u16* __restrict__ V2T) {
    int h = blockIdx.z;
    const long hb = (long)h * 393216;
    const u16* A = BT + (long)h * 1048576;
    __shared__ u16 As[64][40];
    __shared__ u16 Bq[64][40], Bk[64][40], Bv[64][40];
    int tid = threadIdx.x, wave = tid >> 6, lane = tid & 63, g = lane >> 4, l15 = lane & 15;
    int wm = wave >> 1, wn = wave & 1;
    int row0 = blockIdx.y * 64, col0 = blockIdx.x * 64;
    f32x4 acc[3][2][2] = {};
    int sr = tid >> 2, sch = tid & 3;
    const u16* aSrc = A   + (long)(row0 + sr) * 1024 + sch * 8;
    const u16* qSrc = QtH + hb + (long)(col0 + sr) * 1024 + sch * 8;
    const u16* kSrc = KtH + hb + (long)(col0 + sr) * 1024 + sch * 8;
    const u16* vSrc = VtH + hb + (long)(col0 + sr) * 1024 + sch * 8;

    for (int k0 = 0; k0 < 1024; k0 += 32) {
        uint4 va = *(const uint4*)(aSrc + k0);
        uint4 vq = *(const uint4*)(qSrc + k0);
        uint4 vk = *(const uint4*)(kSrc + k0);
        uint4 vv = *(const uint4*)(vSrc + k0);
        *(u64*)&As[sr][sch * 8] = ((const u64*)&va)[0]; *(u64*)&As[sr][sch * 8 + 4] = ((const u64*)&va)[1];
        *(u64*)&Bq[sr][sch * 8] = ((const u64*)&vq)[0]; *(u64*)&Bq[sr][sch * 8 + 4] = ((const u64*)&vq)[1];
        *(u64*)&Bk[sr][sch * 8] = ((const u64*)&vk)[0]; *(u64*)&Bk[sr][sch * 8 + 4] = ((const u64*)&vk)[1];
        *(u64*)&Bv[sr][sch * 8] = ((const u64*)&vv)[0]; *(u64*)&Bv[sr][sch * 8 + 4] = ((const u64*)&vv)[1];
        __syncthreads();
        F8 af0, af1, b0, b1;
        af0.q[0] = *(const u64*)&As[wm * 32 + l15][g * 8];
        af0.q[1] = *(const u64*)&As[wm * 32 + l15][g * 8 + 4];
        af1.q[0] = *(const u64*)&As[wm * 32 + 16 + l15][g * 8];
        af1.q[1] = *(const u64*)&As[wm * 32 + 16 + l15][g * 8 + 4];
        b0.q[0] = *(const u64*)&Bq[wn * 32 + l15][g * 8];
        b0.q[1] = *(const u64*)&Bq[wn * 32 + l15][g * 8 + 4];
        b1.q[0] = *(const u64*)&Bq[wn * 32 + 16 + l15][g * 8];
        b1.q[1] = *(const u64*)&Bq[wn * 32 + 16 + l15][g * 8 + 4];
        acc[0][0][0] = __builtin_amdgcn_mfma_f32_16x16x32_bf16(af0.v, b0.v, acc[0][0][0], 0, 0, 0);
        acc[0][0][1] = __builtin_amdgcn_mfma_f32_16x16x32_bf16(af0.v, b1.v, acc[0][0][1], 0, 0, 0);
        acc[0][1][0] = __builtin_amdgcn_mfma_f32_16x16x32_bf16(af1.v, b0.v, acc[0][1][0], 0, 0, 0);
        acc[0][1][1] = __builtin_amdgcn_mfma_f32_16x16x32_bf16(af1.v, b1.v, acc[0][1][1], 0, 0, 0);
        b0.q[0] = *(const u64*)&Bk[wn * 32 + l15][g * 8];
        b0.q[1] = *(const u64*)&Bk[wn * 32 + l15][g * 8 + 4];
        b1.q[0] = *(const u64*)&Bk[wn * 32 + 16 + l15][g * 8];
        b1.q[1] = *(const u64*)&Bk[wn * 32 + 16 + l15][g * 8 + 4];
        acc[1][0][0] = __builtin_amdgcn_mfma_f32_16x16x32_bf16(af0.v, b0.v, acc[1][0][0], 0, 0, 0);
        acc[1][0][1] = __builtin_amdgcn_mfma_f32_16x16x32_bf16(af0.v, b1.v, acc[1][0][1], 0, 0, 0);
        acc[1][1][0] = __builtin_amdgcn_mfma_f32_16x16x32_bf16(af1.v, b0.v, acc[1][1][0], 0, 0, 0);
        acc[1][1][1] = __builtin_amdgcn_mfma_f32_16x16x32_bf16(af1.v, b1.v, acc[1][1][1], 0, 0, 0);
        b0.q[0] = *(const u64*)&Bv[wn * 32 + l15][g * 8];
        b0.q[1] = *(const u64*)&Bv[wn * 32 + l15][g * 8 + 4];
        b1.q[0] = *(const u64*)&Bv[wn * 32 + 16 + l15][g * 8];
        b1.q[1] = *(const u64*)&Bv[wn * 32 + 16 + l15][g * 8 + 4];
        acc[2][0][0] = __builtin_amdgcn_mfma_f32_16x16x32_bf16(af0.v, b0.v, acc[2][0][0], 0, 0, 0);
        acc[2][0][1] = __builtin_amdgcn_mfma_f32_16x16x32_bf16(af0.v, b1.v, acc[2][0][1], 0, 0, 0);
        acc[2][1][0] = __builtin_amdgcn_mfma_f32_16x16x32_bf16(af1.v, b0.v, acc[2][1][0], 0, 0, 0);
        acc[2][1][1] = __builtin_amdgcn_mfma_f32_16x16x32_bf16(af1.v, b1.v, acc[2][1][1], 0, 0, 0);
        __syncthreads();
    }

    // Q pre-scale: 48^-0.5 * log2(e)  (attention softmax runs in exp2 domain)
    const float qsc = 0.14433756729740643f * 1.4426950408889634f;
#pragma unroll
    for (int fm = 0; fm < 2; ++fm) {
        int rbase = row0 + wm * 32 + fm * 16 + g * 4;  // n
#pragma unroll
        for (int fn = 0; fn < 2; ++fn) {
            int c = col0 + wn * 32 + fn * 16 + l15;    // 0..383 = b*48+d
            int b2 = (c * 683) >> 15, d = c - b2 * 48;
            ushort4 rq = *(const ushort4*)&QtH[hb + (long)c * 1024 + rbase];
            ushort4 rk = *(const ushort4*)&KtH[hb + (long)c * 1024 + rbase];
            ushort4 rv = *(const ushort4*)&VtH[hb + (long)c * 1024 + rbase];
            u16* qp = Q2H + ((long)(h * 8 + b2) * 1024 + rbase) * 48 + d;
            u16* kp = K2H + ((long)(h * 8 + b2) * 1024 + rbase) * 48 + d;
            ushort4 vo;
            const u16* rqa = (const u16*)&rq;
            const u16* rka = (const u16*)&rk;
            const u16* rva = (const u16*)&rv;
            u16* voa = (u16*)&vo;
#pragma unroll
            for (int r = 0; r < 4; ++r) {
                float qv = acc[0][fm][fn][r] + bf2f(rqa[r]);
                qp[r * 48] = f2bf(qv * qsc);
                float kv = acc[1][fm][fn][r] + bf2f(rka[r]);
                kp[r * 48] = f2bf(kv);
                float vv2 = acc[2][fm][fn][r] + bf2f(rva[r]);
                voa[r] = f2bf(vv2);
            }
            *(ushort4*)&V2T[hb + (long)c * 1024 + rbase] = vo;
        }
    }
}

// ---------------- flash attention, MFMA, bf16, wave-split KV ----------------
// grid (64 qblocks of 16 rows, HEADS, BATCH), 256 threads = 4 waves.
// Each wave processes a disjoint 256-key slice for the SAME 16 q-rows (4 iters of 64),
// then a two-barrier LDS combine merges the 4 partial (O, m, l); wave 0 writes.
__global__ __launch_bounds__(256, 4) void attn_mfma_kernel(
        const u16* __restrict__ Q2H, const u16* __restrict__ K2H,
        const u16* __restrict__ V2T, u16* __restrict__ O) {
    int qb = blockIdx.x, h = blockIdx.y, b = blockIdx.z;
    int tid = threadIdx.x, wave = tid >> 6, lane = tid & 63, g = lane >> 4, l15 = lane & 15;

    __shared__ char smem[13824];
    // Pl (loop phase) unions with Oc (combine phase); MLc lives after Oc.
    u16   (*Pl)[16][72]  = (u16(*)[16][72])smem;            // [4][16][72] u16 = 9216 B
    float (*Oc)[16][52]  = (float(*)[16][52])smem;          // [4][16][52] f32 = 13312 B
    float (*MLc)[16][2]  = (float(*)[16][2])(smem + 13312); // 512 B
    const int sw = ((l15 >> 3) & 1) << 5;

    const long bh1024 = (long)(h * 8 + b) * 1024;
    const u16* qptr = Q2H + (bh1024 + qb * 16 + l15) * 48;
    F8 qf0, qf1;
    qf0.q[0] = *(const u64*)(qptr + g * 8);
    qf0.q[1] = *(const u64*)(qptr + g * 8 + 4);
    if (g < 2) {
        qf1.q[0] = *(const u64*)(qptr + 32 + g * 8);
        qf1.q[1] = *(const u64*)(qptr + 32 + g * 8 + 4);
    } else { qf1.q[0] = 0; qf1.q[1] = 0; }

    const u16* vbase = V2T + (long)h * 393216 + (long)b * 49152;  // [48 d][1024 m]

    f32x4 oacc[3] = {};
    float runm = -1e30f, runl = 0.f;

#pragma unroll
    for (int it = 0; it < 4; ++it) {
        const int m0 = wave * 256 + it * 64;
        // ---- QK^T for this wave's 64 keys ----
        f32x4 s[4] = {};
#pragma unroll
        for (int mt = 0; mt < 4; ++mt) {
            const u16* kp = K2H + (bh1024 + m0 + mt * 16 + l15) * 48;
            F8 kf0, kf1;
            kf0.q[0] = *(const u64*)(kp + g * 8);
            kf0.q[1] = *(const u64*)(kp + g * 8 + 4);
            if (g < 2) {
                kf1.q[0] = *(const u64*)(kp + 32 + g * 8);
                kf1.q[1] = *(const u64*)(kp + 32 + g * 8 + 4);
            } else { kf1.q[0] = 0; kf1.q[1] = 0; }
            s[mt] = __builtin_amdgcn_mfma_f32_16x16x32_bf16(kf0.v, qf0.v, s[mt], 0, 0, 0);
            s[mt] = __builtin_amdgcn_mfma_f32_16x16x32_bf16(kf1.v, qf1.v, s[mt], 0, 0, 0);
        }

        // ---- V fragments (independent; latency hides under softmax) ----
        F8 vf[3][2];
#pragma unroll
        for (int dt = 0; dt < 3; ++dt)
#pragma unroll
            for (int ks = 0; ks < 2; ++ks) {
                const u16* vp = vbase + (long)(dt * 16 + l15) * 1024 + m0 + ks * 32 + g * 8;
                vf[dt][ks].q[0] = *(const u64*)vp;
                vf[dt][ks].q[1] = *(const u64*)(vp + 4);
            }

        // ---- online softmax (exp2 domain) ----
        float p[16];
#pragma unroll
        for (int i = 0; i < 16; ++i) p[i] = s[i >> 2][i & 3];
        float pm[8];
#pragma unroll
        for (int i = 0; i < 8; ++i) pm[i] = fmaxf(p[i], p[i + 8]);
#pragma unroll
        for (int st = 4; st > 0; st >>= 1)
#pragma unroll
            for (int i = 0; i < st; ++i) pm[i] = fmaxf(pm[i], pm[i + st]);
        float tmax = pm[0];
        tmax = fmaxf(tmax, __shfl_xor(tmax, 16));
        tmax = fmaxf(tmax, __shfl_xor(tmax, 32));
        if (!__all(tmax <= runm + 8.0f)) {     // defer-max (T13)
            float nm = fmaxf(runm, tmax);
            float corr = __builtin_amdgcn_exp2f(runm - nm);
            runm = nm; runl *= corr;
#pragma unroll
            for (int dt = 0; dt < 3; ++dt) {
                oacc[dt][0] *= corr; oacc[dt][1] *= corr;
                oacc[dt][2] *= corr; oacc[dt][3] *= corr;
            }
        }
        float ps = 0.f;
#pragma unroll
        for (int i = 0; i < 16; ++i) { p[i] = __builtin_amdgcn_exp2f(p[i] - runm); ps += p[i]; }
        ps += __shfl_xor(ps, 16);
        ps += __shfl_xor(ps, 32);
        runl += ps;

        // ---- P -> bf16 -> per-wave LDS redistribution ----
#pragma unroll
        for (int mt = 0; mt < 4; ++mt) {
            u32 wa, wb;
            asm("v_cvt_pk_bf16_f32 %0, %1, %2" : "=v"(wa) : "v"(p[mt * 4]), "v"(p[mt * 4 + 1]));
            asm("v_cvt_pk_bf16_f32 %0, %1, %2" : "=v"(wb) : "v"(p[mt * 4 + 2]), "v"(p[mt * 4 + 3]));
            *(u64*)&Pl[wave][l15][(mt * 16 + g * 4) ^ sw] = ((u64)wb << 32) | wa;
        }
        F8 pb[2];
#pragma unroll
        for (int ks = 0; ks < 2; ++ks) {
            pb[ks].q[0] = *(const u64*)&Pl[wave][l15][(ks * 32 + g * 8) ^ sw];
            pb[ks].q[1] = *(const u64*)&Pl[wave][l15][((ks * 32 + g * 8) + 4) ^ sw];
        }

        // ---- PV ----
#pragma unroll
        for (int dt = 0; dt < 3; ++dt) {
            oacc[dt] = __builtin_amdgcn_mfma_f32_16x16x32_bf16(vf[dt][0].v, pb[0].v, oacc[dt], 0, 0, 0);
            oacc[dt] = __builtin_amdgcn_mfma_f32_16x16x32_bf16(vf[dt][1].v, pb[1].v, oacc[dt], 0, 0, 0);
        }
    }

    // ---- cross-wave combine ----
    __syncthreads();   // all waves done with Pl (unioned with Oc)
#pragma unroll
    for (int dt = 0; dt < 3; ++dt)
#pragma unroll
        for (int r = 0; r < 4; ++r)
            Oc[wave][l15][dt * 16 + g * 4 + r] = oacc[dt][r];
    if (g == 0) { MLc[wave][l15][0] = runm; MLc[wave][l15][1] = runl; }
    __syncthreads();

    if (wave == 0) {
        float mm[4], cc[4];
#pragma unroll
        for (int w = 0; w < 4; ++w) mm[w] = MLc[w][l15][0];
        float M = fmaxf(fmaxf(mm[0], mm[1]), fmaxf(mm[2], mm[3]));
        float LL = 0.f;
#pragma unroll
        for (int w = 0; w < 4; ++w) {
            cc[w] = __builtin_amdgcn_exp2f(mm[w] - M);
            LL += cc[w] * MLc[w][l15][1];
        }
        float inv = 1.f / LL;
        u16* op = O + ((long)b * NTOK + qb * 16 + l15) * D_MODEL + h * DIM_HEAD;
#pragma unroll
        for (int dt = 0; dt < 3; ++dt) {
            ushort4 o;
#pragma unroll
            for (int r = 0; r < 4; ++r) {
                int d = dt * 16 + g * 4 + r;
                float v = cc[0] * Oc[0][l15][d] + cc[1] * Oc[1][l15][d]
                        + cc[2] * Oc[2][l15][d] + cc[3] * Oc[3][l15][d];
                ((u16*)&o)[r] = f2bf(v * inv);
            }
            *(ushort4*)(op + dt * 16 + g * 4) = o;
        }
    }
}

// ---------------- layernorm (+optional residual, optional bf16 copy) ----------------
__global__ __launch_bounds__(128) void ln_kernel(
        const float* __restrict__ X, const float* __restrict__ Rb,
        const float* __restrict__ g, const float* __restrict__ be,
        float* __restrict__ O, u16* __restrict__ Obf, int hasRes) {
    int row = blockIdx.x;
    int tid = threadIdx.x;
    const float* x = X + (long)row * D_MODEL;
    float v[3];
#pragma unroll
    for (int l = 0; l < 3; ++l) {
        int c = tid + l * 128;
        v[l] = x[c];
        if (hasRes) v[l] += Rb[(long)row * D_MODEL + c];
    }
    __shared__ float red[128];
    float s = v[0] + v[1] + v[2];
    red[tid] = s; __syncthreads();
    for (int st = 64; st > 0; st >>= 1) {
        if (tid < st) red[tid] += red[tid + st];
        __syncthreads();
    }
    float mean = red[0] * (1.f / 384.f);
    __syncthreads();
    float sq = 0.f;
#pragma unroll
    for (int l = 0; l < 3; ++l) { float d = v[l] - mean; sq += d * d; }
    red[tid] = sq; __syncthreads();
    for (int st = 64; st > 0; st >>= 1) {
        if (tid < st) red[tid] += red[tid + st];
        __syncthreads();
    }
    float rstd = rsqrtf(red[0] * (1.f / 384.f) + LN_EPS);
#pragma unroll
    for (int l = 0; l < 3; ++l) {
        int c = tid + l * 128;
        float o = (v[l] - mean) * rstd * g[c] + be[c];
        O[(long)row * D_MODEL + c] = o;
        if (Obf) Obf[(long)row * D_MODEL + c] = f2bf(o);
    }
}

extern "C" void kernel_launch(void* const* d_in, const int* in_sizes, int n_in,
                              void* d_out, int out_size, void* d_ws, size_t ws_size,
                              hipStream_t stream) {
    const float* src   = (const float*)d_in[0];
    const float* pos   = (const float*)d_in[1];
    const float* table = (const float*)d_in[2];
    const float* Wq  = (const float*)d_in[3];
    const float* Wk  = (const float*)d_in[4];
    const float* Wv  = (const float*)d_in[5];
    const float* Wo  = (const float*)d_in[6];
    const float* bo  = (const float*)d_in[7];
    const float* W1  = (const float*)d_in[8];
    const float* b1  = (const float*)d_in[9];
    const float* W2  = (const float*)d_in[10];
    const float* b2  = (const float*)d_in[11];
    const float* g1  = (const float*)d_in[12];
    const float* be1 = (const float*)d_in[13];
    const float* g2  = (const float*)d_in[14];
    const float* be2 = (const float*)d_in[15];
    float* out = (float*)d_out;
    u16* ws = (u16*)d_ws;

    const long SZ = (long)BATCH * NTOK * D_MODEL;  // 3,145,728

    u16* WqT  = ws + 0;
    u16* WkT  = ws + 147456;
    u16* WvT  = ws + 294912;
    u16* WoT  = ws + 442368;
    u16* W1T  = ws + 589824;
    u16* W2T  = ws + 1179648;
    u16* QKin = ws + 1769472;
    u16* SRCB = ws + 4915200;
    u16* QtH  = ws + 8060928;    // [8][384][1024]
    u16* KtH  = ws + 11206656;
    u16* VtH  = ws + 14352384;
    u16* BT   = ws + 17498112;   // [8][1024][1024]
    u16* Q2H  = ws + 25886720;   // head-major [(h*8+b)][1024][48], pre-scaled
    u16* K2H  = ws + 29032448;   // head-major [(h*8+b)][1024][48]
    u16* V2T  = ws + 32178176;   // [8][384][1024]
    u16* ATT  = ws + 35323904;
    // aliases (lifetimes disjoint):
    float* Of  = (float*)(ws + 8060928);   // pre-LN1 f32 (over QtH+KtH, dead after bias3)
    float* xf  = (float*)(ws + 14352384);  // post-LN1 f32 (over VtH+BT head)
    u16*   xbf = QKin;                     // post-LN1 bf16 (QKin dead after projections)
    u16*   hbf = Q2H;                      // FF hidden [8192][1536] (over Q2H..ATT, dead by FF1)
    float* ff  = (float*)(ws + 8060928);   // pre-LN2 f32 (over Of, dead after LN1)

    // 1. adds + casts
    add_cast_kernel<<<(int)(SZ / 4 + 255) / 256, 256, 0, stream>>>(
        (const float4*)src, (const float4*)pos, (ushort4*)QKin, (ushort4*)SRCB, (int)(SZ / 4));
    // 2. weight transposes
    dim3 tb(32, 8);
    castT4_kernel<<<dim3(12, 12, 4), tb, 0, stream>>>(Wq, Wk, Wv, Wo, WqT, WkT, WvT, WoT);
    castT_kernel<<<dim3(48, 12), tb, 0, stream>>>(W1, W1T, 384, 1536);
    castT_kernel<<<dim3(12, 48), tb, 0, stream>>>(W2, W2T, 1536, 384);
    // 3. relative bias (transposed, bf16)
    biasT_bf16_kernel<<<32768, 256, 0, stream>>>(table, BT);
    // 4. projections -> head-major transposed bf16
    mgemm_kernel<8, false, false, false><<<dim3(6, 128, 1), 256, 0, stream>>>(
        QKin, WqT, nullptr, nullptr, QtH, nullptr, nullptr,
        8192, 384, 384, 384, 384, 0, 0);
    mgemm_kernel<8, false, false, false><<<dim3(6, 128, 1), 256, 0, stream>>>(
        QKin, WkT, nullptr, nullptr, KtH, nullptr, nullptr,
        8192, 384, 384, 384, 384, 0, 0);
    mgemm_kernel<8, false, false, false><<<dim3(6, 128, 1), 256, 0, stream>>>(
        SRCB, WvT, nullptr, nullptr, VtH, nullptr, nullptr,
        8192, 384, 384, 384, 384, 0, 0);
    // 5. fused bias matmuls -> Q2H (scaled), K2H, V2T
    bias3_kernel<<<dim3(6, 16, 8), 256, 0, stream>>>(BT, QtH, KtH, VtH, Q2H, K2H, V2T);
    // 6. attention (wave-split KV)
    attn_mfma_kernel<<<dim3(64, HEADS, BATCH), 256, 0, stream>>>(Q2H, K2H, V2T, ATT);
    // 7. o = att @ Wo + bo + src
    mgemm_kernel<1, true, true, false><<<dim3(6, 128, 1), 256, 0, stream>>>(
        ATT, WoT, Of, nullptr, nullptr, bo, src,
        8192, 384, 384, 384, 384, 384, 384);
    // 8. x = LN1(o)
    ln_kernel<<<8192, 128, 0, stream>>>(Of, nullptr, g1, be1, xf, xbf, 0);
    // 9. h = gelu(x @ W1 + b1)
    mgemm_kernel<2, true, false, true><<<dim3(24, 128, 1), 256, 0, stream>>>(
        xbf, W1T, nullptr, hbf, nullptr, b1, nullptr,
        8192, 384, 1536, 384, 384, 1536, 0);
    // 10. ff = h @ W2 + b2 + x
    mgemm_kernel<1, true, true, false><<<dim3(6, 128, 1), 256, 0, stream>>>(
        hbf, W2T, ff, nullptr, nullptr, b2, xf,
        8192, 1536, 384, 1536, 1536, 384, 384);
    // 11. out = LN2(ff)
    ln_kernel<<<8192, 128, 0, stream>>>(ff, nullptr, g2, be2, out, nullptr, 0);
}

// Round 8
// 256.828 us; speedup vs baseline: 20.1283x; 1.0506x over previous
//
#include <hip/hip_runtime.h>
#include <math.h>

#define D_MODEL 384
#define HEADS 8
#define DIM_HEAD 48
#define NTOK 1024
#define BATCH 8
#define D_FF 1536
#define LN_EPS 1e-5f

typedef unsigned short u16;
typedef unsigned int u32;
typedef unsigned long long u64;
typedef short short8 __attribute__((ext_vector_type(8)));
typedef float f32x4 __attribute__((ext_vector_type(4)));

union F8 { short8 v; u64 q[2]; u16 u[8]; };

__device__ __forceinline__ u16 f2bf(float f) {
    union { float f; unsigned u; } c; c.f = f;
    unsigned r = c.u + 0x7FFFu + ((c.u >> 16) & 1u);
    return (u16)(r >> 16);
}
__device__ __forceinline__ float bf2f(u16 u) {
    union { unsigned u; float f; } c; c.u = ((unsigned)u) << 16; return c.f;
}

// ---------------- add + cast (QKin = bf16(src+pos), SRCB = bf16(src)) ----------------
__global__ __launch_bounds__(256) void add_cast_kernel(
        const float4* __restrict__ a, const float4* __restrict__ b,
        ushort4* __restrict__ o1, ushort4* __restrict__ o2, int n4) {
    int i = blockIdx.x * blockDim.x + threadIdx.x;
    if (i >= n4) return;
    float4 x = a[i], y = b[i];
    ushort4 u1, u2;
    u1.x = f2bf(x.x + y.x); u1.y = f2bf(x.y + y.y); u1.z = f2bf(x.z + y.z); u1.w = f2bf(x.w + y.w);
    u2.x = f2bf(x.x); u2.y = f2bf(x.y); u2.z = f2bf(x.z); u2.w = f2bf(x.w);
    o1[i] = u1; o2[i] = u2;
}

// ---------------- 4x square transpose + cast (384x384), z-batched ----------------
__global__ __launch_bounds__(256) void castT4_kernel(
        const float* __restrict__ i0, const float* __restrict__ i1,
        const float* __restrict__ i2, const float* __restrict__ i3,
        u16* __restrict__ o0, u16* __restrict__ o1,
        u16* __restrict__ o2, u16* __restrict__ o3) {
    const float* in  = (blockIdx.z == 0) ? i0 : (blockIdx.z == 1) ? i1 : (blockIdx.z == 2) ? i2 : i3;
    u16*         out = (blockIdx.z == 0) ? o0 : (blockIdx.z == 1) ? o1 : (blockIdx.z == 2) ? o2 : o3;
    __shared__ float t[32][33];
    int c0 = blockIdx.x * 32, r0 = blockIdx.y * 32;
    int tx = threadIdx.x, ty = threadIdx.y;  // 32 x 8
    for (int i = ty; i < 32; i += 8)
        t[i][tx] = in[(long)(r0 + i) * 384 + c0 + tx];
    __syncthreads();
    for (int i = ty; i < 32; i += 8)
        out[(long)(c0 + i) * 384 + r0 + tx] = f2bf(t[tx][i]);
}

// ---------------- transpose + cast: out[c][r] = bf16(in[r][c]) ----------------
__global__ __launch_bounds__(256) void castT_kernel(
        const float* __restrict__ in, u16* __restrict__ out, int R, int C) {
    __shared__ float t[32][33];
    int c0 = blockIdx.x * 32, r0 = blockIdx.y * 32;
    int tx = threadIdx.x, ty = threadIdx.y;  // 32 x 8
    for (int i = ty; i < 32; i += 8)
        t[i][tx] = in[(long)(r0 + i) * C + c0 + tx];
    __syncthreads();
    for (int i = ty; i < 32; i += 8)
        out[(long)(c0 + i) * R + r0 + tx] = f2bf(t[tx][i]);
}

// ---------------- relative bias, transposed, bf16: BT[h][n][m] = bias[h][m][n] ----------------
__global__ __launch_bounds__(256) void biasT_bf16_kernel(const float* __restrict__ table,
                                                         u16* __restrict__ BT) {
    long i = (long)blockIdx.x * blockDim.x + threadIdx.x;
    const long total = (long)HEADS * NTOK * NTOK;
    if (i >= total) return;
    int m = (int)(i & 1023);
    int n = (int)((i >> 10) & 1023);
    int h = (int)(i >> 20);
    int dy = (m >> 5) - (n >> 5) + 31;
    int dx = (m & 31) - (n & 31) + 31;
    BT[i] = f2bf(table[(dy * 63 + dx) * HEADS + h]);
}

// ---------------- MFMA GEMM ----------------
// C[M x N] = A[M x K](bf16, row-major) @ B (given as Bt[N x K] bf16, row-major)
// OUTMODE bits: 1 = f32 store, 2 = bf16 store, 8 = head-transposed bf16 store
template<int OUTMODE, bool HAS_BIAS, bool HAS_RES, bool GELU_>
__global__ __launch_bounds__(256) void mgemm_kernel(
        const u16* __restrict__ Ab, const u16* __restrict__ Btb,
        float* __restrict__ Cf, u16* __restrict__ Cb, u16* __restrict__ Ct,
        const float* __restrict__ bias, const float* __restrict__ Rb,
        int M, int Kd, int Nd, int lda, int ldbt, int ldc, int ldr) {
    const u16* A  = Ab;
    const u16* Bt = Btb;

    __shared__ u16 As[64][40];
    __shared__ u16 Bs[64][40];
    int tid = threadIdx.x;
    int wave = tid >> 6, lane = tid & 63, g = lane >> 4, l15 = lane & 15;
    int wm = wave >> 1, wn = wave & 1;
    int row0 = blockIdx.y * 64, col0 = blockIdx.x * 64;

    f32x4 acc[2][2] = {};

    int sr = tid >> 2, sch = tid & 3;
    const u16* aSrc = A + (long)(row0 + sr) * lda + sch * 8;
    const u16* bSrc = Bt + (long)(col0 + sr) * ldbt + sch * 8;

    for (int k0 = 0; k0 < Kd; k0 += 32) {
        {
            uint4 va = *(const uint4*)(aSrc + k0);
            uint4 vb = *(const uint4*)(bSrc + k0);
            *(u64*)&As[sr][sch * 8]     = ((const u64*)&va)[0];
            *(u64*)&As[sr][sch * 8 + 4] = ((const u64*)&va)[1];
            *(u64*)&Bs[sr][sch * 8]     = ((const u64*)&vb)[0];
            *(u64*)&Bs[sr][sch * 8 + 4] = ((const u64*)&vb)[1];
        }
        __syncthreads();
        F8 af[2], bfr[2];
#pragma unroll
        for (int fm = 0; fm < 2; ++fm) {
            int r = wm * 32 + fm * 16 + l15;
            af[fm].q[0] = *(const u64*)&As[r][g * 8];
            af[fm].q[1] = *(const u64*)&As[r][g * 8 + 4];
        }
#pragma unroll
        for (int fn = 0; fn < 2; ++fn) {
            int c = wn * 32 + fn * 16 + l15;
            bfr[fn].q[0] = *(const u64*)&Bs[c][g * 8];
            bfr[fn].q[1] = *(const u64*)&Bs[c][g * 8 + 4];
        }
#pragma unroll
        for (int fm = 0; fm < 2; ++fm)
#pragma unroll
            for (int fn = 0; fn < 2; ++fn)
                acc[fm][fn] = __builtin_amdgcn_mfma_f32_16x16x32_bf16(
                    af[fm].v, bfr[fn].v, acc[fm][fn], 0, 0, 0);
        __syncthreads();
    }

#pragma unroll
    for (int fm = 0; fm < 2; ++fm) {
        int rbase = row0 + wm * 32 + fm * 16 + g * 4;
#pragma unroll
        for (int fn = 0; fn < 2; ++fn) {
            int c = col0 + wn * 32 + fn * 16 + l15;
            if (c < Nd) {
                float bv = HAS_BIAS ? bias[c] : 0.f;
                float vs[4];
#pragma unroll
                for (int r = 0; r < 4; ++r) {
                    float v = acc[fm][fn][r] + bv;
                    if (HAS_RES) v += Rb[(long)(rbase + r) * ldr + c];
                    if (GELU_)   v = 0.5f * v * (1.f + erff(v * 0.70710678118654752f));
                    vs[r] = v;
                    if (OUTMODE & 1) Cf[(long)(rbase + r) * ldc + c] = v;
                    if (OUTMODE & 2) Cb[(long)(rbase + r) * ldc + c] = f2bf(v);
                }
                if (OUTMODE & 8) {
                    int hh2 = (c * 683) >> 15; int dd = c - hh2 * 48;   // valid for c < 768
                    int bb2 = rbase >> 10;     int mm = rbase & 1023;
                    ushort4 o;
                    o.x = f2bf(vs[0]); o.y = f2bf(vs[1]); o.z = f2bf(vs[2]); o.w = f2bf(vs[3]);
                    *(ushort4*)&Ct[(long)hh2 * 393216 + (long)(bb2 * 48 + dd) * 1024 + mm] = o;
                }
            }
        }
    }
}

// ---------------- fused bias matmuls: {Q2H,K2H,V2T} = X + BT[h] @ X ----------------
// 1D grid 768, XCD-swizzled so each XCD owns exactly one head (BT[h] = 2MB, L2-fit).
//   Q2H,K2H: [(h*8+b)][n][48]; V2T: [h][b*48+d][1024]
__global__ __launch_bounds__(256) void bias3_kernel(
        const u16* __restrict__ BT, const u16* __restrict__ QtH,
        const u16* __restrict__ KtH, const u16* __restrict__ VtH,
        u16* __restrict__ Q2H, u16* __restrict__ K2H, u16* __restrict__ V2T) {
    int bid = blockIdx.x;
    int widx = (bid & 7) * 96 + (bid >> 3);   // bijective (768 % 8 == 0)
    int h = widx / 96;
    int rem = widx - h * 96;
    int ry = rem / 6, cx = rem - ry * 6;
    const long hb = (long)h * 393216;
    const u16* A = BT + (long)h * 1048576;
    __shared__ u16 As[64][40];
    __shared__ u16 Bq[64][40], Bk[64][40], Bv[64][40];
    int tid = threadIdx.x, wave = tid >> 6, lane = tid & 63, g = lane >> 4, l15 = lane & 15;
    int wm = wave >> 1, wn = wave & 1;
    int row0 = ry * 64, col0 = cx * 64;
    f32x4 acc[3][2][2] = {};
    int sr = tid >> 2, sch = tid & 3;
    const u16* aSrc = A   + (long)(row0 + sr) * 1024 + sch * 8;
    const u16* qSrc = QtH + hb + (long)(col0 + sr) * 1024 + sch * 8;
    const u16* kSrc = KtH + hb + (long)(col0 + sr) * 1024 + sch * 8;
    const u16* vSrc = VtH + hb + (long)(col0 + sr) * 1024 + sch * 8;

    for (int k0 = 0; k0 < 1024; k0 += 32) {
        uint4 va = *(const uint4*)(aSrc + k0);
        uint4 vq = *(const uint4*)(qSrc + k0);
        uint4 vk = *(const uint4*)(kSrc + k0);
        uint4 vv = *(const uint4*)(vSrc + k0);
        *(u64*)&As[sr][sch * 8] = ((const u64*)&va)[0]; *(u64*)&As[sr][sch * 8 + 4] = ((const u64*)&va)[1];
        *(u64*)&Bq[sr][sch * 8] = ((const u64*)&vq)[0]; *(u64*)&Bq[sr][sch * 8 + 4] = ((const u64*)&vq)[1];
        *(u64*)&Bk[sr][sch * 8] = ((const u64*)&vk)[0]; *(u64*)&Bk[sr][sch * 8 + 4] = ((const u64*)&vk)[1];
        *(u64*)&Bv[sr][sch * 8] = ((const u64*)&vv)[0]; *(u64*)&Bv[sr][sch * 8 + 4] = ((const u64*)&vv)[1];
        __syncthreads();
        F8 af0, af1, b0, b1;
        af0.q[0] = *(const u64*)&As[wm * 32 + l15][g * 8];
        af0.q[1] = *(const u64*)&As[wm * 32 + l15][g * 8 + 4];
        af1.q[0] = *(const u64*)&As[wm * 32 + 16 + l15][g * 8];
        af1.q[1] = *(const u64*)&As[wm * 32 + 16 + l15][g * 8 + 4];
        b0.q[0] = *(const u64*)&Bq[wn * 32 + l15][g * 8];
        b0.q[1] = *(const u64*)&Bq[wn * 32 + l15][g * 8 + 4];
        b1.q[0] = *(const u64*)&Bq[wn * 32 + 16 + l15][g * 8];
        b1.q[1] = *(const u64*)&Bq[wn * 32 + 16 + l15][g * 8 + 4];
        acc[0][0][0] = __builtin_amdgcn_mfma_f32_16x16x32_bf16(af0.v, b0.v, acc[0][0][0], 0, 0, 0);
        acc[0][0][1] = __builtin_amdgcn_mfma_f32_16x16x32_bf16(af0.v, b1.v, acc[0][0][1], 0, 0, 0);
        acc[0][1][0] = __builtin_amdgcn_mfma_f32_16x16x32_bf16(af1.v, b0.v, acc[0][1][0], 0, 0, 0);
        acc[0][1][1] = __builtin_amdgcn_mfma_f32_16x16x32_bf16(af1.v, b1.v, acc[0][1][1], 0, 0, 0);
        b0.q[0] = *(const u64*)&Bk[wn * 32 + l15][g * 8];
        b0.q[1] = *(const u64*)&Bk[wn * 32 + l15][g * 8 + 4];
        b1.q[0] = *(const u64*)&Bk[wn * 32 + 16 + l15][g * 8];
        b1.q[1] = *(const u64*)&Bk[wn * 32 + 16 + l15][g * 8 + 4];
        acc[1][0][0] = __builtin_amdgcn_mfma_f32_16x16x32_bf16(af0.v, b0.v, acc[1][0][0], 0, 0, 0);
        acc[1][0][1] = __builtin_amdgcn_mfma_f32_16x16x32_bf16(af0.v, b1.v, acc[1][0][1], 0, 0, 0);
        acc[1][1][0] = __builtin_amdgcn_mfma_f32_16x16x32_bf16(af1.v, b0.v, acc[1][1][0], 0, 0, 0);
        acc[1][1][1] = __builtin_amdgcn_mfma_f32_16x16x32_bf16(af1.v, b1.v, acc[1][1][1], 0, 0, 0);
        b0.q[0] = *(const u64*)&Bv[wn * 32 + l15][g * 8];
        b0.q[1] = *(const u64*)&Bv[wn * 32 + l15][g * 8 + 4];
        b1.q[0] = *(const u64*)&Bv[wn * 32 + 16 + l15][g * 8];
        b1.q[1] = *(const u64*)&Bv[wn * 32 + 16 + l15][g * 8 + 4];
        acc[2][0][0] = __builtin_amdgcn_mfma_f32_16x16x32_bf16(af0.v, b0.v, acc[2][0][0], 0, 0, 0);
        acc[2][0][1] = __builtin_amdgcn_mfma_f32_16x16x32_bf16(af0.v, b1.v, acc[2][0][1], 0, 0, 0);
        acc[2][1][0] = __builtin_amdgcn_mfma_f32_16x16x32_bf16(af1.v, b0.v, acc[2][1][0], 0, 0, 0);
        acc[2][1][1] = __builtin_amdgcn_mfma_f32_16x16x32_bf16(af1.v, b1.v, acc[2][1][1], 0, 0, 0);
        __syncthreads();
    }

    // Q pre-scale: 48^-0.5 * log2(e)  (attention softmax runs in exp2 domain)
    const float qsc = 0.14433756729740643f * 1.4426950408889634f;
#pragma unroll
    for (int fm = 0; fm < 2; ++fm) {
        int rbase = row0 + wm * 32 + fm * 16 + g * 4;  // n
#pragma unroll
        for (int fn = 0; fn < 2; ++fn) {
            int c = col0 + wn * 32 + fn * 16 + l15;    // 0..383 = b*48+d
            int b2 = (c * 683) >> 15, d = c - b2 * 48;
            ushort4 rq = *(const ushort4*)&QtH[hb + (long)c * 1024 + rbase];
            ushort4 rk = *(const ushort4*)&KtH[hb + (long)c * 1024 + rbase];
            ushort4 rv = *(const ushort4*)&VtH[hb + (long)c * 1024 + rbase];
            u16* qp = Q2H + ((long)(h * 8 + b2) * 1024 + rbase) * 48 + d;
            u16* kp = K2H + ((long)(h * 8 + b2) * 1024 + rbase) * 48 + d;
            ushort4 vo;
            const u16* rqa = (const u16*)&rq;
            const u16* rka = (const u16*)&rk;
            const u16* rva = (const u16*)&rv;
            u16* voa = (u16*)&vo;
#pragma unroll
            for (int r = 0; r < 4; ++r) {
                float qv = acc[0][fm][fn][r] + bf2f(rqa[r]);
                qp[r * 48] = f2bf(qv * qsc);
                float kv = acc[1][fm][fn][r] + bf2f(rka[r]);
                kp[r * 48] = f2bf(kv);
                float vv2 = acc[2][fm][fn][r] + bf2f(rva[r]);
                voa[r] = f2bf(vv2);
            }
            *(ushort4*)&V2T[hb + (long)c * 1024 + rbase] = vo;
        }
    }
}

// ---------------- flash attention, MFMA, bf16, wave-split KV, XCD-swizzled ----------------
// 1D grid 4096 (= 8 b x 8 h x 64 qb). Swizzle: each XCD owns 8 complete (b,h) groups,
// so K/V working sets (192KB each) stay L2-resident per XCD.
__global__ __launch_bounds__(256, 4) void attn_mfma_kernel(
        const u16* __restrict__ Q2H, const u16* __restrict__ K2H,
        const u16* __restrict__ V2T, u16* __restrict__ O) {
    int bid = blockIdx.x;
    int widx = (bid & 7) * 512 + (bid >> 3);   // bijective (4096 % 8 == 0)
    int qb = widx & 63;
    int h  = (widx >> 6) & 7;
    int b  = widx >> 9;
    int tid = threadIdx.x, wave = tid >> 6, lane = tid & 63, g = lane >> 4, l15 = lane & 15;

    __shared__ char smem[13824];
    u16   (*Pl)[16][72]  = (u16(*)[16][72])smem;            // [4][16][72] u16 = 9216 B
    float (*Oc)[16][52]  = (float(*)[16][52])smem;          // [4][16][52] f32 = 13312 B
    float (*MLc)[16][2]  = (float(*)[16][2])(smem + 13312); // 512 B
    const int sw = ((l15 >> 3) & 1) << 5;

    const long bh1024 = (long)(h * 8 + b) * 1024;
    const u16* qptr = Q2H + (bh1024 + qb * 16 + l15) * 48;
    F8 qf0, qf1;
    qf0.q[0] = *(const u64*)(qptr + g * 8);
    qf0.q[1] = *(const u64*)(qptr + g * 8 + 4);
    if (g < 2) {
        qf1.q[0] = *(const u64*)(qptr + 32 + g * 8);
        qf1.q[1] = *(const u64*)(qptr + 32 + g * 8 + 4);
    } else { qf1.q[0] = 0; qf1.q[1] = 0; }

    const u16* vbase = V2T + (long)h * 393216 + (long)b * 49152;  // [48 d][1024 m]

    f32x4 oacc[3] = {};
    float runm = -1e30f, runl = 0.f;

#pragma unroll
    for (int it = 0; it < 4; ++it) {
        const int m0 = wave * 256 + it * 64;
        // ---- QK^T for this wave's 64 keys ----
        f32x4 s[4] = {};
#pragma unroll
        for (int mt = 0; mt < 4; ++mt) {
            const u16* kp = K2H + (bh1024 + m0 + mt * 16 + l15) * 48;
            F8 kf0, kf1;
            kf0.q[0] = *(const u64*)(kp + g * 8);
            kf0.q[1] = *(const u64*)(kp + g * 8 + 4);
            if (g < 2) {
                kf1.q[0] = *(const u64*)(kp + 32 + g * 8);
                kf1.q[1] = *(const u64*)(kp + 32 + g * 8 + 4);
            } else { kf1.q[0] = 0; kf1.q[1] = 0; }
            s[mt] = __builtin_amdgcn_mfma_f32_16x16x32_bf16(kf0.v, qf0.v, s[mt], 0, 0, 0);
            s[mt] = __builtin_amdgcn_mfma_f32_16x16x32_bf16(kf1.v, qf1.v, s[mt], 0, 0, 0);
        }

        // ---- V fragments (independent; latency hides under softmax) ----
        F8 vf[3][2];
#pragma unroll
        for (int dt = 0; dt < 3; ++dt)
#pragma unroll
            for (int ks = 0; ks < 2; ++ks) {
                const u16* vp = vbase + (long)(dt * 16 + l15) * 1024 + m0 + ks * 32 + g * 8;
                vf[dt][ks].q[0] = *(const u64*)vp;
                vf[dt][ks].q[1] = *(const u64*)(vp + 4);
            }

        // ---- online softmax (exp2 domain) ----
        float p[16];
#pragma unroll
        for (int i = 0; i < 16; ++i) p[i] = s[i >> 2][i & 3];
        float pm[8];
#pragma unroll
        for (int i = 0; i < 8; ++i) pm[i] = fmaxf(p[i], p[i + 8]);
#pragma unroll
        for (int st = 4; st > 0; st >>= 1)
#pragma unroll
            for (int i = 0; i < st; ++i) pm[i] = fmaxf(pm[i], pm[i + st]);
        float tmax = pm[0];
        tmax = fmaxf(tmax, __shfl_xor(tmax, 16));
        tmax = fmaxf(tmax, __shfl_xor(tmax, 32));
        if (!__all(tmax <= runm + 8.0f)) {     // defer-max (T13)
            float nm = fmaxf(runm, tmax);
            float corr = __builtin_amdgcn_exp2f(runm - nm);
            runm = nm; runl *= corr;
#pragma unroll
            for (int dt = 0; dt < 3; ++dt) {
                oacc[dt][0] *= corr; oacc[dt][1] *= corr;
                oacc[dt][2] *= corr; oacc[dt][3] *= corr;
            }
        }
        float ps = 0.f;
#pragma unroll
        for (int i = 0; i < 16; ++i) { p[i] = __builtin_amdgcn_exp2f(p[i] - runm); ps += p[i]; }
        ps += __shfl_xor(ps, 16);
        ps += __shfl_xor(ps, 32);
        runl += ps;

        // ---- P -> bf16 -> per-wave LDS redistribution ----
#pragma unroll
        for (int mt = 0; mt < 4; ++mt) {
            u32 wa, wb;
            asm("v_cvt_pk_bf16_f32 %0, %1, %2" : "=v"(wa) : "v"(p[mt * 4]), "v"(p[mt * 4 + 1]));
            asm("v_cvt_pk_bf16_f32 %0, %1, %2" : "=v"(wb) : "v"(p[mt * 4 + 2]), "v"(p[mt * 4 + 3]));
            *(u64*)&Pl[wave][l15][(mt * 16 + g * 4) ^ sw] = ((u64)wb << 32) | wa;
        }
        F8 pb[2];
#pragma unroll
        for (int ks = 0; ks < 2; ++ks) {
            pb[ks].q[0] = *(const u64*)&Pl[wave][l15][(ks * 32 + g * 8) ^ sw];
            pb[ks].q[1] = *(const u64*)&Pl[wave][l15][((ks * 32 + g * 8) + 4) ^ sw];
        }

        // ---- PV ----
#pragma unroll
        for (int dt = 0; dt < 3; ++dt) {
            oacc[dt] = __builtin_amdgcn_mfma_f32_16x16x32_bf16(vf[dt][0].v, pb[0].v, oacc[dt], 0, 0, 0);
            oacc[dt] = __builtin_amdgcn_mfma_f32_16x16x32_bf16(vf[dt][1].v, pb[1].v, oacc[dt], 0, 0, 0);
        }
    }

    // ---- cross-wave combine ----
    __syncthreads();   // all waves done with Pl (unioned with Oc)
#pragma unroll
    for (int dt = 0; dt < 3; ++dt)
#pragma unroll
        for (int r = 0; r < 4; ++r)
            Oc[wave][l15][dt * 16 + g * 4 + r] = oacc[dt][r];
    if (g == 0) { MLc[wave][l15][0] = runm; MLc[wave][l15][1] = runl; }
    __syncthreads();

    if (wave == 0) {
        float mm[4], cc[4];
#pragma unroll
        for (int w = 0; w < 4; ++w) mm[w] = MLc[w][l15][0];
        float M = fmaxf(fmaxf(mm[0], mm[1]), fmaxf(mm[2], mm[3]));
        float LL = 0.f;
#pragma unroll
        for (int w = 0; w < 4; ++w) {
            cc[w] = __builtin_amdgcn_exp2f(mm[w] - M);
            LL += cc[w] * MLc[w][l15][1];
        }
        float inv = 1.f / LL;
        u16* op = O + ((long)b * NTOK + qb * 16 + l15) * D_MODEL + h * DIM_HEAD;
#pragma unroll
        for (int dt = 0; dt < 3; ++dt) {
            ushort4 o;
#pragma unroll
            for (int r = 0; r < 4; ++r) {
                int d = dt * 16 + g * 4 + r;
                float v = cc[0] * Oc[0][l15][d] + cc[1] * Oc[1][l15][d]
                        + cc[2] * Oc[2][l15][d] + cc[3] * Oc[3][l15][d];
                ((u16*)&o)[r] = f2bf(v * inv);
            }
            *(ushort4*)(op + dt * 16 + g * 4) = o;
        }
    }
}

// ---------------- layernorm (+optional residual, optional bf16 copy) ----------------
__global__ __launch_bounds__(128) void ln_kernel(
        const float* __restrict__ X, const float* __restrict__ Rb,
        const float* __restrict__ g, const float* __restrict__ be,
        float* __restrict__ O, u16* __restrict__ Obf, int hasRes) {
    int row = blockIdx.x;
    int tid = threadIdx.x;
    const float* x = X + (long)row * D_MODEL;
    float v[3];
#pragma unroll
    for (int l = 0; l < 3; ++l) {
        int c = tid + l * 128;
        v[l] = x[c];
        if (hasRes) v[l] += Rb[(long)row * D_MODEL + c];
    }
    __shared__ float red[128];
    float s = v[0] + v[1] + v[2];
    red[tid] = s; __syncthreads();
    for (int st = 64; st > 0; st >>= 1) {
        if (tid < st) red[tid] += red[tid + st];
        __syncthreads();
    }
    float mean = red[0] * (1.f / 384.f);
    __syncthreads();
    float sq = 0.f;
#pragma unroll
    for (int l = 0; l < 3; ++l) { float d = v[l] - mean; sq += d * d; }
    red[tid] = sq; __syncthreads();
    for (int st = 64; st > 0; st >>= 1) {
        if (tid < st) red[tid] += red[tid + st];
        __syncthreads();
    }
    float rstd = rsqrtf(red[0] * (1.f / 384.f) + LN_EPS);
#pragma unroll
    for (int l = 0; l < 3; ++l) {
        int c = tid + l * 128;
        float o = (v[l] - mean) * rstd * g[c] + be[c];
        O[(long)row * D_MODEL + c] = o;
        if (Obf) Obf[(long)row * D_MODEL + c] = f2bf(o);
    }
}

extern "C" void kernel_launch(void* const* d_in, const int* in_sizes, int n_in,
                              void* d_out, int out_size, void* d_ws, size_t ws_size,
                              hipStream_t stream) {
    const float* src   = (const float*)d_in[0];
    const float* pos   = (const float*)d_in[1];
    const float* table = (const float*)d_in[2];
    const float* Wq  = (const float*)d_in[3];
    const float* Wk  = (const float*)d_in[4];
    const float* Wv  = (const float*)d_in[5];
    const float* Wo  = (const float*)d_in[6];
    const float* bo  = (const float*)d_in[7];
    const float* W1  = (const float*)d_in[8];
    const float* b1  = (const float*)d_in[9];
    const float* W2  = (const float*)d_in[10];
    const float* b2  = (const float*)d_in[11];
    const float* g1  = (const float*)d_in[12];
    const float* be1 = (const float*)d_in[13];
    const float* g2  = (const float*)d_in[14];
    const float* be2 = (const float*)d_in[15];
    float* out = (float*)d_out;
    u16* ws = (u16*)d_ws;

    const long SZ = (long)BATCH * NTOK * D_MODEL;  // 3,145,728

    u16* WqT  = ws + 0;          // WqT,WkT contiguous => one merged Q+K projection (Nd=768)
    u16* WkT  = ws + 147456;
    u16* WvT  = ws + 294912;
    u16* WoT  = ws + 442368;
    u16* W1T  = ws + 589824;
    u16* W2T  = ws + 1179648;
    u16* QKin = ws + 1769472;
    u16* SRCB = ws + 4915200;
    u16* QtH  = ws + 8060928;    // [8][384][1024]; KtH contiguous after (merged store target)
    u16* KtH  = ws + 11206656;
    u16* VtH  = ws + 14352384;
    u16* BT   = ws + 17498112;   // [8][1024][1024]
    u16* Q2H  = ws + 25886720;   // head-major [(h*8+b)][1024][48], pre-scaled
    u16* K2H  = ws + 29032448;
    u16* V2T  = ws + 32178176;   // [8][384][1024]
    u16* ATT  = ws + 35323904;
    // aliases (lifetimes disjoint):
    float* Of  = (float*)(ws + 8060928);   // pre-LN1 f32 (over QtH+KtH, dead after bias3)
    float* xf  = (float*)(ws + 14352384);  // post-LN1 f32 (over VtH+BT head)
    u16*   xbf = QKin;                     // post-LN1 bf16 (QKin dead after projections)
    u16*   hbf = Q2H;                      // FF hidden [8192][1536] (over Q2H..ATT, dead by FF1)
    float* ff  = (float*)(ws + 8060928);   // pre-LN2 f32 (over Of, dead after LN1)

    // 1. adds + casts
    add_cast_kernel<<<(int)(SZ / 4 + 255) / 256, 256, 0, stream>>>(
        (const float4*)src, (const float4*)pos, (ushort4*)QKin, (ushort4*)SRCB, (int)(SZ / 4));
    // 2. weight transposes
    dim3 tb(32, 8);
    castT4_kernel<<<dim3(12, 12, 4), tb, 0, stream>>>(Wq, Wk, Wv, Wo, WqT, WkT, WvT, WoT);
    castT_kernel<<<dim3(48, 12), tb, 0, stream>>>(W1, W1T, 384, 1536);
    castT_kernel<<<dim3(12, 48), tb, 0, stream>>>(W2, W2T, 1536, 384);
    // 3. relative bias (transposed, bf16)
    biasT_bf16_kernel<<<32768, 256, 0, stream>>>(table, BT);
    // 4. projections -> head-major transposed bf16.  Q and K merged (Nd=768, one A-stage).
    mgemm_kernel<8, false, false, false><<<dim3(12, 128, 1), 256, 0, stream>>>(
        QKin, WqT, nullptr, nullptr, QtH, nullptr, nullptr,
        8192, 384, 768, 384, 384, 0, 0);
    mgemm_kernel<8, false, false, false><<<dim3(6, 128, 1), 256, 0, stream>>>(
        SRCB, WvT, nullptr, nullptr, VtH, nullptr, nullptr,
        8192, 384, 384, 384, 384, 0, 0);
    // 5. fused bias matmuls -> Q2H (scaled), K2H, V2T   (XCD-swizzled, 1 head per XCD)
    bias3_kernel<<<768, 256, 0, stream>>>(BT, QtH, KtH, VtH, Q2H, K2H, V2T);
    // 6. attention (wave-split KV, XCD-swizzled)
    attn_mfma_kernel<<<4096, 256, 0, stream>>>(Q2H, K2H, V2T, ATT);
    // 7. o = att @ Wo + bo + src
    mgemm_kernel<1, true, true, false><<<dim3(6, 128, 1), 256, 0, stream>>>(
        ATT, WoT, Of, nullptr, nullptr, bo, src,
        8192, 384, 384, 384, 384, 384, 384);
    // 8. x = LN1(o)
    ln_kernel<<<8192, 128, 0, stream>>>(Of, nullptr, g1, be1, xf, xbf, 0);
    // 9. h = gelu(x @ W1 + b1)
    mgemm_kernel<2, true, false, true><<<dim3(24, 128, 1), 256, 0, stream>>>(
        xbf, W1T, nullptr, hbf, nullptr, b1, nullptr,
        8192, 384, 1536, 384, 384, 1536, 0);
    // 10. ff = h @ W2 + b2 + x
    mgemm_kernel<1, true, true, false><<<dim3(6, 128, 1), 256, 0, stream>>>(
        hbf, W2T, ff, nullptr, nullptr, b2, xf,
        8192, 1536, 384, 1536, 1536, 384, 384);
    // 11. out = LN2(ff)
    ln_kernel<<<8192, 128, 0, stream>>>(ff, nullptr, g2, be2, out, nullptr, 0);
}

// Round 9
// 232.116 us; speedup vs baseline: 22.2712x; 1.1065x over previous
//
#include <hip/hip_runtime.h>
#include <math.h>

#define D_MODEL 384
#define HEADS 8
#define DIM_HEAD 48
#define NTOK 1024
#define BATCH 8
#define D_FF 1536
#define LN_EPS 1e-5f

typedef unsigned short u16;
typedef unsigned int u32;
typedef unsigned long long u64;
typedef short short8 __attribute__((ext_vector_type(8)));
typedef float f32x4 __attribute__((ext_vector_type(4)));

union F8 { short8 v; u64 q[2]; u16 u[8]; uint4 u4; };

__device__ __forceinline__ u16 f2bf(float f) {
    union { float f; unsigned u; } c; c.f = f;
    unsigned r = c.u + 0x7FFFu + ((c.u >> 16) & 1u);
    return (u16)(r >> 16);
}
__device__ __forceinline__ float bf2f(u16 u) {
    union { unsigned u; float f; } c; c.u = ((unsigned)u) << 16; return c.f;
}

// ---------------- add + cast (QKin = bf16(src+pos), SRCB = bf16(src)) ----------------
__global__ __launch_bounds__(256) void add_cast_kernel(
        const float4* __restrict__ a, const float4* __restrict__ b,
        ushort4* __restrict__ o1, ushort4* __restrict__ o2, int n4) {
    int i = blockIdx.x * blockDim.x + threadIdx.x;
    if (i >= n4) return;
    float4 x = a[i], y = b[i];
    ushort4 u1, u2;
    u1.x = f2bf(x.x + y.x); u1.y = f2bf(x.y + y.y); u1.z = f2bf(x.z + y.z); u1.w = f2bf(x.w + y.w);
    u2.x = f2bf(x.x); u2.y = f2bf(x.y); u2.z = f2bf(x.z); u2.w = f2bf(x.w);
    o1[i] = u1; o2[i] = u2;
}

// ---------------- 4x square transpose + cast (384x384), z-batched ----------------
__global__ __launch_bounds__(256) void castT4_kernel(
        const float* __restrict__ i0, const float* __restrict__ i1,
        const float* __restrict__ i2, const float* __restrict__ i3,
        u16* __restrict__ o0, u16* __restrict__ o1,
        u16* __restrict__ o2, u16* __restrict__ o3) {
    const float* in  = (blockIdx.z == 0) ? i0 : (blockIdx.z == 1) ? i1 : (blockIdx.z == 2) ? i2 : i3;
    u16*         out = (blockIdx.z == 0) ? o0 : (blockIdx.z == 1) ? o1 : (blockIdx.z == 2) ? o2 : o3;
    __shared__ float t[32][33];
    int c0 = blockIdx.x * 32, r0 = blockIdx.y * 32;
    int tx = threadIdx.x, ty = threadIdx.y;  // 32 x 8
    for (int i = ty; i < 32; i += 8)
        t[i][tx] = in[(long)(r0 + i) * 384 + c0 + tx];
    __syncthreads();
    for (int i = ty; i < 32; i += 8)
        out[(long)(c0 + i) * 384 + r0 + tx] = f2bf(t[tx][i]);
}

// ---------------- transpose + cast: out[c][r] = bf16(in[r][c]) ----------------
__global__ __launch_bounds__(256) void castT_kernel(
        const float* __restrict__ in, u16* __restrict__ out, int R, int C) {
    __shared__ float t[32][33];
    int c0 = blockIdx.x * 32, r0 = blockIdx.y * 32;
    int tx = threadIdx.x, ty = threadIdx.y;  // 32 x 8
    for (int i = ty; i < 32; i += 8)
        t[i][tx] = in[(long)(r0 + i) * C + c0 + tx];
    __syncthreads();
    for (int i = ty; i < 32; i += 8)
        out[(long)(c0 + i) * R + r0 + tx] = f2bf(t[tx][i]);
}

// ---------------- relative bias, transposed, bf16: BT[h][n][m] = bias[h][m][n] ----------------
__global__ __launch_bounds__(256) void biasT_bf16_kernel(const float* __restrict__ table,
                                                         u16* __restrict__ BT) {
    long i = (long)blockIdx.x * blockDim.x + threadIdx.x;
    const long total = (long)HEADS * NTOK * NTOK;
    if (i >= total) return;
    int m = (int)(i & 1023);
    int n = (int)((i >> 10) & 1023);
    int h = (int)(i >> 20);
    int dy = (m >> 5) - (n >> 5) + 31;
    int dx = (m & 31) - (n & 31) + 31;
    BT[i] = f2bf(table[(dy * 63 + dx) * HEADS + h]);
}

// ---------------- MFMA GEMM ----------------
// C[M x N] = A[M x K](bf16, row-major) @ B (given as Bt[N x K] bf16, row-major)
// OUTMODE bits: 1 = f32 store, 2 = bf16 store, 8 = head-transposed bf16 store
template<int OUTMODE, bool HAS_BIAS, bool HAS_RES, bool GELU_>
__global__ __launch_bounds__(256) void mgemm_kernel(
        const u16* __restrict__ Ab, const u16* __restrict__ Btb,
        float* __restrict__ Cf, u16* __restrict__ Cb, u16* __restrict__ Ct,
        const float* __restrict__ bias, const float* __restrict__ Rb,
        int M, int Kd, int Nd, int lda, int ldbt, int ldc, int ldr) {
    const u16* A  = Ab;
    const u16* Bt = Btb;

    __shared__ u16 As[64][40];
    __shared__ u16 Bs[64][40];
    int tid = threadIdx.x;
    int wave = tid >> 6, lane = tid & 63, g = lane >> 4, l15 = lane & 15;
    int wm = wave >> 1, wn = wave & 1;
    int row0 = blockIdx.y * 64, col0 = blockIdx.x * 64;

    f32x4 acc[2][2] = {};

    int sr = tid >> 2, sch = tid & 3;
    const u16* aSrc = A + (long)(row0 + sr) * lda + sch * 8;
    const u16* bSrc = Bt + (long)(col0 + sr) * ldbt + sch * 8;

    for (int k0 = 0; k0 < Kd; k0 += 32) {
        {
            uint4 va = *(const uint4*)(aSrc + k0);
            uint4 vb = *(const uint4*)(bSrc + k0);
            *(u64*)&As[sr][sch * 8]     = ((const u64*)&va)[0];
            *(u64*)&As[sr][sch * 8 + 4] = ((const u64*)&va)[1];
            *(u64*)&Bs[sr][sch * 8]     = ((const u64*)&vb)[0];
            *(u64*)&Bs[sr][sch * 8 + 4] = ((const u64*)&vb)[1];
        }
        __syncthreads();
        F8 af[2], bfr[2];
#pragma unroll
        for (int fm = 0; fm < 2; ++fm) {
            int r = wm * 32 + fm * 16 + l15;
            af[fm].q[0] = *(const u64*)&As[r][g * 8];
            af[fm].q[1] = *(const u64*)&As[r][g * 8 + 4];
        }
#pragma unroll
        for (int fn = 0; fn < 2; ++fn) {
            int c = wn * 32 + fn * 16 + l15;
            bfr[fn].q[0] = *(const u64*)&Bs[c][g * 8];
            bfr[fn].q[1] = *(const u64*)&Bs[c][g * 8 + 4];
        }
#pragma unroll
        for (int fm = 0; fm < 2; ++fm)
#pragma unroll
            for (int fn = 0; fn < 2; ++fn)
                acc[fm][fn] = __builtin_amdgcn_mfma_f32_16x16x32_bf16(
                    af[fm].v, bfr[fn].v, acc[fm][fn], 0, 0, 0);
        __syncthreads();
    }

#pragma unroll
    for (int fm = 0; fm < 2; ++fm) {
        int rbase = row0 + wm * 32 + fm * 16 + g * 4;
#pragma unroll
        for (int fn = 0; fn < 2; ++fn) {
            int c = col0 + wn * 32 + fn * 16 + l15;
            if (c < Nd) {
                float bv = HAS_BIAS ? bias[c] : 0.f;
                float vs[4];
#pragma unroll
                for (int r = 0; r < 4; ++r) {
                    float v = acc[fm][fn][r] + bv;
                    if (HAS_RES) v += Rb[(long)(rbase + r) * ldr + c];
                    if (GELU_)   v = 0.5f * v * (1.f + erff(v * 0.70710678118654752f));
                    vs[r] = v;
                    if (OUTMODE & 1) Cf[(long)(rbase + r) * ldc + c] = v;
                    if (OUTMODE & 2) Cb[(long)(rbase + r) * ldc + c] = f2bf(v);
                }
                if (OUTMODE & 8) {
                    int hh2 = (c * 683) >> 15; int dd = c - hh2 * 48;   // valid for c < 768
                    int bb2 = rbase >> 10;     int mm = rbase & 1023;
                    ushort4 o;
                    o.x = f2bf(vs[0]); o.y = f2bf(vs[1]); o.z = f2bf(vs[2]); o.w = f2bf(vs[3]);
                    *(ushort4*)&Ct[(long)hh2 * 393216 + (long)(bb2 * 48 + dd) * 1024 + mm] = o;
                }
            }
        }
    }
}

// ---------------- fused bias matmuls -> MFMA-fragment-tiled Q/K/V ----------------
// 1D grid 768, XCD-swizzled (one head per XCD).
// Q2H/K2H: [bh][tok-tile tb][ks2][g4][l15 16][e8]  (k padded 48->64, pads zeroed; Q pre-scaled)
// V2T:     [bh][m-tile mb16][dt3][ks2][g4][l15 16][e8]
__global__ __launch_bounds__(256) void bias3_kernel(
        const u16* __restrict__ BT, const u16* __restrict__ QtH,
        const u16* __restrict__ KtH, const u16* __restrict__ VtH,
        u16* __restrict__ Q2H, u16* __restrict__ K2H, u16* __restrict__ V2T) {
    int bid = blockIdx.x;
    int widx = (bid & 7) * 96 + (bid >> 3);   // bijective (768 % 8 == 0)
    int h = widx / 96;
    int rem = widx - h * 96;
    int ry = rem / 6, cx = rem - ry * 6;
    const long hb = (long)h * 393216;
    const u16* A = BT + (long)h * 1048576;
    __shared__ u16 As[64][40];
    __shared__ u16 Bq[64][40], Bk[64][40], Bv[64][40];
    int tid = threadIdx.x, wave = tid >> 6, lane = tid & 63, g = lane >> 4, l15 = lane & 15;
    int wm = wave >> 1, wn = wave & 1;
    int row0 = ry * 64, col0 = cx * 64;
    f32x4 acc[3][2][2] = {};
    int sr = tid >> 2, sch = tid & 3;
    const u16* aSrc = A   + (long)(row0 + sr) * 1024 + sch * 8;
    const u16* qSrc = QtH + hb + (long)(col0 + sr) * 1024 + sch * 8;
    const u16* kSrc = KtH + hb + (long)(col0 + sr) * 1024 + sch * 8;
    const u16* vSrc = VtH + hb + (long)(col0 + sr) * 1024 + sch * 8;

    for (int k0 = 0; k0 < 1024; k0 += 32) {
        uint4 va = *(const uint4*)(aSrc + k0);
        uint4 vq = *(const uint4*)(qSrc + k0);
        uint4 vk = *(const uint4*)(kSrc + k0);
        uint4 vv = *(const uint4*)(vSrc + k0);
        *(u64*)&As[sr][sch * 8] = ((const u64*)&va)[0]; *(u64*)&As[sr][sch * 8 + 4] = ((const u64*)&va)[1];
        *(u64*)&Bq[sr][sch * 8] = ((const u64*)&vq)[0]; *(u64*)&Bq[sr][sch * 8 + 4] = ((const u64*)&vq)[1];
        *(u64*)&Bk[sr][sch * 8] = ((const u64*)&vk)[0]; *(u64*)&Bk[sr][sch * 8 + 4] = ((const u64*)&vk)[1];
        *(u64*)&Bv[sr][sch * 8] = ((const u64*)&vv)[0]; *(u64*)&Bv[sr][sch * 8 + 4] = ((const u64*)&vv)[1];
        __syncthreads();
        F8 af0, af1, b0, b1;
        af0.q[0] = *(const u64*)&As[wm * 32 + l15][g * 8];
        af0.q[1] = *(const u64*)&As[wm * 32 + l15][g * 8 + 4];
        af1.q[0] = *(const u64*)&As[wm * 32 + 16 + l15][g * 8];
        af1.q[1] = *(const u64*)&As[wm * 32 + 16 + l15][g * 8 + 4];
        b0.q[0] = *(const u64*)&Bq[wn * 32 + l15][g * 8];
        b0.q[1] = *(const u64*)&Bq[wn * 32 + l15][g * 8 + 4];
        b1.q[0] = *(const u64*)&Bq[wn * 32 + 16 + l15][g * 8];
        b1.q[1] = *(const u64*)&Bq[wn * 32 + 16 + l15][g * 8 + 4];
        acc[0][0][0] = __builtin_amdgcn_mfma_f32_16x16x32_bf16(af0.v, b0.v, acc[0][0][0], 0, 0, 0);
        acc[0][0][1] = __builtin_amdgcn_mfma_f32_16x16x32_bf16(af0.v, b1.v, acc[0][0][1], 0, 0, 0);
        acc[0][1][0] = __builtin_amdgcn_mfma_f32_16x16x32_bf16(af1.v, b0.v, acc[0][1][0], 0, 0, 0);
        acc[0][1][1] = __builtin_amdgcn_mfma_f32_16x16x32_bf16(af1.v, b1.v, acc[0][1][1], 0, 0, 0);
        b0.q[0] = *(const u64*)&Bk[wn * 32 + l15][g * 8];
        b0.q[1] = *(const u64*)&Bk[wn * 32 + l15][g * 8 + 4];
        b1.q[0] = *(const u64*)&Bk[wn * 32 + 16 + l15][g * 8];
        b1.q[1] = *(const u64*)&Bk[wn * 32 + 16 + l15][g * 8 + 4];
        acc[1][0][0] = __builtin_amdgcn_mfma_f32_16x16x32_bf16(af0.v, b0.v, acc[1][0][0], 0, 0, 0);
        acc[1][0][1] = __builtin_amdgcn_mfma_f32_16x16x32_bf16(af0.v, b1.v, acc[1][0][1], 0, 0, 0);
        acc[1][1][0] = __builtin_amdgcn_mfma_f32_16x16x32_bf16(af1.v, b0.v, acc[1][1][0], 0, 0, 0);
        acc[1][1][1] = __builtin_amdgcn_mfma_f32_16x16x32_bf16(af1.v, b1.v, acc[1][1][1], 0, 0, 0);
        b0.q[0] = *(const u64*)&Bv[wn * 32 + l15][g * 8];
        b0.q[1] = *(const u64*)&Bv[wn * 32 + l15][g * 8 + 4];
        b1.q[0] = *(const u64*)&Bv[wn * 32 + 16 + l15][g * 8];
        b1.q[1] = *(const u64*)&Bv[wn * 32 + 16 + l15][g * 8 + 4];
        acc[2][0][0] = __builtin_amdgcn_mfma_f32_16x16x32_bf16(af0.v, b0.v, acc[2][0][0], 0, 0, 0);
        acc[2][0][1] = __builtin_amdgcn_mfma_f32_16x16x32_bf16(af0.v, b1.v, acc[2][0][1], 0, 0, 0);
        acc[2][1][0] = __builtin_amdgcn_mfma_f32_16x16x32_bf16(af1.v, b0.v, acc[2][1][0], 0, 0, 0);
        acc[2][1][1] = __builtin_amdgcn_mfma_f32_16x16x32_bf16(af1.v, b1.v, acc[2][1][1], 0, 0, 0);
        __syncthreads();
    }

    // Q pre-scale: 48^-0.5 * log2(e)  (attention softmax runs in exp2 domain)
    const float qsc = 0.14433756729740643f * 1.4426950408889634f;
#pragma unroll
    for (int fm = 0; fm < 2; ++fm) {
        int rbase = row0 + wm * 32 + fm * 16 + g * 4;  // token (n for Q/K, m for V)
#pragma unroll
        for (int fn = 0; fn < 2; ++fn) {
            int c = col0 + wn * 32 + fn * 16 + l15;    // 0..383 = b*48+d
            int b2 = (c * 683) >> 15, d = c - b2 * 48;
            long bh = (long)h * 8 + b2;
            ushort4 rq = *(const ushort4*)&QtH[hb + (long)c * 1024 + rbase];
            ushort4 rk = *(const ushort4*)&KtH[hb + (long)c * 1024 + rbase];
            ushort4 rv = *(const ushort4*)&VtH[hb + (long)c * 1024 + rbase];
            const u16* rqa = (const u16*)&rq;
            const u16* rka = (const u16*)&rk;
            const u16* rva = (const u16*)&rv;
            // Q/K fragment-tile address: tile (bh, rbase>>4), slot (ks, g3), lane (token&15, e)
            int ks = d >> 5, g3 = (d >> 3) & 3, e = d & 7;
            long qbase = ((bh * 64 + (rbase >> 4)) * 8 + ks * 4 + g3) * 128
                       + (rbase & 15) * 8 + e;
            ushort4 vo;
            u16* voa = (u16*)&vo;
#pragma unroll
            for (int r = 0; r < 4; ++r) {
                float qv = acc[0][fm][fn][r] + bf2f(rqa[r]);
                Q2H[qbase + r * 8] = f2bf(qv * qsc);
                float kv = acc[1][fm][fn][r] + bf2f(rka[r]);
                K2H[qbase + r * 8] = f2bf(kv);
                voa[r] = f2bf(acc[2][fm][fn][r] + bf2f(rva[r]));
            }
            // V fragment-tile (token m = rbase..rbase+3 contiguous within one 8-chunk)
            long vaddr = ((((bh * 16 + (rbase >> 6)) * 3 + (d >> 4)) * 2
                          + ((rbase >> 5) & 1)) * 4 + ((rbase >> 3) & 3)) * 128
                       + (d & 15) * 8 + (rbase & 7);
            *(ushort4*)&V2T[vaddr] = vo;
            // zero k-pads (d_pad = 48+d for d<16 -> ks=1, g3=2..3)
            if (d < 16) {
                long pbase = ((bh * 64 + (rbase >> 4)) * 8 + 4 + 2 + (d >> 3)) * 128
                           + (rbase & 15) * 8 + (d & 7);
#pragma unroll
                for (int r = 0; r < 4; ++r) {
                    Q2H[pbase + r * 8] = 0;
                    K2H[pbase + r * 8] = 0;
                }
            }
        }
    }
}

// ---------------- flash attention, MFMA, bf16, wave-split KV, fragment-tiled ----------------
// 1D grid 4096 XCD-swizzled. All Q/K/V loads are single coalesced 16B/lane (1KB/instr).
__global__ __launch_bounds__(256, 4) void attn_mfma_kernel(
        const u16* __restrict__ Q2H, const u16* __restrict__ K2H,
        const u16* __restrict__ V2T, u16* __restrict__ O) {
    int bid = blockIdx.x;
    int widx = (bid & 7) * 512 + (bid >> 3);   // bijective (4096 % 8 == 0)
    int qb = widx & 63;
    int h  = (widx >> 6) & 7;
    int b  = widx >> 9;
    int tid = threadIdx.x, wave = tid >> 6, lane = tid & 63, g = lane >> 4, l15 = lane & 15;

    __shared__ char smem[13824];
    u16   (*Pl)[16][72]  = (u16(*)[16][72])smem;            // [4][16][72] u16 = 9216 B
    float (*Oc)[16][52]  = (float(*)[16][52])smem;          // [4][16][52] f32 = 13312 B
    float (*MLc)[16][2]  = (float(*)[16][2])(smem + 13312); // 512 B
    const int sw = ((l15 >> 3) & 1) << 5;
    const int loff = (g * 16 + l15) * 8;   // fragment lane offset (u16)

    const long bh = (long)(h * 8 + b);
    const u16* qtile = Q2H + (bh * 64 + qb) * 1024;
    F8 qf0, qf1;
    qf0.u4 = *(const uint4*)(qtile + loff);
    qf1.u4 = *(const uint4*)(qtile + 512 + loff);

    f32x4 oacc[3] = {};
    float runm = -1e30f, runl = 0.f;

#pragma unroll
    for (int it = 0; it < 4; ++it) {
        // ---- QK^T for this wave's 64 keys (4 key-tiles of 16) ----
        f32x4 s[4] = {};
#pragma unroll
        for (int mt = 0; mt < 4; ++mt) {
            const u16* ktile = K2H + (bh * 64 + wave * 16 + it * 4 + mt) * 1024;
            F8 kf0, kf1;
            kf0.u4 = *(const uint4*)(ktile + loff);
            kf1.u4 = *(const uint4*)(ktile + 512 + loff);
            s[mt] = __builtin_amdgcn_mfma_f32_16x16x32_bf16(kf0.v, qf0.v, s[mt], 0, 0, 0);
            s[mt] = __builtin_amdgcn_mfma_f32_16x16x32_bf16(kf1.v, qf1.v, s[mt], 0, 0, 0);
        }

        // ---- V fragments (independent; latency hides under softmax) ----
        const u16* vtile = V2T + (bh * 16 + wave * 4 + it) * 3072;
        F8 vf[3][2];
#pragma unroll
        for (int dt = 0; dt < 3; ++dt)
#pragma unroll
            for (int ks = 0; ks < 2; ++ks)
                vf[dt][ks].u4 = *(const uint4*)(vtile + (dt * 2 + ks) * 512 + loff);

        // ---- online softmax (exp2 domain; scale*log2e pre-folded into Q) ----
        float p[16];
#pragma unroll
        for (int i = 0; i < 16; ++i) p[i] = s[i >> 2][i & 3];
        float pm[8];
#pragma unroll
        for (int i = 0; i < 8; ++i) pm[i] = fmaxf(p[i], p[i + 8]);
#pragma unroll
        for (int st = 4; st > 0; st >>= 1)
#pragma unroll
            for (int i = 0; i < st; ++i) pm[i] = fmaxf(pm[i], pm[i + st]);
        float tmax = pm[0];
        tmax = fmaxf(tmax, __shfl_xor(tmax, 16));
        tmax = fmaxf(tmax, __shfl_xor(tmax, 32));
        if (!__all(tmax <= runm + 8.0f)) {     // defer-max (T13)
            float nm = fmaxf(runm, tmax);
            float corr = __builtin_amdgcn_exp2f(runm - nm);
            runm = nm; runl *= corr;
#pragma unroll
            for (int dt = 0; dt < 3; ++dt) {
                oacc[dt][0] *= corr; oacc[dt][1] *= corr;
                oacc[dt][2] *= corr; oacc[dt][3] *= corr;
            }
        }
        float ps = 0.f;
#pragma unroll
        for (int i = 0; i < 16; ++i) { p[i] = __builtin_amdgcn_exp2f(p[i] - runm); ps += p[i]; }
        ps += __shfl_xor(ps, 16);
        ps += __shfl_xor(ps, 32);
        runl += ps;

        // ---- P -> bf16 -> per-wave LDS redistribution ----
#pragma unroll
        for (int mt = 0; mt < 4; ++mt) {
            u32 wa, wb;
            asm("v_cvt_pk_bf16_f32 %0, %1, %2" : "=v"(wa) : "v"(p[mt * 4]), "v"(p[mt * 4 + 1]));
            asm("v_cvt_pk_bf16_f32 %0, %1, %2" : "=v"(wb) : "v"(p[mt * 4 + 2]), "v"(p[mt * 4 + 3]));
            *(u64*)&Pl[wave][l15][(mt * 16 + g * 4) ^ sw] = ((u64)wb << 32) | wa;
        }
        F8 pb[2];
#pragma unroll
        for (int ks = 0; ks < 2; ++ks) {
            pb[ks].q[0] = *(const u64*)&Pl[wave][l15][(ks * 32 + g * 8) ^ sw];
            pb[ks].q[1] = *(const u64*)&Pl[wave][l15][((ks * 32 + g * 8) + 4) ^ sw];
        }

        // ---- PV ----
#pragma unroll
        for (int dt = 0; dt < 3; ++dt) {
            oacc[dt] = __builtin_amdgcn_mfma_f32_16x16x32_bf16(vf[dt][0].v, pb[0].v, oacc[dt], 0, 0, 0);
            oacc[dt] = __builtin_amdgcn_mfma_f32_16x16x32_bf16(vf[dt][1].v, pb[1].v, oacc[dt], 0, 0, 0);
        }
    }

    // ---- cross-wave combine ----
    __syncthreads();   // all waves done with Pl (unioned with Oc)
#pragma unroll
    for (int dt = 0; dt < 3; ++dt)
#pragma unroll
        for (int r = 0; r < 4; ++r)
            Oc[wave][l15][dt * 16 + g * 4 + r] = oacc[dt][r];
    if (g == 0) { MLc[wave][l15][0] = runm; MLc[wave][l15][1] = runl; }
    __syncthreads();

    if (wave == 0) {
        float mm[4], cc[4];
#pragma unroll
        for (int w = 0; w < 4; ++w) mm[w] = MLc[w][l15][0];
        float M = fmaxf(fmaxf(mm[0], mm[1]), fmaxf(mm[2], mm[3]));
        float LL = 0.f;
#pragma unroll
        for (int w = 0; w < 4; ++w) {
            cc[w] = __builtin_amdgcn_exp2f(mm[w] - M);
            LL += cc[w] * MLc[w][l15][1];
        }
        float inv = 1.f / LL;
        u16* op = O + ((long)b * NTOK + qb * 16 + l15) * D_MODEL + h * DIM_HEAD;
#pragma unroll
        for (int dt = 0; dt < 3; ++dt) {
            ushort4 o;
#pragma unroll
            for (int r = 0; r < 4; ++r) {
                int d = dt * 16 + g * 4 + r;
                float v = cc[0] * Oc[0][l15][d] + cc[1] * Oc[1][l15][d]
                        + cc[2] * Oc[2][l15][d] + cc[3] * Oc[3][l15][d];
                ((u16*)&o)[r] = f2bf(v * inv);
            }
            *(ushort4*)(op + dt * 16 + g * 4) = o;
        }
    }
}

// ---------------- layernorm (+optional residual, optional bf16 copy) ----------------
__global__ __launch_bounds__(128) void ln_kernel(
        const float* __restrict__ X, const float* __restrict__ Rb,
        const float* __restrict__ g, const float* __restrict__ be,
        float* __restrict__ O, u16* __restrict__ Obf, int hasRes) {
    int row = blockIdx.x;
    int tid = threadIdx.x;
    const float* x = X + (long)row * D_MODEL;
    float v[3];
#pragma unroll
    for (int l = 0; l < 3; ++l) {
        int c = tid + l * 128;
        v[l] = x[c];
        if (hasRes) v[l] += Rb[(long)row * D_MODEL + c];
    }
    __shared__ float red[128];
    float s = v[0] + v[1] + v[2];
    red[tid] = s; __syncthreads();
    for (int st = 64; st > 0; st >>= 1) {
        if (tid < st) red[tid] += red[tid + st];
        __syncthreads();
    }
    float mean = red[0] * (1.f / 384.f);
    __syncthreads();
    float sq = 0.f;
#pragma unroll
    for (int l = 0; l < 3; ++l) { float d = v[l] - mean; sq += d * d; }
    red[tid] = sq; __syncthreads();
    for (int st = 64; st > 0; st >>= 1) {
        if (tid < st) red[tid] += red[tid + st];
        __syncthreads();
    }
    float rstd = rsqrtf(red[0] * (1.f / 384.f) + LN_EPS);
#pragma unroll
    for (int l = 0; l < 3; ++l) {
        int c = tid + l * 128;
        float o = (v[l] - mean) * rstd * g[c] + be[c];
        O[(long)row * D_MODEL + c] = o;
        if (Obf) Obf[(long)row * D_MODEL + c] = f2bf(o);
    }
}

extern "C" void kernel_launch(void* const* d_in, const int* in_sizes, int n_in,
                              void* d_out, int out_size, void* d_ws, size_t ws_size,
                              hipStream_t stream) {
    const float* src   = (const float*)d_in[0];
    const float* pos   = (const float*)d_in[1];
    const float* table = (const float*)d_in[2];
    const float* Wq  = (const float*)d_in[3];
    const float* Wk  = (const float*)d_in[4];
    const float* Wv  = (const float*)d_in[5];
    const float* Wo  = (const float*)d_in[6];
    const float* bo  = (const float*)d_in[7];
    const float* W1  = (const float*)d_in[8];
    const float* b1  = (const float*)d_in[9];
    const float* W2  = (const float*)d_in[10];
    const float* b2  = (const float*)d_in[11];
    const float* g1  = (const float*)d_in[12];
    const float* be1 = (const float*)d_in[13];
    const float* g2  = (const float*)d_in[14];
    const float* be2 = (const float*)d_in[15];
    float* out = (float*)d_out;
    u16* ws = (u16*)d_ws;

    const long SZ = (long)BATCH * NTOK * D_MODEL;  // 3,145,728

    u16* WqT  = ws + 0;          // WqT,WkT contiguous => merged Q+K projection (Nd=768)
    u16* WkT  = ws + 147456;
    u16* WvT  = ws + 294912;
    u16* WoT  = ws + 442368;
    u16* W1T  = ws + 589824;
    u16* W2T  = ws + 1179648;
    u16* QKin = ws + 1769472;
    u16* SRCB = ws + 4915200;
    u16* QtH  = ws + 8060928;    // [8][384][1024]; KtH contiguous after (merged store target)
    u16* KtH  = ws + 11206656;
    u16* VtH  = ws + 14352384;
    u16* BT   = ws + 17498112;   // [8][1024][1024], dead after bias3
    u16* ATT  = ws + 17498112;   // aliases BT (written by attention, after bias3)
    u16* Q2H  = ws + 25886720;   // frag-tiled [64 bh][64 tb][1024], 4,194,304 u16
    u16* K2H  = ws + 30081024;   // frag-tiled, 4,194,304 u16
    u16* V2T  = ws + 34275328;   // frag-tiled [64 bh][16 mb][3072], 3,145,728 u16 (end 37,421,056)
    // aliases (lifetimes disjoint):
    float* Of  = (float*)(ws + 8060928);   // pre-LN1 f32 (over QtH+KtH, dead after bias3)
    float* xf  = (float*)(ws + 14352384);  // post-LN1 f32 (over VtH + BT head; ATT dead by then)
    u16*   xbf = QKin;                     // post-LN1 bf16 (QKin dead after projections)
    u16*   hbf = Q2H;                      // FF hidden [8192][1536] (over Q2H..V2T, dead by FF1)
    float* ff  = (float*)(ws + 8060928);   // pre-LN2 f32 (over Of, dead after LN1)

    // 1. adds + casts
    add_cast_kernel<<<(int)(SZ / 4 + 255) / 256, 256, 0, stream>>>(
        (const float4*)src, (const float4*)pos, (ushort4*)QKin, (ushort4*)SRCB, (int)(SZ / 4));
    // 2. weight transposes
    dim3 tb(32, 8);
    castT4_kernel<<<dim3(12, 12, 4), tb, 0, stream>>>(Wq, Wk, Wv, Wo, WqT, WkT, WvT, WoT);
    castT_kernel<<<dim3(48, 12), tb, 0, stream>>>(W1, W1T, 384, 1536);
    castT_kernel<<<dim3(12, 48), tb, 0, stream>>>(W2, W2T, 1536, 384);
    // 3. relative bias (transposed, bf16)
    biasT_bf16_kernel<<<32768, 256, 0, stream>>>(table, BT);
    // 4. projections -> head-major transposed bf16.  Q and K merged (Nd=768).
    mgemm_kernel<8, false, false, false><<<dim3(12, 128, 1), 256, 0, stream>>>(
        QKin, WqT, nullptr, nullptr, QtH, nullptr, nullptr,
        8192, 384, 768, 384, 384, 0, 0);
    mgemm_kernel<8, false, false, false><<<dim3(6, 128, 1), 256, 0, stream>>>(
        SRCB, WvT, nullptr, nullptr, VtH, nullptr, nullptr,
        8192, 384, 384, 384, 384, 0, 0);
    // 5. fused bias matmuls -> fragment-tiled Q2H (scaled), K2H, V2T
    bias3_kernel<<<768, 256, 0, stream>>>(BT, QtH, KtH, VtH, Q2H, K2H, V2T);
    // 6. attention (wave-split KV, XCD-swizzled, coalesced fragment loads)
    attn_mfma_kernel<<<4096, 256, 0, stream>>>(Q2H, K2H, V2T, ATT);
    // 7. o = att @ Wo + bo + src
    mgemm_kernel<1, true, true, false><<<dim3(6, 128, 1), 256, 0, stream>>>(
        ATT, WoT, Of, nullptr, nullptr, bo, src,
        8192, 384, 384, 384, 384, 384, 384);
    // 8. x = LN1(o)
    ln_kernel<<<8192, 128, 0, stream>>>(Of, nullptr, g1, be1, xf, xbf, 0);
    // 9. h = gelu(x @ W1 + b1)
    mgemm_kernel<2, true, false, true><<<dim3(24, 128, 1), 256, 0, stream>>>(
        xbf, W1T, nullptr, hbf, nullptr, b1, nullptr,
        8192, 384, 1536, 384, 384, 1536, 0);
    // 10. ff = h @ W2 + b2 + x
    mgemm_kernel<1, true, true, false><<<dim3(6, 128, 1), 256, 0, stream>>>(
        hbf, W2T, ff, nullptr, nullptr, b2, xf,
        8192, 1536, 384, 1536, 1536, 384, 384);
    // 11. out = LN2(ff)
    ln_kernel<<<8192, 128, 0, stream>>>(ff, nullptr, g2, be2, out, nullptr, 0);
}